// Round 1
// baseline (522.584 us; speedup 1.0000x reference)
//
#include <hip/hip_runtime.h>
#include <hip/hip_bf16.h>
#include <math.h>

#define DIM 768
#define DFF 2048
#define NH 12
#define HD 64
#define NB 16
#define NOBJ 52
#define LL 24
#define LNEPS 1e-5f

typedef __attribute__((ext_vector_type(8))) short bf16x8;
typedef __attribute__((ext_vector_type(4))) float f32x4;

__device__ __forceinline__ unsigned short f2b(float x) {
    union { float f; unsigned int u; } v; v.f = x;
    unsigned int r = v.u + 0x7fffu + ((v.u >> 16) & 1u);
    return (unsigned short)(r >> 16);
}

__device__ __forceinline__ f32x4 mfma16(bf16x8 a, bf16x8 b, f32x4 c) {
    return __builtin_amdgcn_mfma_f32_16x16x32_bf16(a, b, c, 0, 0, 0);
}

// ---------------------------------------------------------------------------
// Generic bf16-MFMA GEMM: C[M,N] = A[M,K] @ B[K,N] (+bias) (+relu)
// A,B,C f32 row-major. M%64==0, N%64==0, K%32==0.
// Block 256 thr = 4 waves (2x2), tile 64x64, K-step 32.
// ---------------------------------------------------------------------------
__global__ __launch_bounds__(256)
void gemm_bf16_kernel(const float* __restrict__ A, const float* __restrict__ B,
                      const float* __restrict__ bias, float* __restrict__ C,
                      int M, int N, int K, int relu)
{
    __shared__ __align__(16) unsigned short Asm[64][40];
    __shared__ __align__(16) unsigned short Bsm[64][40];   // transposed: [n][k]
    const int tid = threadIdx.x;
    const int lane = tid & 63;
    const int w = tid >> 6;
    const int wm = w >> 1, wn = w & 1;
    const int lr = lane & 15, lk = lane >> 4;
    const int n0 = blockIdx.x * 64, m0 = blockIdx.y * 64;

    f32x4 acc[2][2] = {};

    const int ar = tid >> 2, ac = (tid & 3) * 8;   // A: 64 rows x 32 cols
    const int bk = tid >> 3, bn = (tid & 7) * 8;   // B: 32 k x 64 n

    for (int k0 = 0; k0 < K; k0 += 32) {
        const float* asrc = A + (size_t)(m0 + ar) * K + k0 + ac;
        #pragma unroll
        for (int e = 0; e < 8; ++e) Asm[ar][ac + e] = f2b(asrc[e]);
        const float* bsrc = B + (size_t)(k0 + bk) * N + n0 + bn;
        #pragma unroll
        for (int e = 0; e < 8; ++e) Bsm[bn + e][bk] = f2b(bsrc[e]);
        __syncthreads();
        bf16x8 a0 = *(const bf16x8*)&Asm[wm * 32 + lr][lk * 8];
        bf16x8 a1 = *(const bf16x8*)&Asm[wm * 32 + 16 + lr][lk * 8];
        bf16x8 b0 = *(const bf16x8*)&Bsm[wn * 32 + lr][lk * 8];
        bf16x8 b1 = *(const bf16x8*)&Bsm[wn * 32 + 16 + lr][lk * 8];
        acc[0][0] = mfma16(a0, b0, acc[0][0]);
        acc[0][1] = mfma16(a0, b1, acc[0][1]);
        acc[1][0] = mfma16(a1, b0, acc[1][0]);
        acc[1][1] = mfma16(a1, b1, acc[1][1]);
        __syncthreads();
    }
    #pragma unroll
    for (int mt = 0; mt < 2; ++mt) {
        #pragma unroll
        for (int bt = 0; bt < 2; ++bt) {
            int col = n0 + wn * 32 + bt * 16 + lr;
            float bv = bias ? bias[col] : 0.f;
            #pragma unroll
            for (int r = 0; r < 4; ++r) {
                int row = m0 + wm * 32 + mt * 16 + lk * 4 + r;
                float v = acc[mt][bt][r] + bv;
                if (relu) v = fmaxf(v, 0.f);
                C[(size_t)row * N + col] = v;
            }
        }
    }
}

// ---------------------------------------------------------------------------
// VW precompute: VWt holds B = (Ve_h @ Wo_h) in MFMA-fragment order (bf16):
//   layout [n][ks(9)][tc(48)][lane(64)][e(8)], element (k=h*24+l, col=d)
//   k = ks*32+ko, lane=(ko>>3)*16 + (d&15), e=ko&7, tc=d>>4
// ---------------------------------------------------------------------------
__global__ __launch_bounds__(256)
void vw_kernel(const float* __restrict__ Ve, const float* __restrict__ Wo,
               unsigned short* __restrict__ VWt)
{
    __shared__ float vsm[24][64];
    const int b = blockIdx.x;           // n*NH + h
    const int n = b / NH, h = b % NH;
    const int tid = threadIdx.x;
    for (int p = tid; p < 24 * 64; p += 256) {
        int l = p >> 6, d = p & 63;
        vsm[l][d] = Ve[((size_t)(n * LL + l)) * DIM + h * HD + d];
    }
    __syncthreads();
    unsigned short* VWn = VWt + (size_t)n * 9 * 48 * 64 * 8;
    for (int c = 0; c < 3; ++c) {
        int d = c * 256 + tid;
        float acc[24];
        #pragma unroll
        for (int l = 0; l < 24; ++l) acc[l] = 0.f;
        for (int dp = 0; dp < 64; ++dp) {
            float wv = Wo[(size_t)(h * HD + dp) * DIM + d];
            #pragma unroll
            for (int l = 0; l < 24; ++l) acc[l] += vsm[l][dp] * wv;
        }
        int tc = d >> 4, dl = d & 15;
        #pragma unroll
        for (int l = 0; l < 24; ++l) {
            int k = h * 24 + l;
            int ks = k >> 5, ko = k & 31;
            int lanei = (ko >> 3) * 16 + dl;
            VWn[(((size_t)ks * 48 + tc) * 64 + lanei) * 8 + (ko & 7)] = f2b(acc[l]);
        }
    }
}

// ---------------------------------------------------------------------------
// S2e[n,h,q,l] = Qe[n,q,h,:]·Ke[n,l,h,:]  and  T[n,h,l] = e_bq_h·Ke[n,l,h,:]
// ---------------------------------------------------------------------------
__global__ __launch_bounds__(256)
void s2e_kernel(const float* __restrict__ Qe, const float* __restrict__ Ke,
                const float* __restrict__ ebq,
                float* __restrict__ S2e, float* __restrict__ Tb)
{
    __shared__ float ksm[24][64];
    const int b = blockIdx.x; const int n = b / NH, h = b % NH;
    const int tid = threadIdx.x;
    for (int p = tid; p < 24 * 64; p += 256) {
        int l = p >> 6, d = p & 63;
        ksm[l][d] = Ke[((size_t)(n * LL + l)) * DIM + h * HD + d];
    }
    __syncthreads();
    for (int p = tid; p < NOBJ * LL; p += 256) {
        int q = p / LL, l = p % LL;
        const float* qr = Qe + ((size_t)(n * NOBJ + q)) * DIM + h * HD;
        float s = 0.f;
        #pragma unroll
        for (int d = 0; d < 64; ++d) s += qr[d] * ksm[l][d];
        S2e[(((size_t)(n * NH + h)) * NOBJ + q) * LL + l] = s;
    }
    if (tid < LL) {
        float s = 0.f;
        #pragma unroll
        for (int d = 0; d < 64; ++d) s += ebq[h * HD + d] * ksm[tid][d];
        Tb[((size_t)(n * NH + h)) * LL + tid] = s;
    }
}

// ---------------------------------------------------------------------------
// Node attention: one wave per (n,h,q). grid = NB*NH*13, block 256 (4 waves).
// ---------------------------------------------------------------------------
__global__ __launch_bounds__(256)
void node_attn_kernel(const float* __restrict__ Qn, const float* __restrict__ Kn,
                      const float* __restrict__ Vn, const int* __restrict__ co_mask,
                      float* __restrict__ Ctxn)
{
    const int b = blockIdx.x;
    const int qb = b % 13;
    const int h = (b / 13) % NH;
    const int n = b / (13 * NH);
    const int lane = threadIdx.x & 63;
    const int wv = threadIdx.x >> 6;
    const int q = qb * 4 + wv;
    const float qd = Qn[((size_t)(n * NOBJ + q)) * DIM + h * HD + lane];
    float logit = 0.f;
    for (int l = 0; l < LL; ++l) {
        float kd = Kn[((size_t)(n * LL + l)) * DIM + h * HD + lane];
        float p = qd * kd;
        #pragma unroll
        for (int o = 32; o; o >>= 1) p += __shfl_xor(p, o);
        if (lane == l) logit = p;
    }
    float x;
    if (lane < LL) {
        int cm = co_mask[((size_t)n * LL + lane) * NOBJ + q];
        x = (cm > 0) ? logit * 0.125f : -1e9f;
    } else x = -INFINITY;
    float m = x;
    #pragma unroll
    for (int o = 32; o; o >>= 1) m = fmaxf(m, __shfl_xor(m, o));
    float e = (lane < LL) ? __expf(x - m) : 0.f;
    float s = e;
    #pragma unroll
    for (int o = 32; o; o >>= 1) s += __shfl_xor(s, o);
    float a = e / s;
    float ctx = 0.f;
    for (int l = 0; l < LL; ++l) {
        float al = __shfl(a, l);
        ctx += al * Vn[((size_t)(n * LL + l)) * DIM + h * HD + lane];
    }
    Ctxn[((size_t)(n * NOBJ + q)) * DIM + h * HD + lane] = ctx;
}

// ---------------------------------------------------------------------------
// Edge main: block per (n,i). Softmax of (S2[i]+T-S2[j]) -> A[52(pad64)][288]
// in LDS (bf16), then C[64x768] = A @ VW_n via MFMA, max over valid j rows,
// +e_bo, write edge[n,i,:]. Block 512 thr = 8 waves (2 M x 4 N).
// ---------------------------------------------------------------------------
__global__ __launch_bounds__(512)
void edge_kernel(const float* __restrict__ S2e, const float* __restrict__ Tb,
                 const int* __restrict__ co_mask, const unsigned short* __restrict__ VWt,
                 const float* __restrict__ ebo, float* __restrict__ Edge)
{
    __shared__ __align__(16) unsigned short Asm[64][296];
    __shared__ float maxbuf[2][768];
    const int blk = blockIdx.x;
    const int n = blk / NOBJ, i = blk % NOBJ;
    const int tid = threadIdx.x;
    const float* S2n = S2e + (size_t)n * NH * NOBJ * LL;

    for (int p = tid; p < 64 * NH; p += 512) {
        int j = p / NH, h = p % NH;
        unsigned short* arow = &Asm[j][h * LL];
        if (j < NOBJ) {
            const float* Si = S2n + (h * NOBJ + i) * LL;
            const float* Sj = S2n + (h * NOBJ + j) * LL;
            const float* Th = Tb + ((size_t)n * NH + h) * LL;
            float x[24]; float mx = -INFINITY;
            #pragma unroll
            for (int l = 0; l < 24; ++l) {
                float v = (Si[l] + Th[l] - Sj[l]) * 0.125f;
                int cm = co_mask[((size_t)n * LL + l) * NOBJ + j];
                v = (cm > 0) ? v : -1e9f;
                x[l] = v; mx = fmaxf(mx, v);
            }
            float sum = 0.f;
            #pragma unroll
            for (int l = 0; l < 24; ++l) { float e = __expf(x[l] - mx); x[l] = e; sum += e; }
            float inv = 1.f / sum;
            #pragma unroll
            for (int l = 0; l < 24; ++l) arow[l] = f2b(x[l] * inv);
        } else {
            #pragma unroll
            for (int l = 0; l < 24; ++l) arow[l] = 0;
        }
    }
    __syncthreads();

    const int lane = tid & 63, w = tid >> 6;
    const int wm = w >> 2, wn = w & 3;
    const int lr = lane & 15, lk = lane >> 4;
    const unsigned short* Bn = VWt + (size_t)n * 9 * 48 * 64 * 8;
    f32x4 acc[2][12] = {};

    for (int ks = 0; ks < 9; ++ks) {
        bf16x8 a0 = *(const bf16x8*)&Asm[wm * 32 + lr][ks * 32 + lk * 8];
        bf16x8 a1 = *(const bf16x8*)&Asm[wm * 32 + 16 + lr][ks * 32 + lk * 8];
        #pragma unroll
        for (int nt = 0; nt < 12; ++nt) {
            int tc = wn * 12 + nt;
            bf16x8 bfr = *(const bf16x8*)&Bn[(((size_t)ks * 48 + tc) * 64 + lane) * 8];
            acc[0][nt] = mfma16(a0, bfr, acc[0][nt]);
            acc[1][nt] = mfma16(a1, bfr, acc[1][nt]);
        }
    }

    #pragma unroll
    for (int nt = 0; nt < 12; ++nt) {
        float m = -INFINITY;
        #pragma unroll
        for (int mt = 0; mt < 2; ++mt) {
            #pragma unroll
            for (int r = 0; r < 4; ++r) {
                int row = wm * 32 + mt * 16 + lk * 4 + r;
                float v = acc[mt][nt][r];
                m = (row < NOBJ) ? fmaxf(m, v) : m;
            }
        }
        m = fmaxf(m, __shfl_xor(m, 16));
        m = fmaxf(m, __shfl_xor(m, 32));
        if (lk == 0) maxbuf[wm][wn * 192 + nt * 16 + lr] = m;
    }
    __syncthreads();
    for (int c = tid; c < DIM; c += 512) {
        Edge[((size_t)(n * NOBJ + i)) * DIM + c] =
            fmaxf(maxbuf[0][c], maxbuf[1][c]) + ebo[c];
    }
}

// ---------------------------------------------------------------------------
// dst[row*sd + c] = LN(x1[row*s1 + c] + x2[row*s2 + c]) * g + b, c in [0,768)
// ---------------------------------------------------------------------------
__global__ __launch_bounds__(256)
void ln_add_kernel(const float* __restrict__ x1, int s1,
                   const float* __restrict__ x2, int s2,
                   const float* __restrict__ g, const float* __restrict__ bb,
                   float* __restrict__ dst, int sd)
{
    __shared__ float red[8];
    const int row = blockIdx.x, tid = threadIdx.x;
    const float* p1 = x1 + (size_t)row * s1;
    const float* p2 = x2 + (size_t)row * s2;
    float v[3];
    float s = 0.f;
    #pragma unroll
    for (int c = 0; c < 3; ++c) { v[c] = p1[tid + 256 * c] + p2[tid + 256 * c]; s += v[c]; }
    #pragma unroll
    for (int o = 32; o; o >>= 1) s += __shfl_xor(s, o);
    if ((tid & 63) == 0) red[tid >> 6] = s;
    __syncthreads();
    float mean = (red[0] + red[1] + red[2] + red[3]) * (1.f / 768.f);
    float var = 0.f;
    #pragma unroll
    for (int c = 0; c < 3; ++c) { float d = v[c] - mean; var += d * d; }
    #pragma unroll
    for (int o = 32; o; o >>= 1) var += __shfl_xor(var, o);
    __syncthreads();
    if ((tid & 63) == 0) red[4 + (tid >> 6)] = var;
    __syncthreads();
    float vt = (red[4] + red[5] + red[6] + red[7]) * (1.f / 768.f);
    float rs = rsqrtf(vt + LNEPS);
    #pragma unroll
    for (int c = 0; c < 3; ++c) {
        int col = tid + 256 * c;
        dst[(size_t)row * sd + col] = (v[c] - mean) * rs * g[col] + bb[col];
    }
}

// ---------------------------------------------------------------------------
extern "C" void kernel_launch(void* const* d_in, const int* in_sizes, int n_in,
                              void* d_out, int out_size, void* d_ws, size_t ws_size,
                              hipStream_t stream)
{
    (void)in_sizes; (void)n_in; (void)out_size; (void)ws_size;
    const float* lang  = (const float*)d_in[0];
    const float* obj   = (const float*)d_in[1];
    const int* co_mask = (const int*)d_in[4];
    const float* e_wq = (const float*)d_in[5];
    const float* e_bq = (const float*)d_in[6];
    const float* e_wk = (const float*)d_in[7];
    const float* e_bk = (const float*)d_in[8];
    const float* e_wv = (const float*)d_in[9];
    const float* e_bv = (const float*)d_in[10];
    const float* e_wo = (const float*)d_in[11];
    const float* e_bo = (const float*)d_in[12];
    const float* n_wq = (const float*)d_in[13];
    const float* n_bq = (const float*)d_in[14];
    const float* n_wk = (const float*)d_in[15];
    const float* n_bk = (const float*)d_in[16];
    const float* n_wv = (const float*)d_in[17];
    const float* n_bv = (const float*)d_in[18];
    const float* n_wo = (const float*)d_in[19];
    const float* n_bo = (const float*)d_in[20];
    const float* ffn_w1 = (const float*)d_in[21];
    const float* ffn_b1 = (const float*)d_in[22];
    const float* ffn_w2 = (const float*)d_in[23];
    const float* ffn_b2 = (const float*)d_in[24];
    const float* ln_e_g = (const float*)d_in[25];
    const float* ln_e_b = (const float*)d_in[26];
    const float* ln_q_g = (const float*)d_in[27];
    const float* ln_q_b = (const float*)d_in[28];
    const float* ln2_g = (const float*)d_in[29];
    const float* ln2_b = (const float*)d_in[30];
    float* out = (float*)d_out;

    // workspace layout (f32 elements; all 16B-aligned)
    float* W = (float*)d_ws;
    float* Qe    = W;                 // 832*768
    float* Qn    = Qe + 638976;
    float* Ke    = Qn + 638976;       // 384*768
    float* Vebuf = Ke + 294912;
    float* Kn    = Vebuf + 294912;
    float* Vn    = Kn + 294912;
    float* Ctxn  = Vn + 294912;       // 832*768
    float* NodeP = Ctxn + 638976;
    float* Edge  = NodeP + 638976;
    float* H1    = Edge + 638976;     // 832*2048
    float* H2    = H1 + 1703936;      // 832*768
    float* Fused = H2 + 638976;       // 832*1536
    float* S2e   = Fused + 1277952;   // 16*12*52*24
    float* Tb    = S2e + 239616;      // 16*12*24
    unsigned short* VWt = (unsigned short*)(Tb + 4608);  // 16*9*48*64*8 bf16

    dim3 blk(256);
    // projections
    gemm_bf16_kernel<<<dim3(12, 13), blk, 0, stream>>>(obj,  e_wq, nullptr, Qe,    832, 768, 768, 0);
    gemm_bf16_kernel<<<dim3(12, 13), blk, 0, stream>>>(obj,  n_wq, n_bq,    Qn,    832, 768, 768, 0);
    gemm_bf16_kernel<<<dim3(12, 6),  blk, 0, stream>>>(lang, e_wk, e_bk,    Ke,    384, 768, 768, 0);
    gemm_bf16_kernel<<<dim3(12, 6),  blk, 0, stream>>>(lang, e_wv, e_bv,    Vebuf, 384, 768, 768, 0);
    gemm_bf16_kernel<<<dim3(12, 6),  blk, 0, stream>>>(lang, n_wk, n_bk,    Kn,    384, 768, 768, 0);
    gemm_bf16_kernel<<<dim3(12, 6),  blk, 0, stream>>>(lang, n_wv, n_bv,    Vn,    384, 768, 768, 0);
    // edge precomputes
    vw_kernel<<<NB * NH, blk, 0, stream>>>(Vebuf, e_wo, VWt);
    s2e_kernel<<<NB * NH, blk, 0, stream>>>(Qe, Ke, e_bq, S2e, Tb);
    // node branch
    node_attn_kernel<<<NB * NH * 13, blk, 0, stream>>>(Qn, Kn, Vn, co_mask, Ctxn);
    gemm_bf16_kernel<<<dim3(12, 13), blk, 0, stream>>>(Ctxn, n_wo, n_bo, NodeP, 832, 768, 768, 0);
    ln_add_kernel<<<832, blk, 0, stream>>>(obj, 768, NodeP, 768, ln_q_g, ln_q_b, Fused, 1536);
    // edge branch
    edge_kernel<<<832, dim3(512), 0, stream>>>(S2e, Tb, co_mask, VWt, e_bo, Edge);
    ln_add_kernel<<<832, blk, 0, stream>>>(obj, 768, Edge, 768, ln_e_g, ln_e_b, Fused + 768, 1536);
    // FFN
    gemm_bf16_kernel<<<dim3(32, 13), blk, 0, stream>>>(Fused, ffn_w1, ffn_b1, H1, 832, 2048, 1536, 1);
    gemm_bf16_kernel<<<dim3(12, 13), blk, 0, stream>>>(H1, ffn_w2, ffn_b2, H2, 832, 768, 2048, 0);
    ln_add_kernel<<<832, blk, 0, stream>>>(Fused, 1536, H2, 768, ln2_g, ln2_b, out, 768);
}

// Round 2
// 415.216 us; speedup vs baseline: 1.2586x; 1.2586x over previous
//
#include <hip/hip_runtime.h>
#include <math.h>

#define NOBJ 52
#define LL 24
#define NHEAD 12

typedef __attribute__((ext_vector_type(8))) short bf16x8;
typedef __attribute__((ext_vector_type(4))) float f32x4;
typedef __attribute__((ext_vector_type(4))) unsigned int u32x4;

__device__ __forceinline__ unsigned short f2b(float x) {
    union { float f; unsigned int u; } v; v.f = x;
    unsigned int r = v.u + 0x7fffu + ((v.u >> 16) & 1u);
    return (unsigned short)(r >> 16);
}
__device__ __forceinline__ float b2f(unsigned short u) {
    union { unsigned int u; float f; } v; v.u = ((unsigned int)u) << 16;
    return v.f;
}
__device__ __forceinline__ f32x4 mfma16(bf16x8 a, bf16x8 b, f32x4 c) {
    return __builtin_amdgcn_mfma_f32_16x16x32_bf16(a, b, c, 0, 0, 0);
}
__device__ __forceinline__ void gl_lds16(const void* g, void* lds) {
    __builtin_amdgcn_global_load_lds(
        (const __attribute__((address_space(1))) unsigned int*)g,
        (__attribute__((address_space(3))) unsigned int*)lds, 16, 0, 0);
}

// ---------------------------------------------------------------------------
// packw: transpose f32 [K][N] -> bf16 [N][K], 9 jobs selected by blockIdx.y
// ---------------------------------------------------------------------------
__global__ __launch_bounds__(256)
void packw_kernel(const float* s0, const float* s1, const float* s2,
                  const float* s3, const float* s4, const float* s5,
                  const float* s6, const float* s7, const float* s8,
                  unsigned short* d0, unsigned short* d1, unsigned short* d2,
                  unsigned short* d3, unsigned short* d4, unsigned short* d5,
                  unsigned short* d6, unsigned short* d7, unsigned short* d8)
{
    __shared__ float ts[32][33];
    const int job = blockIdx.y;
    const float* src; unsigned short* dst; int K, N;
    if      (job == 0) { src = s0; dst = d0; K = 768;  N = 768;  }
    else if (job == 1) { src = s1; dst = d1; K = 768;  N = 768;  }
    else if (job == 2) { src = s2; dst = d2; K = 768;  N = 768;  }
    else if (job == 3) { src = s3; dst = d3; K = 768;  N = 768;  }
    else if (job == 4) { src = s4; dst = d4; K = 768;  N = 768;  }
    else if (job == 5) { src = s5; dst = d5; K = 768;  N = 768;  }
    else if (job == 6) { src = s6; dst = d6; K = 768;  N = 768;  }
    else if (job == 7) { src = s7; dst = d7; K = 1536; N = 2048; }
    else               { src = s8; dst = d8; K = 2048; N = 768;  }
    const int ntk = K >> 5;
    const int tiles = ntk * (N >> 5);
    const int t = blockIdx.x;
    if (t >= tiles) return;
    const int k0 = (t % ntk) << 5, n0 = (t / ntk) << 5;
    const int tx = threadIdx.x & 31, ty = threadIdx.x >> 5;
    #pragma unroll
    for (int i = 0; i < 4; ++i)
        ts[ty + 8*i][tx] = src[(size_t)(k0 + ty + 8*i) * N + n0 + tx];
    __syncthreads();
    #pragma unroll
    for (int i = 0; i < 4; ++i)
        dst[(size_t)(n0 + ty + 8*i) * K + k0 + tx] = f2b(ts[tx][ty + 8*i]);
}

// ---------------------------------------------------------------------------
// packa: obj->bf16 (pad to 896 rows, zeros), lang->bf16, combined biases
// ---------------------------------------------------------------------------
__global__ __launch_bounds__(256)
void packa_kernel(const float* __restrict__ obj, const float* __restrict__ lang,
                  const float* __restrict__ n_bq,
                  const float* __restrict__ e_bk, const float* __restrict__ e_bv,
                  const float* __restrict__ n_bk, const float* __restrict__ n_bv,
                  unsigned short* __restrict__ objb, unsigned short* __restrict__ langb,
                  float* __restrict__ bqc, float* __restrict__ blc)
{
    const int i = blockIdx.x * 256 + threadIdx.x;
    const int T0 = 896 * 768, T1 = T0 + 384 * 768, T2 = T1 + 1536, T3 = T2 + 3072;
    if (i >= T3) return;
    if (i < T0) {
        objb[i] = (i < 832 * 768) ? f2b(obj[i]) : (unsigned short)0;
    } else if (i < T1) {
        int j = i - T0; langb[j] = f2b(lang[j]);
    } else if (i < T2) {
        int j = i - T1;
        bqc[j] = (j < 768) ? 0.f : n_bq[j - 768];
    } else {
        int j = i - T2;
        int s = j / 768, c = j % 768;
        const float* p = (s == 0) ? e_bk : (s == 1) ? e_bv : (s == 2) ? n_bk : n_bv;
        blc[j] = p[c];
    }
}

// ---------------------------------------------------------------------------
// Generic GEMM: C[M,N] = A[M,K](bf16,lda) @ Bt[N,K](bf16)^T + bias, opt relu.
// 128x128 tile, BK=32, 256 thr (4 waves 2x2, each 64x64), global_load_lds dbuf.
// Outputs: C (f32, opt) and/or Cb (bf16, opt), both stride ldc. Rows >= M skipped.
// ---------------------------------------------------------------------------
__global__ __launch_bounds__(256)
void gemm_tn(const unsigned short* __restrict__ A, int lda,
             const unsigned short* __restrict__ Bt,
             const float* __restrict__ bias,
             float* __restrict__ C, unsigned short* __restrict__ Cb,
             int ldc, int M, int K, int relu)
{
    __shared__ __align__(16) unsigned short As[2][128 * 32];
    __shared__ __align__(16) unsigned short Bs[2][128 * 32];
    const int tid = threadIdx.x;
    const int lane = tid & 63;
    const int w = tid >> 6, wr = w >> 1, wc = w & 1;
    const int lr = lane & 15, lk = lane >> 4;
    const int n0 = blockIdx.x * 128, m0 = blockIdx.y * 128;
    const int sr = tid >> 2, sc = (tid & 3) * 8;

    f32x4 acc[4][4] = {};
    const int NT = K >> 5;

    gl_lds16(A + (size_t)(m0 + sr) * lda + sc,        &As[0][tid * 8]);
    gl_lds16(A + (size_t)(m0 + 64 + sr) * lda + sc,   &As[0][2048 + tid * 8]);
    gl_lds16(Bt + (size_t)(n0 + sr) * K + sc,         &Bs[0][tid * 8]);
    gl_lds16(Bt + (size_t)(n0 + 64 + sr) * K + sc,    &Bs[0][2048 + tid * 8]);
    __syncthreads();

    for (int t = 0; t < NT; ++t) {
        const int cur = t & 1;
        if (t + 1 < NT) {
            const int k0 = (t + 1) << 5;
            gl_lds16(A + (size_t)(m0 + sr) * lda + k0 + sc,      &As[cur ^ 1][tid * 8]);
            gl_lds16(A + (size_t)(m0 + 64 + sr) * lda + k0 + sc, &As[cur ^ 1][2048 + tid * 8]);
            gl_lds16(Bt + (size_t)(n0 + sr) * K + k0 + sc,       &Bs[cur ^ 1][tid * 8]);
            gl_lds16(Bt + (size_t)(n0 + 64 + sr) * K + k0 + sc,  &Bs[cur ^ 1][2048 + tid * 8]);
        }
        bf16x8 af[4], bfv[4];
        #pragma unroll
        for (int mt = 0; mt < 4; ++mt)
            af[mt] = *(const bf16x8*)&As[cur][(wr * 64 + mt * 16 + lr) * 32 + lk * 8];
        #pragma unroll
        for (int nt = 0; nt < 4; ++nt)
            bfv[nt] = *(const bf16x8*)&Bs[cur][(wc * 64 + nt * 16 + lr) * 32 + lk * 8];
        #pragma unroll
        for (int mt = 0; mt < 4; ++mt)
            #pragma unroll
            for (int nt = 0; nt < 4; ++nt)
                acc[mt][nt] = mfma16(af[mt], bfv[nt], acc[mt][nt]);
        __syncthreads();
    }

    #pragma unroll
    for (int mt = 0; mt < 4; ++mt) {
        #pragma unroll
        for (int nt = 0; nt < 4; ++nt) {
            const int col = n0 + wc * 64 + nt * 16 + lr;
            const float bv = bias ? bias[col] : 0.f;
            #pragma unroll
            for (int r = 0; r < 4; ++r) {
                const int row = m0 + wr * 64 + mt * 16 + lk * 4 + r;
                if (row < M) {
                    float v = acc[mt][nt][r] + bv;
                    if (relu) v = fmaxf(v, 0.f);
                    if (C)  C[(size_t)row * ldc + col] = v;
                    if (Cb) Cb[(size_t)row * ldc + col] = f2b(v);
                }
            }
        }
    }
}

// ---------------------------------------------------------------------------
// VW precompute: VWt[n][d][h*24+l] = sum_dp Ve[n,l,h,dp] * Wo[h*64+dp, d]  (bf16)
// block per (n,h)
// ---------------------------------------------------------------------------
__global__ __launch_bounds__(256)
void vw_kernel(const unsigned short* __restrict__ LCb, const float* __restrict__ Wo,
               unsigned short* __restrict__ VWt)
{
    __shared__ float vsm[24][64];
    const int b = blockIdx.x;
    const int n = b / NHEAD, h = b % NHEAD;
    const int tid = threadIdx.x;
    for (int p = tid; p < 24 * 64; p += 256) {
        int l = p >> 6, d = p & 63;
        vsm[l][d] = b2f(LCb[(size_t)(n * 24 + l) * 3072 + 768 + h * 64 + d]);
    }
    __syncthreads();
    unsigned short* VWn = VWt + (size_t)n * 768 * 288;
    for (int c = 0; c < 3; ++c) {
        const int d = c * 256 + tid;
        float acc[24] = {};
        for (int dp = 0; dp < 64; ++dp) {
            float wv = Wo[(size_t)(h * 64 + dp) * 768 + d];
            #pragma unroll
            for (int l = 0; l < 24; ++l) acc[l] += vsm[l][dp] * wv;
        }
        unsigned int u[12];
        #pragma unroll
        for (int cc = 0; cc < 12; ++cc)
            u[cc] = (unsigned int)f2b(acc[2 * cc]) | ((unsigned int)f2b(acc[2 * cc + 1]) << 16);
        u32x4* dst = (u32x4*)(VWn + (size_t)d * 288 + h * 24);
        dst[0] = (u32x4){u[0], u[1], u[2], u[3]};
        dst[1] = (u32x4){u[4], u[5], u[6], u[7]};
        dst[2] = (u32x4){u[8], u[9], u[10], u[11]};
    }
}

// ---------------------------------------------------------------------------
// S2e[n,h,q,l] = Qe[n,q,h,:].Ke[n,l,h,:]; T[n,h,l] = e_bq_h.Ke  — block per (n,h)
// ---------------------------------------------------------------------------
__global__ __launch_bounds__(256)
void s2e_kernel(const unsigned short* __restrict__ QCb, const unsigned short* __restrict__ LCb,
                const float* __restrict__ ebq,
                float* __restrict__ S2e, float* __restrict__ Tb)
{
    __shared__ float qsm[52][65];
    __shared__ float ksm[24][65];
    const int b = blockIdx.x;
    const int n = b / NHEAD, h = b % NHEAD;
    const int tid = threadIdx.x;
    for (int p = tid; p < 52 * 64; p += 256) {
        int q = p >> 6, d = p & 63;
        qsm[q][d] = b2f(QCb[(size_t)(n * 52 + q) * 1536 + h * 64 + d]);
    }
    for (int p = tid; p < 24 * 64; p += 256) {
        int l = p >> 6, d = p & 63;
        ksm[l][d] = b2f(LCb[(size_t)(n * 24 + l) * 3072 + h * 64 + d]);
    }
    __syncthreads();
    for (int p = tid; p < 52 * 24; p += 256) {
        int q = p / 24, l = p % 24;
        float s = 0.f;
        #pragma unroll
        for (int d = 0; d < 64; ++d) s += qsm[q][d] * ksm[l][d];
        S2e[((size_t)(n * NHEAD + h) * 52 + q) * 24 + l] = s;
    }
    if (tid < 24) {
        float s = 0.f;
        #pragma unroll
        for (int d = 0; d < 64; ++d) s += ebq[h * 64 + d] * ksm[tid][d];
        Tb[((size_t)n * NHEAD + h) * 24 + tid] = s;
    }
}

// ---------------------------------------------------------------------------
// Node attention: block per (n,h); K/V staged in LDS; wave handles 13 q.
// ---------------------------------------------------------------------------
__global__ __launch_bounds__(256)
void node_attn_kernel(const unsigned short* __restrict__ QCb,
                      const unsigned short* __restrict__ LCb,
                      const int* __restrict__ co_mask,
                      unsigned short* __restrict__ Ctxnb)
{
    __shared__ float ksm[24][65];
    __shared__ float vsm[24][65];
    const int b = blockIdx.x;
    const int n = b / NHEAD, h = b % NHEAD;
    const int tid = threadIdx.x;
    for (int p = tid; p < 24 * 64; p += 256) {
        int l = p >> 6, d = p & 63;
        const unsigned short* Lr = LCb + (size_t)(n * 24 + l) * 3072;
        ksm[l][d] = b2f(Lr[1536 + h * 64 + d]);
        vsm[l][d] = b2f(Lr[2304 + h * 64 + d]);
    }
    __syncthreads();
    const int lane = tid & 63, wq = tid >> 6;
    for (int iq = 0; iq < 13; ++iq) {
        const int q = wq * 13 + iq;
        const float qd = b2f(QCb[(size_t)(n * 52 + q) * 1536 + 768 + h * 64 + lane]);
        float logit = 0.f;
        for (int l = 0; l < 24; ++l) {
            float p = qd * ksm[l][lane];
            #pragma unroll
            for (int o = 32; o; o >>= 1) p += __shfl_xor(p, o);
            if (lane == l) logit = p;
        }
        float x = -INFINITY;
        if (lane < 24)
            x = (co_mask[((size_t)n * 24 + lane) * 52 + q] > 0) ? logit * 0.125f : -1e9f;
        float m = x;
        #pragma unroll
        for (int o = 32; o; o >>= 1) m = fmaxf(m, __shfl_xor(m, o));
        float e = (lane < 24) ? __expf(x - m) : 0.f;
        float s = e;
        #pragma unroll
        for (int o = 32; o; o >>= 1) s += __shfl_xor(s, o);
        const float a = e / s;
        float ctx = 0.f;
        for (int l = 0; l < 24; ++l)
            ctx += __shfl(a, l) * vsm[l][lane];
        Ctxnb[(size_t)(n * 52 + q) * 768 + h * 64 + lane] = f2b(ctx);
    }
}

// ---------------------------------------------------------------------------
// Edge main: block per (n, i, 128-col tile). In-LDS softmax (XOR-swizzled A)
// then A[64x288] @ VW[288x128] via MFMA (B dbuf-staged), max over j, +e_bo.
// ---------------------------------------------------------------------------
__global__ __launch_bounds__(256)
void edge_kernel(const float* __restrict__ S2e, const float* __restrict__ Tb,
                 const int* __restrict__ co_mask,
                 const unsigned short* __restrict__ VWt,
                 const float* __restrict__ ebo, float* __restrict__ Edge)
{
    __shared__ __align__(16) unsigned short Asm[64 * 288];
    __shared__ __align__(16) unsigned short Bs[2][128 * 32];
    __shared__ float SiT[288];
    __shared__ unsigned char cmb[24 * 52];
    __shared__ float maxbuf[2][128];
    const int bi = blockIdx.x;                 // n*52 + i
    const int n = bi / 52, i = bi % 52;
    const int n0 = blockIdx.y * 128;
    const int tid = threadIdx.x;
    const unsigned short* Bn = VWt + (size_t)n * 768 * 288;
    const float* S2n = S2e + (size_t)n * NHEAD * 52 * 24;

    // prologue: stage B tile 0 early (overlaps softmax)
    gl_lds16(Bn + (size_t)(n0 + (tid >> 2)) * 288 + (tid & 3) * 8,      &Bs[0][tid * 8]);
    gl_lds16(Bn + (size_t)(n0 + 64 + (tid >> 2)) * 288 + (tid & 3) * 8, &Bs[0][2048 + tid * 8]);

    for (int p = tid; p < 288; p += 256) {
        int h = p / 24, l = p % 24;
        SiT[p] = S2n[((size_t)h * 52 + i) * 24 + l] + Tb[((size_t)n * NHEAD + h) * 24 + l];
    }
    for (int p = tid; p < 24 * 52; p += 256)
        cmb[p] = (unsigned char)(co_mask[(size_t)n * 24 * 52 + p] > 0);
    __syncthreads();

    // softmax rows -> Asm (bf16, XOR-swizzled by row)
    for (int p = tid; p < 624; p += 256) {
        const int h = p / 52, j = p % 52;
        const float* Sj = S2n + ((size_t)h * 52 + j) * 24;
        const float* st = SiT + h * 24;
        float x[24]; float mx = -1e30f;
        #pragma unroll
        for (int l = 0; l < 24; ++l) {
            float v = (st[l] - Sj[l]) * 0.125f;
            v = cmb[l * 52 + j] ? v : -1e9f;
            x[l] = v; mx = fmaxf(mx, v);
        }
        float sum = 0.f;
        #pragma unroll
        for (int l = 0; l < 24; ++l) { float e = __expf(x[l] - mx); x[l] = e; sum += e; }
        const float inv = 1.f / sum;
        unsigned int u[12];
        #pragma unroll
        for (int c = 0; c < 12; ++c)
            u[c] = (unsigned int)f2b(x[2 * c] * inv) | ((unsigned int)f2b(x[2 * c + 1] * inv) << 16);
        char* base = (char*)Asm;
        const int rb = j * 576 + h * 48;
        const int sw = (j & 7) << 4;
        *(u32x4*)(base + ((rb) ^ sw))      = (u32x4){u[0], u[1], u[2], u[3]};
        *(u32x4*)(base + ((rb + 16) ^ sw)) = (u32x4){u[4], u[5], u[6], u[7]};
        *(u32x4*)(base + ((rb + 32) ^ sw)) = (u32x4){u[8], u[9], u[10], u[11]};
    }
    for (int p = tid; p < 12 * 36; p += 256) {       // zero rows 52..63
        const int row = 52 + p / 36, c = p % 36;
        *(u32x4*)((char*)Asm + ((row * 576 + c * 16) ^ ((row & 7) << 4))) = (u32x4){0, 0, 0, 0};
    }
    __syncthreads();

    const int lane = tid & 63, w = tid >> 6;
    const int wr = w >> 1, wc = w & 1;
    const int lr = lane & 15, lk = lane >> 4;
    f32x4 acc[2][4] = {};
    for (int t = 0; t < 9; ++t) {
        const int cur = t & 1;
        if (t < 8) {
            const int k0 = (t + 1) * 32;
            gl_lds16(Bn + (size_t)(n0 + (tid >> 2)) * 288 + k0 + (tid & 3) * 8,      &Bs[cur ^ 1][tid * 8]);
            gl_lds16(Bn + (size_t)(n0 + 64 + (tid >> 2)) * 288 + k0 + (tid & 3) * 8, &Bs[cur ^ 1][2048 + tid * 8]);
        }
        bf16x8 af[2], bfv[4];
        #pragma unroll
        for (int mt = 0; mt < 2; ++mt) {
            const int row = wr * 32 + mt * 16 + lr;
            af[mt] = *(const bf16x8*)((char*)Asm + ((row * 576 + t * 64 + lk * 16) ^ ((row & 7) << 4)));
        }
        #pragma unroll
        for (int nt = 0; nt < 4; ++nt)
            bfv[nt] = *(const bf16x8*)&Bs[cur][(wc * 64 + nt * 16 + lr) * 32 + lk * 8];
        #pragma unroll
        for (int mt = 0; mt < 2; ++mt)
            #pragma unroll
            for (int nt = 0; nt < 4; ++nt)
                acc[mt][nt] = mfma16(af[mt], bfv[nt], acc[mt][nt]);
        __syncthreads();
    }

    #pragma unroll
    for (int nt = 0; nt < 4; ++nt) {
        float m = -1e30f;
        #pragma unroll
        for (int mt = 0; mt < 2; ++mt)
            #pragma unroll
            for (int r = 0; r < 4; ++r) {
                const int row = wr * 32 + mt * 16 + lk * 4 + r;
                if (row < NOBJ) m = fmaxf(m, acc[mt][nt][r]);
            }
        m = fmaxf(m, __shfl_xor(m, 16));
        m = fmaxf(m, __shfl_xor(m, 32));
        if (lk == 0) maxbuf[wr][wc * 64 + nt * 16 + lr] = m;
    }
    __syncthreads();
    if (tid < 128) {
        const int c = n0 + tid;
        Edge[(size_t)bi * 768 + c] = fmaxf(maxbuf[0][tid], maxbuf[1][tid]) + ebo[c];
    }
}

// ---------------------------------------------------------------------------
// LN(x1 + x2): x1 from f32 or bf16; outputs f32 and/or bf16
// ---------------------------------------------------------------------------
__global__ __launch_bounds__(256)
void ln_add_kernel(const float* __restrict__ x1f, const unsigned short* __restrict__ x1b, int s1,
                   const float* __restrict__ x2, int s2,
                   const float* __restrict__ g, const float* __restrict__ bb,
                   float* __restrict__ dstf, unsigned short* __restrict__ dstb, int sd)
{
    __shared__ float red[8];
    const int row = blockIdx.x, tid = threadIdx.x;
    float v[3]; float s = 0.f;
    #pragma unroll
    for (int c = 0; c < 3; ++c) {
        const int col = tid + 256 * c;
        const float a = x1f ? x1f[(size_t)row * s1 + col] : b2f(x1b[(size_t)row * s1 + col]);
        v[c] = a + x2[(size_t)row * s2 + col]; s += v[c];
    }
    #pragma unroll
    for (int o = 32; o; o >>= 1) s += __shfl_xor(s, o);
    if ((tid & 63) == 0) red[tid >> 6] = s;
    __syncthreads();
    const float mean = (red[0] + red[1] + red[2] + red[3]) * (1.f / 768.f);
    float var = 0.f;
    #pragma unroll
    for (int c = 0; c < 3; ++c) { const float d = v[c] - mean; var += d * d; }
    #pragma unroll
    for (int o = 32; o; o >>= 1) var += __shfl_xor(var, o);
    __syncthreads();
    if ((tid & 63) == 0) red[4 + (tid >> 6)] = var;
    __syncthreads();
    const float vt = (red[4] + red[5] + red[6] + red[7]) * (1.f / 768.f);
    const float rs = rsqrtf(vt + 1e-5f);
    #pragma unroll
    for (int c = 0; c < 3; ++c) {
        const int col = tid + 256 * c;
        const float o = (v[c] - mean) * rs * g[col] + bb[col];
        if (dstf) dstf[(size_t)row * sd + col] = o;
        if (dstb) dstb[(size_t)row * sd + col] = f2b(o);
    }
}

// ---------------------------------------------------------------------------
extern "C" void kernel_launch(void* const* d_in, const int* in_sizes, int n_in,
                              void* d_out, int out_size, void* d_ws, size_t ws_size,
                              hipStream_t stream)
{
    (void)in_sizes; (void)n_in; (void)out_size; (void)ws_size;
    const float* lang  = (const float*)d_in[0];
    const float* obj   = (const float*)d_in[1];
    const int* co_mask = (const int*)d_in[4];
    const float* e_wq = (const float*)d_in[5];
    const float* e_bq = (const float*)d_in[6];
    const float* e_wk = (const float*)d_in[7];
    const float* e_bk = (const float*)d_in[8];
    const float* e_wv = (const float*)d_in[9];
    const float* e_bv = (const float*)d_in[10];
    const float* e_wo = (const float*)d_in[11];
    const float* e_bo = (const float*)d_in[12];
    const float* n_wq = (const float*)d_in[13];
    const float* n_bq = (const float*)d_in[14];
    const float* n_wk = (const float*)d_in[15];
    const float* n_bk = (const float*)d_in[16];
    const float* n_wv = (const float*)d_in[17];
    const float* n_bv = (const float*)d_in[18];
    const float* n_wo = (const float*)d_in[19];
    const float* n_bo = (const float*)d_in[20];
    const float* ffn_w1 = (const float*)d_in[21];
    const float* ffn_b1 = (const float*)d_in[22];
    const float* ffn_w2 = (const float*)d_in[23];
    const float* ffn_b2 = (const float*)d_in[24];
    const float* ln_e_g = (const float*)d_in[25];
    const float* ln_e_b = (const float*)d_in[26];
    const float* ln_q_g = (const float*)d_in[27];
    const float* ln_q_b = (const float*)d_in[28];
    const float* ln2_g = (const float*)d_in[29];
    const float* ln2_b = (const float*)d_in[30];
    float* out = (float*)d_out;

    // ---- workspace layout (byte offsets, with lifetime-based aliasing) ----
    char* wsb = (char*)d_ws;
    unsigned short* Wqt   = (unsigned short*)(wsb + 0);         // 2359296 [dead after obj-proj]
    unsigned short* Wlt   = (unsigned short*)(wsb + 2359296);   // 4718592 [dead after lang-proj]
    unsigned short* Wot   = (unsigned short*)(wsb + 7077888);   // 1179648
    unsigned short* W1t   = (unsigned short*)(wsb + 8257536);   // 6291456
    unsigned short* W2t   = (unsigned short*)(wsb + 14548992);  // 3145728
    unsigned short* objb  = (unsigned short*)(wsb + 17694720);  // 1376256 [dead after obj-proj]
    unsigned short* langb = (unsigned short*)(wsb + 19070976);  // 589824  [dead after lang-proj]
    float*          bqc   = (float*)(wsb + 19660800);           // 6144
    float*          blc   = (float*)(wsb + 19666944);           // 12288
    unsigned short* QCb   = (unsigned short*)(wsb + 19679232);  // 2752512 [dead after node_attn]
    unsigned short* LCb   = (unsigned short*)(wsb + 22431744);  // 2359296 [dead after node_attn]
    unsigned short* VWtp  = (unsigned short*)(wsb + 24791040);  // 7077888 [dead after edge]
    unsigned short* Ctxnb = (unsigned short*)(wsb + 31868928);  // 1376256
    unsigned short* Fusedb= (unsigned short*)(wsb + 33245184);  // 2752512  (end: 35997696)
    // aliases (written after their hosts die)
    float* NodeP = (float*)(wsb + 0);          // 2752512 over Wqt/Wlt
    float* Edge  = (float*)(wsb + 2752512);    // 2555904 over Wlt
    float* S2e   = (float*)(wsb + 17694720);   // 958464 over objb
    float* Tb    = (float*)(wsb + 18653184);   // 18432
    unsigned short* H1b = (unsigned short*)(wsb + 19679232);  // 3670016 over QCb/LCb
    float* H2    = (float*)(wsb + 24791040);   // 2752512 over VWt

    dim3 blk(256);
    // 1-2: pack
    packw_kernel<<<dim3(3072, 9), blk, 0, stream>>>(
        e_wq, n_wq, e_wk, e_wv, n_wk, n_wv, n_wo, ffn_w1, ffn_w2,
        Wqt, Wqt + 768 * 768, Wlt, Wlt + 768 * 768, Wlt + 2 * 768 * 768,
        Wlt + 3 * 768 * 768, Wot, W1t, W2t);
    packa_kernel<<<dim3(3859), blk, 0, stream>>>(obj, lang, n_bq, e_bk, e_bv, n_bk, n_bv,
                                                 objb, langb, bqc, blc);
    // 3-4: fused projections
    gemm_tn<<<dim3(12, 7), blk, 0, stream>>>(objb, 768, Wqt, bqc, nullptr, QCb, 1536, 832, 768, 0);
    gemm_tn<<<dim3(24, 3), blk, 0, stream>>>(langb, 768, Wlt, blc, nullptr, LCb, 3072, 384, 768, 0);
    // 5-7: edge precompute + node branch pieces
    vw_kernel<<<192, blk, 0, stream>>>(LCb, e_wo, VWtp);
    s2e_kernel<<<192, blk, 0, stream>>>(QCb, LCb, e_bq, S2e, Tb);
    node_attn_kernel<<<192, blk, 0, stream>>>(QCb, LCb, co_mask, Ctxnb);
    // 8: node output projection
    gemm_tn<<<dim3(6, 7), blk, 0, stream>>>(Ctxnb, 768, Wot, n_bo, NodeP, nullptr, 768, 832, 768, 0);
    // 9: edge main
    edge_kernel<<<dim3(832, 6), blk, 0, stream>>>(S2e, Tb, co_mask, VWtp, e_bo, Edge);
    // 10-11: fuse layernorms -> Fusedb (bf16)
    ln_add_kernel<<<832, blk, 0, stream>>>(obj, nullptr, 768, NodeP, 768, ln_q_g, ln_q_b,
                                           nullptr, Fusedb, 1536);
    ln_add_kernel<<<832, blk, 0, stream>>>(obj, nullptr, 768, Edge, 768, ln_e_g, ln_e_b,
                                           nullptr, Fusedb + 768, 1536);
    // 12-13: FFN
    gemm_tn<<<dim3(16, 7), blk, 0, stream>>>(Fusedb, 1536, W1t, ffn_b1, nullptr, H1b, 2048, 832, 1536, 1);
    gemm_tn<<<dim3(6, 7), blk, 0, stream>>>(H1b, 2048, W2t, ffn_b2, H2, nullptr, 768, 832, 2048, 0);
    // 14: final LN
    ln_add_kernel<<<832, blk, 0, stream>>>(nullptr, Fusedb, 1536, H2, 768, ln2_g, ln2_b,
                                           out, nullptr, 768);
}

// Round 3
// 268.345 us; speedup vs baseline: 1.9474x; 1.5473x over previous
//
#include <hip/hip_runtime.h>
#include <math.h>

#define NOBJ 52
#define LL 24
#define NHEAD 12

typedef __attribute__((ext_vector_type(8))) short bf16x8;
typedef __attribute__((ext_vector_type(4))) float f32x4;
typedef __attribute__((ext_vector_type(4))) unsigned int u32x4;

__device__ __forceinline__ unsigned short f2b(float x) {
    union { float f; unsigned int u; } v; v.f = x;
    unsigned int r = v.u + 0x7fffu + ((v.u >> 16) & 1u);
    return (unsigned short)(r >> 16);
}
__device__ __forceinline__ float b2f(unsigned short u) {
    union { unsigned int u; float f; } v; v.u = ((unsigned int)u) << 16;
    return v.f;
}
__device__ __forceinline__ unsigned int pack2(float a, float b) {
    return (unsigned int)f2b(a) | ((unsigned int)f2b(b) << 16);
}
__device__ __forceinline__ f32x4 mfma16(bf16x8 a, bf16x8 b, f32x4 c) {
    return __builtin_amdgcn_mfma_f32_16x16x32_bf16(a, b, c, 0, 0, 0);
}
__device__ __forceinline__ void gl_lds16(const void* g, void* lds) {
    __builtin_amdgcn_global_load_lds(
        (const __attribute__((address_space(1))) unsigned int*)g,
        (__attribute__((address_space(3))) unsigned int*)lds, 16, 0, 0);
}

// ---------------------------------------------------------------------------
// pack_all: 9 weight transposes (f32 [K][N] -> bf16 [N][K]) + activation pack
// ---------------------------------------------------------------------------
__global__ __launch_bounds__(256)
void pack_all_kernel(const float* s0, const float* s1, const float* s2,
                     const float* s3, const float* s4, const float* s5,
                     const float* s6, const float* s7, const float* s8,
                     unsigned short* d0, unsigned short* d1, unsigned short* d2,
                     unsigned short* d3, unsigned short* d4, unsigned short* d5,
                     unsigned short* d6, unsigned short* d7, unsigned short* d8,
                     const float* obj, const float* lang, const float* n_bq,
                     const float* e_bk, const float* e_bv,
                     const float* n_bk, const float* n_bv,
                     unsigned short* objb, unsigned short* langb,
                     float* bqc, float* blc)
{
    __shared__ float ts[32][33];
    const int bid = blockIdx.x;
    const int tid = threadIdx.x;
    if (bid < 8640) {
        int job, t;
        if (bid < 4032)      { job = bid / 576; t = bid % 576; }
        else if (bid < 7104) { job = 7; t = bid - 4032; }
        else                 { job = 8; t = bid - 7104; }
        const float* src; unsigned short* dst; int K, N;
        if      (job == 0) { src = s0; dst = d0; K = 768;  N = 768;  }
        else if (job == 1) { src = s1; dst = d1; K = 768;  N = 768;  }
        else if (job == 2) { src = s2; dst = d2; K = 768;  N = 768;  }
        else if (job == 3) { src = s3; dst = d3; K = 768;  N = 768;  }
        else if (job == 4) { src = s4; dst = d4; K = 768;  N = 768;  }
        else if (job == 5) { src = s5; dst = d5; K = 768;  N = 768;  }
        else if (job == 6) { src = s6; dst = d6; K = 768;  N = 768;  }
        else if (job == 7) { src = s7; dst = d7; K = 1536; N = 2048; }
        else               { src = s8; dst = d8; K = 2048; N = 768;  }
        const int ntk = K >> 5;
        const int k0 = (t % ntk) << 5, n0 = (t / ntk) << 5;
        const int tx = tid & 31, ty = tid >> 5;
        #pragma unroll
        for (int i = 0; i < 4; ++i)
            ts[ty + 8 * i][tx] = src[(size_t)(k0 + ty + 8 * i) * N + n0 + tx];
        __syncthreads();
        #pragma unroll
        for (int i = 0; i < 4; ++i)
            dst[(size_t)(n0 + ty + 8 * i) * K + k0 + tx] = f2b(ts[tx][ty + 8 * i]);
    } else {
        const int i = (bid - 8640) * 256 + tid;
        const int T0 = 896 * 768, T1 = T0 + 384 * 768, T2 = T1 + 1536;
        if (i < T0) {
            objb[i] = (i < 832 * 768) ? f2b(obj[i]) : (unsigned short)0;
        } else if (i < T1) {
            int j = i - T0; langb[j] = f2b(lang[j]);
        } else if (i < T2) {
            int j = i - T1;
            bqc[j] = (j < 768) ? 0.f : n_bq[j - 768];
        } else {
            int j = i - T2;
            int s = j / 768, c = j % 768;
            const float* p = (s == 0) ? e_bk : (s == 1) ? e_bv : (s == 2) ? n_bk : n_bv;
            blc[j] = p[c];
        }
    }
}

// ---------------------------------------------------------------------------
// GEMM: C[M,N] = A[M,K](bf16) @ Bt[N,K]^T + bias (+relu). 128x128 tile, BK=64,
// dbuf global_load_lds, chunk-XOR LDS swizzle. Up to 2 jobs per launch.
// ---------------------------------------------------------------------------
struct GemmJob {
    const unsigned short* A; const unsigned short* Bt; const float* bias;
    float* C; unsigned short* Cb;
    int lda, ldc, M, K, nbx, nb, relu;
};

__global__ __launch_bounds__(256)
void gemm_tn(GemmJob j0, GemmJob j1)
{
    __shared__ __align__(16) unsigned short As[2][128 * 64];
    __shared__ __align__(16) unsigned short Bs[2][128 * 64];
    GemmJob J = j0;
    int bid = blockIdx.x;
    if (bid >= j0.nb) { bid -= j0.nb; J = j1; }
    const int bx = bid % J.nbx, by = bid / J.nbx;
    const int n0 = bx * 128, m0 = by * 128;
    const int tid = threadIdx.x;
    const int lane = tid & 63;
    const int w = tid >> 6, wr = w >> 1, wc = w & 1;
    const int lr = lane & 15, lk = lane >> 4;

    f32x4 acc[4][4] = {};
    const int NT = J.K >> 6;

    const unsigned short* Ab = J.A;
    const unsigned short* Bb = J.Bt;
    const int lda = J.lda, K = J.K;

    #pragma unroll
    for (int q = 0; q < 4; ++q) {       // stage t=0
        int chunk = q * 256 + tid;
        int row = chunk >> 3, kp = chunk & 7;
        int kl = (kp ^ (row & 7)) * 8;
        gl_lds16(Ab + (size_t)(m0 + row) * lda + kl, &As[0][chunk * 8]);
        gl_lds16(Bb + (size_t)(n0 + row) * K + kl, &Bs[0][chunk * 8]);
    }
    __syncthreads();

    for (int t = 0; t < NT; ++t) {
        const int cur = t & 1;
        if (t + 1 < NT) {
            const int k0 = (t + 1) << 6;
            #pragma unroll
            for (int q = 0; q < 4; ++q) {
                int chunk = q * 256 + tid;
                int row = chunk >> 3, kp = chunk & 7;
                int kl = k0 + (kp ^ (row & 7)) * 8;
                gl_lds16(Ab + (size_t)(m0 + row) * lda + kl, &As[cur ^ 1][chunk * 8]);
                gl_lds16(Bb + (size_t)(n0 + row) * K + kl, &Bs[cur ^ 1][chunk * 8]);
            }
        }
        #pragma unroll
        for (int kk = 0; kk < 2; ++kk) {
            bf16x8 af[4], bv[4];
            #pragma unroll
            for (int mt = 0; mt < 4; ++mt) {
                int row = wr * 64 + mt * 16 + lr;
                int pc = (kk * 4 + lk) ^ (row & 7);
                af[mt] = *(const bf16x8*)&As[cur][row * 64 + pc * 8];
            }
            #pragma unroll
            for (int nt = 0; nt < 4; ++nt) {
                int col = wc * 64 + nt * 16 + lr;
                int pc = (kk * 4 + lk) ^ (col & 7);
                bv[nt] = *(const bf16x8*)&Bs[cur][col * 64 + pc * 8];
            }
            #pragma unroll
            for (int mt = 0; mt < 4; ++mt)
                #pragma unroll
                for (int nt = 0; nt < 4; ++nt)
                    acc[mt][nt] = mfma16(af[mt], bv[nt], acc[mt][nt]);
        }
        __syncthreads();
    }

    #pragma unroll
    for (int mt = 0; mt < 4; ++mt) {
        #pragma unroll
        for (int nt = 0; nt < 4; ++nt) {
            const int col = n0 + wc * 64 + nt * 16 + lr;
            const float bvv = J.bias ? J.bias[col] : 0.f;
            #pragma unroll
            for (int r = 0; r < 4; ++r) {
                const int row = m0 + wr * 64 + mt * 16 + lk * 4 + r;
                if (row < J.M) {
                    float v = acc[mt][nt][r] + bvv;
                    if (J.relu) v = fmaxf(v, 0.f);
                    if (J.C)  J.C[(size_t)row * J.ldc + col] = v;
                    if (J.Cb) J.Cb[(size_t)row * J.ldc + col] = f2b(v);
                }
            }
        }
    }
}

// ---------------------------------------------------------------------------
// mid: job0 = VW precompute, job1 = S2e/T scores, job2 = node attention
// grid 576 blocks (192 per job), 256 thr
// ---------------------------------------------------------------------------
__global__ __launch_bounds__(256)
void mid_kernel(const unsigned short* __restrict__ QCb,
                const unsigned short* __restrict__ LCb,
                const float* __restrict__ e_wo, const float* __restrict__ e_bq,
                const int* __restrict__ co_mask,
                unsigned short* __restrict__ VWt,
                float* __restrict__ S2e, float* __restrict__ Tb,
                unsigned short* __restrict__ Ctxnb)
{
    __shared__ float sA[52][68];
    __shared__ float sB[24][68];
    __shared__ float sC[24][68];
    __shared__ unsigned char scm[24 * 52];
    const int job = blockIdx.x / 192;
    const int b = blockIdx.x % 192;
    const int n = b / NHEAD, h = b % NHEAD;
    const int tid = threadIdx.x;

    if (job == 0) {
        // ---- VW: per (n,h): Ve[24x64] @ Wo_h[64x768] -> swizzled bf16 layout
        for (int p = tid; p < 24 * 64; p += 256) {
            int l = p >> 6, d = p & 63;
            sB[l][d] = b2f(LCb[(size_t)(n * 24 + l) * 3072 + 768 + h * 64 + d]);
        }
        __syncthreads();
        unsigned short* VWn = VWt + (size_t)n * 221184;
        for (int c = 0; c < 3; ++c) {
            const int d = c * 256 + tid;
            float acc[24] = {};
            for (int dp = 0; dp < 64; ++dp) {
                float wv = e_wo[(size_t)(h * 64 + dp) * 768 + d];
                #pragma unroll
                for (int l = 0; l < 24; ++l) acc[l] += sB[l][dp] * wv;
            }
            #pragma unroll
            for (int cc = 0; cc < 3; ++cc) {
                u32x4 u;
                #pragma unroll
                for (int m = 0; m < 4; ++m)
                    u[m] = pack2(acc[cc * 8 + 2 * m], acc[cc * 8 + 2 * m + 1]);
                int kc = h * 3 + cc;
                int ks = kc >> 2, kk8 = (kc & 3) ^ (d & 3);
                *(u32x4*)(VWn + (size_t)ks * 24576 + d * 32 + kk8 * 8) = u;
            }
        }
    } else if (job == 1) {
        // ---- S2e[n,h,q,l] = Qe.Ke ; T[n,h,l] = e_bq_h.Ke
        for (int p = tid; p < 52 * 64; p += 256) {
            int q = p >> 6, d = p & 63;
            sA[q][d] = b2f(QCb[(size_t)(n * 52 + q) * 1536 + h * 64 + d]);
        }
        for (int p = tid; p < 24 * 64; p += 256) {
            int l = p >> 6, d = p & 63;
            sB[l][d] = b2f(LCb[(size_t)(n * 24 + l) * 3072 + h * 64 + d]);
        }
        __syncthreads();
        for (int p = tid; p < 52 * 24; p += 256) {
            int q = p / 24, l = p % 24;
            float s = 0.f;
            #pragma unroll
            for (int d = 0; d < 64; ++d) s += sA[q][d] * sB[l][d];
            S2e[((size_t)(n * NHEAD + h) * 52 + q) * 24 + l] = s;
        }
        if (tid < 24) {
            float s = 0.f;
            #pragma unroll
            for (int d = 0; d < 64; ++d) s += e_bq[h * 64 + d] * sB[tid][d];
            Tb[((size_t)n * NHEAD + h) * 24 + tid] = s;
        }
    } else {
        // ---- node attention: 4 lanes per query
        for (int p = tid; p < 24 * 64; p += 256) {
            int l = p >> 6, d = p & 63;
            const unsigned short* Lr = LCb + (size_t)(n * 24 + l) * 3072;
            sB[l][d] = b2f(Lr[1536 + h * 64 + d]);
            sC[l][d] = b2f(Lr[2304 + h * 64 + d]);
        }
        for (int p = tid; p < 24 * 52; p += 256)
            scm[p] = (unsigned char)(co_mask[(size_t)n * 24 * 52 + p] > 0);
        __syncthreads();
        const int q = tid >> 2;
        const int qe = q < 52 ? q : 51;
        const int g16 = (tid & 3) * 16;
        float qv[16];
        {
            const unsigned short* qp = QCb + (size_t)(n * 52 + qe) * 1536 + 768 + h * 64 + g16;
            #pragma unroll
            for (int c = 0; c < 16; ++c) qv[c] = b2f(qp[c]);
        }
        float lg[24];
        #pragma unroll
        for (int l = 0; l < 24; ++l) {
            float s = 0.f;
            #pragma unroll
            for (int c4 = 0; c4 < 4; ++c4) {
                f32x4 kv = *(const f32x4*)&sB[l][g16 + c4 * 4];
                s += qv[c4 * 4 + 0] * kv[0] + qv[c4 * 4 + 1] * kv[1]
                   + qv[c4 * 4 + 2] * kv[2] + qv[c4 * 4 + 3] * kv[3];
            }
            s += __shfl_xor(s, 1);
            s += __shfl_xor(s, 2);
            lg[l] = s;
        }
        float x[24]; float mx = -1e30f;
        #pragma unroll
        for (int l = 0; l < 24; ++l) {
            float v = scm[l * 52 + qe] ? lg[l] * 0.125f : -1e9f;
            x[l] = v; mx = fmaxf(mx, v);
        }
        float sum = 0.f;
        #pragma unroll
        for (int l = 0; l < 24; ++l) { x[l] = __expf(x[l] - mx); sum += x[l]; }
        const float inv = 1.f / sum;
        f32x4 ctx[4] = {};
        #pragma unroll
        for (int l = 0; l < 24; ++l) {
            const float a = x[l] * inv;
            #pragma unroll
            for (int c4 = 0; c4 < 4; ++c4) {
                f32x4 vv = *(const f32x4*)&sC[l][g16 + c4 * 4];
                ctx[c4] += a * vv;
            }
        }
        if (q < 52) {
            unsigned short* op = Ctxnb + (size_t)(n * 52 + q) * 768 + h * 64 + g16;
            u32x4 o0, o1;
            #pragma unroll
            for (int m = 0; m < 4; ++m) {
                o0[m] = pack2(ctx[m >> 1][(m & 1) * 2], ctx[m >> 1][(m & 1) * 2 + 1]);
                o1[m] = pack2(ctx[2 + (m >> 1)][(m & 1) * 2], ctx[2 + (m >> 1)][(m & 1) * 2 + 1]);
            }
            *(u32x4*)op = o0;
            *(u32x4*)(op + 8) = o1;
        }
    }
}

// ---------------------------------------------------------------------------
// Edge main: block per (n,i) [XCD-swizzled], 512 thr / 8 waves (1x8).
// Softmax once -> Pf[64x288] (row-XOR swz), A@VW over all 768 cols,
// B dbuf-staged from pre-permuted VWt, fused max-over-j + e_bo.
// ---------------------------------------------------------------------------
__global__ __launch_bounds__(512)
void edge_kernel(const float* __restrict__ S2e, const float* __restrict__ Tb,
                 const int* __restrict__ co_mask,
                 const unsigned short* __restrict__ VWt,
                 const float* __restrict__ ebo, float* __restrict__ Edge)
{
    __shared__ __align__(16) unsigned short Pf[64 * 288];
    __shared__ __align__(16) unsigned short Bs[2][768 * 32];
    __shared__ float SiT[288];
    __shared__ unsigned char cmb[24 * 52];
    const int bid = blockIdx.x;
    const int bi = (bid & 7) * 104 + (bid >> 3);   // XCD-contiguous n
    const int n = bi / 52, i = bi % 52;
    const int tid = threadIdx.x;
    const unsigned short* VWn = VWt + (size_t)n * 221184;
    const float* S2n = S2e + (size_t)n * NHEAD * 52 * 24;

    {   // stage B ks=0 early
        const unsigned short* src = VWn;
        #pragma unroll
        for (int q = 0; q < 6; ++q) {
            int chunk = q * 512 + tid;
            gl_lds16(src + chunk * 8, &Bs[0][chunk * 8]);
        }
    }
    for (int p = tid; p < 288; p += 512) {
        int h = p / 24, l = p % 24;
        SiT[p] = S2n[((size_t)h * 52 + i) * 24 + l] + Tb[((size_t)n * NHEAD + h) * 24 + l];
    }
    for (int p = tid; p < 24 * 52; p += 512)
        cmb[p] = (unsigned char)(co_mask[(size_t)n * 24 * 52 + p] > 0);
    __syncthreads();

    // softmax rows (h,j) -> Pf, bf16, row-safe XOR swizzle key (j&3)<<4
    for (int p = tid; p < 624; p += 512) {
        const int h = p / 52, j = p % 52;
        const float* Sj = S2n + ((size_t)h * 52 + j) * 24;
        const float* st = SiT + h * 24;
        float x[24]; float mx = -1e30f;
        #pragma unroll
        for (int l = 0; l < 24; ++l) {
            float v = (st[l] - Sj[l]) * 0.125f;
            v = cmb[l * 52 + j] ? v : -1e9f;
            x[l] = v; mx = fmaxf(mx, v);
        }
        float sum = 0.f;
        #pragma unroll
        for (int l = 0; l < 24; ++l) { float e = __expf(x[l] - mx); x[l] = e; sum += e; }
        const float inv = 1.f / sum;
        unsigned int u[12];
        #pragma unroll
        for (int c = 0; c < 12; ++c) u[c] = pack2(x[2 * c] * inv, x[2 * c + 1] * inv);
        char* base = (char*)Pf;
        const int rb = j * 576 + h * 48;
        const int sw = (j & 3) << 4;
        *(u32x4*)(base + ((rb) ^ sw))      = (u32x4){u[0], u[1], u[2], u[3]};
        *(u32x4*)(base + ((rb + 16) ^ sw)) = (u32x4){u[4], u[5], u[6], u[7]};
        *(u32x4*)(base + ((rb + 32) ^ sw)) = (u32x4){u[8], u[9], u[10], u[11]};
    }
    for (int p = tid; p < 432; p += 512) {          // zero rows 52..63
        const int row = 52 + p / 36, cb = (p % 36) * 16;
        *(u32x4*)((char*)Pf + ((row * 576 + cb) ^ ((row & 3) << 4))) = (u32x4){0, 0, 0, 0};
    }
    __syncthreads();

    const int lane = tid & 63, w = tid >> 6;        // wave w: cols w*96..w*96+95
    const int lr = lane & 15, lk = lane >> 4;
    f32x4 acc[4][6] = {};
    for (int ks = 0; ks < 9; ++ks) {
        const int cur = ks & 1;
        if (ks < 8) {
            const unsigned short* src = VWn + (size_t)(ks + 1) * 24576;
            #pragma unroll
            for (int q = 0; q < 6; ++q) {
                int chunk = q * 512 + tid;
                gl_lds16(src + chunk * 8, &Bs[cur ^ 1][chunk * 8]);
            }
        }
        bf16x8 af[4];
        #pragma unroll
        for (int mt = 0; mt < 4; ++mt) {
            int row = mt * 16 + lr;
            af[mt] = *(const bf16x8*)((char*)Pf +
                      ((row * 576 + ks * 64 + lk * 16) ^ ((row & 3) << 4)));
        }
        #pragma unroll
        for (int nt = 0; nt < 6; ++nt) {
            int col = w * 96 + nt * 16 + lr;
            bf16x8 bv = *(const bf16x8*)&Bs[cur][col * 32 + ((lk ^ (col & 3)) << 3)];
            #pragma unroll
            for (int mt = 0; mt < 4; ++mt)
                acc[mt][nt] = mfma16(af[mt], bv, acc[mt][nt]);
        }
        __syncthreads();
    }

    #pragma unroll
    for (int nt = 0; nt < 6; ++nt) {
        float m = -1e30f;
        #pragma unroll
        for (int mt = 0; mt < 4; ++mt)
            #pragma unroll
            for (int r = 0; r < 4; ++r) {
                int row = mt * 16 + lk * 4 + r;
                if (row < NOBJ) m = fmaxf(m, acc[mt][nt][r]);
            }
        m = fmaxf(m, __shfl_xor(m, 16));
        m = fmaxf(m, __shfl_xor(m, 32));
        if (lk == 0) {
            int col = w * 96 + nt * 16 + lr;
            Edge[(size_t)bi * 768 + col] = m + ebo[col];
        }
    }
}

// ---------------------------------------------------------------------------
// ln_dual: rows 0..831 -> LN(obj+NodeP) to Fusedb[:,0:768];
//          rows 832..1663 -> LN(obj+Edge) to Fusedb[:,768:1536]
// ---------------------------------------------------------------------------
__global__ __launch_bounds__(256)
void ln_dual_kernel(const float* __restrict__ obj,
                    const float* __restrict__ NodeP, const float* __restrict__ EdgeB,
                    const float* __restrict__ gq, const float* __restrict__ bq,
                    const float* __restrict__ ge, const float* __restrict__ be,
                    unsigned short* __restrict__ Fusedb)
{
    __shared__ float red[8];
    const int job = blockIdx.x >= 832;
    const int row = blockIdx.x - (job ? 832 : 0);
    const int tid = threadIdx.x;
    const float* x2 = (job ? EdgeB : NodeP) + (size_t)row * 768;
    const float* x1 = obj + (size_t)row * 768;
    const float* g = job ? ge : gq;
    const float* bb = job ? be : bq;
    float v[3]; float s = 0.f;
    #pragma unroll
    for (int c = 0; c < 3; ++c) {
        const int col = tid + 256 * c;
        v[c] = x1[col] + x2[col]; s += v[c];
    }
    #pragma unroll
    for (int o = 32; o; o >>= 1) s += __shfl_xor(s, o);
    if ((tid & 63) == 0) red[tid >> 6] = s;
    __syncthreads();
    const float mean = (red[0] + red[1] + red[2] + red[3]) * (1.f / 768.f);
    float var = 0.f;
    #pragma unroll
    for (int c = 0; c < 3; ++c) { const float d = v[c] - mean; var += d * d; }
    #pragma unroll
    for (int o = 32; o; o >>= 1) var += __shfl_xor(var, o);
    __syncthreads();
    if ((tid & 63) == 0) red[4 + (tid >> 6)] = var;
    __syncthreads();
    const float vt = (red[4] + red[5] + red[6] + red[7]) * (1.f / 768.f);
    const float rs = rsqrtf(vt + 1e-5f);
    unsigned short* dst = Fusedb + (size_t)row * 1536 + (job ? 768 : 0);
    #pragma unroll
    for (int c = 0; c < 3; ++c) {
        const int col = tid + 256 * c;
        dst[col] = f2b((v[c] - mean) * rs * g[col] + bb[col]);
    }
}

// ---------------------------------------------------------------------------
// final LN: out = LN(Fusedb(bf16, stride 1536) + H2) (f32)
// ---------------------------------------------------------------------------
__global__ __launch_bounds__(256)
void ln2_kernel(const unsigned short* __restrict__ x1b,
                const float* __restrict__ x2,
                const float* __restrict__ g, const float* __restrict__ bb,
                float* __restrict__ dst)
{
    __shared__ float red[8];
    const int row = blockIdx.x, tid = threadIdx.x;
    float v[3]; float s = 0.f;
    #pragma unroll
    for (int c = 0; c < 3; ++c) {
        const int col = tid + 256 * c;
        v[c] = b2f(x1b[(size_t)row * 1536 + col]) + x2[(size_t)row * 768 + col];
        s += v[c];
    }
    #pragma unroll
    for (int o = 32; o; o >>= 1) s += __shfl_xor(s, o);
    if ((tid & 63) == 0) red[tid >> 6] = s;
    __syncthreads();
    const float mean = (red[0] + red[1] + red[2] + red[3]) * (1.f / 768.f);
    float var = 0.f;
    #pragma unroll
    for (int c = 0; c < 3; ++c) { const float d = v[c] - mean; var += d * d; }
    #pragma unroll
    for (int o = 32; o; o >>= 1) var += __shfl_xor(var, o);
    __syncthreads();
    if ((tid & 63) == 0) red[4 + (tid >> 6)] = var;
    __syncthreads();
    const float vt = (red[4] + red[5] + red[6] + red[7]) * (1.f / 768.f);
    const float rs = rsqrtf(vt + 1e-5f);
    #pragma unroll
    for (int c = 0; c < 3; ++c) {
        const int col = tid + 256 * c;
        dst[(size_t)row * 768 + col] = (v[c] - mean) * rs * g[col] + bb[col];
    }
}

// ---------------------------------------------------------------------------
extern "C" void kernel_launch(void* const* d_in, const int* in_sizes, int n_in,
                              void* d_out, int out_size, void* d_ws, size_t ws_size,
                              hipStream_t stream)
{
    (void)in_sizes; (void)n_in; (void)out_size; (void)ws_size;
    const float* lang  = (const float*)d_in[0];
    const float* obj   = (const float*)d_in[1];
    const int* co_mask = (const int*)d_in[4];
    const float* e_wq = (const float*)d_in[5];
    const float* e_bq = (const float*)d_in[6];
    const float* e_wk = (const float*)d_in[7];
    const float* e_bk = (const float*)d_in[8];
    const float* e_wv = (const float*)d_in[9];
    const float* e_bv = (const float*)d_in[10];
    const float* e_wo = (const float*)d_in[11];
    const float* e_bo = (const float*)d_in[12];
    const float* n_wq = (const float*)d_in[13];
    const float* n_bq = (const float*)d_in[14];
    const float* n_wk = (const float*)d_in[15];
    const float* n_bk = (const float*)d_in[16];
    const float* n_wv = (const float*)d_in[17];
    const float* n_bv = (const float*)d_in[18];
    const float* n_wo = (const float*)d_in[19];
    const float* n_bo = (const float*)d_in[20];
    const float* ffn_w1 = (const float*)d_in[21];
    const float* ffn_b1 = (const float*)d_in[22];
    const float* ffn_w2 = (const float*)d_in[23];
    const float* ffn_b2 = (const float*)d_in[24];
    const float* ln_e_g = (const float*)d_in[25];
    const float* ln_e_b = (const float*)d_in[26];
    const float* ln_q_g = (const float*)d_in[27];
    const float* ln_q_b = (const float*)d_in[28];
    const float* ln2_g = (const float*)d_in[29];
    const float* ln2_b = (const float*)d_in[30];
    float* out = (float*)d_out;

    // ---- workspace layout (byte offsets, lifetime-aliased) ----
    char* wsb = (char*)d_ws;
    unsigned short* Wqt   = (unsigned short*)(wsb + 0);         // [1536][768]
    unsigned short* Wlt   = (unsigned short*)(wsb + 2359296);   // [3072][768]
    unsigned short* Wot   = (unsigned short*)(wsb + 7077888);   // [768][768]
    unsigned short* W1t   = (unsigned short*)(wsb + 8257536);   // [2048][1536]
    unsigned short* W2t   = (unsigned short*)(wsb + 14548992);  // [768][2048]
    unsigned short* objb  = (unsigned short*)(wsb + 17694720);  // [896][768]
    unsigned short* langb = (unsigned short*)(wsb + 19070976);  // [384][768]
    float*          bqc   = (float*)(wsb + 19660800);           // [1536]
    float*          blc   = (float*)(wsb + 19666944);           // [3072]
    unsigned short* QCb   = (unsigned short*)(wsb + 19679232);  // [896][1536]
    unsigned short* LCb   = (unsigned short*)(wsb + 22431744);  // [384][3072]
    unsigned short* VWtp  = (unsigned short*)(wsb + 24791040);  // 16*9*24576
    unsigned short* Ctxnb = (unsigned short*)(wsb + 31868928);  // [896][768]
    unsigned short* Fusedb= (unsigned short*)(wsb + 33245184);  // [896][1536]
    // aliases (hosts dead before these are written)
    float* NodeP = (float*)(wsb + 0);          // over Wqt
    float* EdgeB = (float*)(wsb + 2555904);    // over Wlt
    float* S2e   = (float*)(wsb + 17694720);   // over objb
    float* Tb    = (float*)(wsb + 18653184);
    unsigned short* H1b = (unsigned short*)(wsb + 19679232);  // over QCb/LCb
    float* H2    = (float*)(wsb + 24791040);   // over VWt

    dim3 blk(256);
    // 1: pack everything
    pack_all_kernel<<<12498, blk, 0, stream>>>(
        e_wq, n_wq, e_wk, e_wv, n_wk, n_wv, n_wo, ffn_w1, ffn_w2,
        Wqt, Wqt + 768 * 768, Wlt, Wlt + 768 * 768, Wlt + 2 * 768 * 768,
        Wlt + 3 * 768 * 768, Wot, W1t, W2t,
        obj, lang, n_bq, e_bk, e_bv, n_bk, n_bv, objb, langb, bqc, blc);
    // 2: both input projections in one launch
    {
        GemmJob p0 = {objb, Wqt, bqc, nullptr, QCb, 768, 1536, 832, 768, 12, 84, 0};
        GemmJob p1 = {langb, Wlt, blc, nullptr, LCb, 768, 3072, 384, 768, 24, 72, 0};
        gemm_tn<<<156, blk, 0, stream>>>(p0, p1);
    }
    // 3: VW + S2e/T + node attention
    mid_kernel<<<576, blk, 0, stream>>>(QCb, LCb, e_wo, e_bq, co_mask, VWtp, S2e, Tb, Ctxnb);
    // 4: node output projection
    {
        GemmJob p0 = {Ctxnb, Wot, n_bo, NodeP, nullptr, 768, 768, 832, 768, 6, 42, 0};
        GemmJob p1 = {}; p1.nb = 0;
        gemm_tn<<<42, blk, 0, stream>>>(p0, p1);
    }
    // 5: edge main
    edge_kernel<<<832, dim3(512), 0, stream>>>(S2e, Tb, co_mask, VWtp, e_bo, EdgeB);
    // 6: both fuse layernorms
    ln_dual_kernel<<<1664, blk, 0, stream>>>(obj, NodeP, EdgeB, ln_q_g, ln_q_b,
                                             ln_e_g, ln_e_b, Fusedb);
    // 7-8: FFN
    {
        GemmJob p0 = {Fusedb, W1t, ffn_b1, nullptr, H1b, 1536, 2048, 832, 1536, 16, 112, 1};
        GemmJob p1 = {}; p1.nb = 0;
        gemm_tn<<<112, blk, 0, stream>>>(p0, p1);
    }
    {
        GemmJob p0 = {H1b, W2t, ffn_b2, H2, nullptr, 2048, 768, 832, 2048, 6, 42, 0};
        GemmJob p1 = {}; p1.nb = 0;
        gemm_tn<<<42, blk, 0, stream>>>(p0, p1);
    }
    // 9: final LN
    ln2_kernel<<<832, blk, 0, stream>>>(Fusedb, H2, ln2_g, ln2_b, out);
}

// Round 4
// 165.783 us; speedup vs baseline: 3.1522x; 1.6187x over previous
//
#include <hip/hip_runtime.h>
#include <math.h>

#define NOBJ 52
#define LL 24
#define NHEAD 12

typedef __attribute__((ext_vector_type(8))) short bf16x8;
typedef __attribute__((ext_vector_type(4))) float f32x4;
typedef __attribute__((ext_vector_type(4))) unsigned int u32x4;
typedef __attribute__((ext_vector_type(2))) unsigned int u32x2;

__device__ __forceinline__ unsigned short f2b(float x) {
    union { float f; unsigned int u; } v; v.f = x;
    unsigned int r = v.u + 0x7fffu + ((v.u >> 16) & 1u);
    return (unsigned short)(r >> 16);
}
__device__ __forceinline__ float b2f(unsigned short u) {
    union { unsigned int u; float f; } v; v.u = ((unsigned int)u) << 16;
    return v.f;
}
__device__ __forceinline__ unsigned int pack2(float a, float b) {
    return (unsigned int)f2b(a) | ((unsigned int)f2b(b) << 16);
}
__device__ __forceinline__ f32x4 mfma16(bf16x8 a, bf16x8 b, f32x4 c) {
    return __builtin_amdgcn_mfma_f32_16x16x32_bf16(a, b, c, 0, 0, 0);
}
__device__ __forceinline__ void gl_lds16(const void* g, void* lds) {
    __builtin_amdgcn_global_load_lds(
        (const __attribute__((address_space(1))) unsigned int*)g,
        (__attribute__((address_space(3))) unsigned int*)lds, 16, 0, 0);
}

// ---------------------------------------------------------------------------
// pack_all: 10 weight transposes (f32 [K][N] -> bf16 [N][K], 64x64 tiles)
// + vectorized activation/bias pack
// blocks [0,1152): 8 square 768x768 jobs; [1152,1920): ffn_w1; [1920,2304): ffn_w2
// blocks >= 2304: activations (4 f32 per thread)
// ---------------------------------------------------------------------------
__global__ __launch_bounds__(256)
void pack_all_kernel(const float* s0, const float* s1, const float* s2,
                     const float* s3, const float* s4, const float* s5,
                     const float* s6, const float* s7,   // squares (s7=e_wo)
                     const float* s8, const float* s9,   // ffn_w1, ffn_w2
                     unsigned short* d0, unsigned short* d1, unsigned short* d2,
                     unsigned short* d3, unsigned short* d4, unsigned short* d5,
                     unsigned short* d6, unsigned short* d7,
                     unsigned short* d8, unsigned short* d9,
                     const float* obj, const float* lang, const float* n_bq,
                     const float* e_bk, const float* e_bv,
                     const float* n_bk, const float* n_bv,
                     unsigned short* objb, unsigned short* langb,
                     float* bqc, float* blc)
{
    __shared__ float ts[64][65];
    const int bid = blockIdx.x;
    const int tid = threadIdx.x;
    if (bid < 2304) {
        const float* src; unsigned short* dst; int K, N, t;
        if (bid < 1152) {
            const int job = bid / 144; t = bid % 144; K = 768; N = 768;
            if      (job == 0) { src = s0; dst = d0; }
            else if (job == 1) { src = s1; dst = d1; }
            else if (job == 2) { src = s2; dst = d2; }
            else if (job == 3) { src = s3; dst = d3; }
            else if (job == 4) { src = s4; dst = d4; }
            else if (job == 5) { src = s5; dst = d5; }
            else if (job == 6) { src = s6; dst = d6; }
            else               { src = s7; dst = d7; }
        } else if (bid < 1920) { t = bid - 1152; K = 1536; N = 2048; src = s8; dst = d8; }
        else                   { t = bid - 1920; K = 2048; N = 768;  src = s9; dst = d9; }
        const int ntk = K >> 6;
        const int k0 = (t % ntk) << 6, n0 = (t / ntk) << 6;
        const int tx = tid & 63, ty = tid >> 6;
        #pragma unroll
        for (int i = 0; i < 16; ++i) {
            const int row = i * 4 + ty;
            ts[row][tx] = src[(size_t)(k0 + row) * N + n0 + tx];
        }
        __syncthreads();
        #pragma unroll
        for (int i = 0; i < 16; ++i) {
            const int row = i * 4 + ty;
            dst[(size_t)(n0 + row) * K + k0 + tx] = f2b(ts[tx][row]);
        }
    } else {
        const int base = ((bid - 2304) * 256 + tid) * 4;
        const int T0 = 832 * 768, T1 = T0 + 384 * 768, T2 = T1 + 1536, T3 = T2 + 3072;
        if (base >= T3) return;
        if (base < T0) {
            f32x4 v = *(const f32x4*)(obj + base);
            *(u32x2*)(objb + base) = (u32x2){pack2(v[0], v[1]), pack2(v[2], v[3])};
        } else if (base < T1) {
            const int j = base - T0;
            f32x4 v = *(const f32x4*)(lang + j);
            *(u32x2*)(langb + j) = (u32x2){pack2(v[0], v[1]), pack2(v[2], v[3])};
        } else if (base < T2) {
            const int j = base - T1;
            if (j < 768) { *(f32x4*)(bqc + j) = (f32x4){0.f, 0.f, 0.f, 0.f}; }
            else         { *(f32x4*)(bqc + j) = *(const f32x4*)(n_bq + j - 768); }
        } else {
            const int j = base - T2;
            const int s = j / 768, c = j % 768;
            const float* p = (s == 0) ? e_bk : (s == 1) ? e_bv : (s == 2) ? n_bk : n_bv;
            *(f32x4*)(blc + j) = *(const f32x4*)(p + c);
        }
    }
}

// ---------------------------------------------------------------------------
// GEMM: C[M,N] = A[M,K](bf16) @ Bt[N,K]^T + bias (+relu). 64x128 tile, BK=64,
// dbuf global_load_lds, chunk-XOR LDS swizzle. Up to 2 jobs per launch.
// M % 64 == 0, N % 128 == 0, K % 64 == 0.
// ---------------------------------------------------------------------------
struct GemmJob {
    const unsigned short* A; const unsigned short* Bt; const float* bias;
    float* C; unsigned short* Cb;
    int lda, ldc, K, nbx, nb, relu;
};

__global__ __launch_bounds__(256)
void gemm_tn(GemmJob j0, GemmJob j1)
{
    __shared__ __align__(16) unsigned short As[2][64 * 64];
    __shared__ __align__(16) unsigned short Bs[2][128 * 64];
    GemmJob J = j0;
    int bid = blockIdx.x;
    if (bid >= j0.nb) { bid -= j0.nb; J = j1; }
    const int n0 = (bid % J.nbx) * 128, m0 = (bid / J.nbx) * 64;
    const int tid = threadIdx.x;
    const int lane = tid & 63;
    const int w = tid >> 6, wr = w >> 1, wc = w & 1;
    const int lr = lane & 15, lk = lane >> 4;
    const int lda = J.lda, K = J.K;
    const unsigned short* Ab = J.A + (size_t)m0 * lda;
    const unsigned short* Bb = J.Bt + (size_t)n0 * K;

    f32x4 acc[2][4] = {};
    const int NT = K >> 6;

    #pragma unroll
    for (int q = 0; q < 2; ++q) {
        const int c = q * 256 + tid, row = c >> 3, p = (c & 7) ^ (row & 7);
        gl_lds16(Ab + (size_t)row * lda + p * 8, &As[0][c * 8]);
    }
    #pragma unroll
    for (int q = 0; q < 4; ++q) {
        const int c = q * 256 + tid, row = c >> 3, p = (c & 7) ^ (row & 7);
        gl_lds16(Bb + (size_t)row * K + p * 8, &Bs[0][c * 8]);
    }
    __syncthreads();

    for (int t = 0; t < NT; ++t) {
        const int cur = t & 1;
        if (t + 1 < NT) {
            const int k0 = (t + 1) << 6;
            #pragma unroll
            for (int q = 0; q < 2; ++q) {
                const int c = q * 256 + tid, row = c >> 3, p = (c & 7) ^ (row & 7);
                gl_lds16(Ab + (size_t)row * lda + k0 + p * 8, &As[cur ^ 1][c * 8]);
            }
            #pragma unroll
            for (int q = 0; q < 4; ++q) {
                const int c = q * 256 + tid, row = c >> 3, p = (c & 7) ^ (row & 7);
                gl_lds16(Bb + (size_t)row * K + k0 + p * 8, &Bs[cur ^ 1][c * 8]);
            }
        }
        #pragma unroll
        for (int kk = 0; kk < 2; ++kk) {
            bf16x8 af[2], bv[4];
            #pragma unroll
            for (int mt = 0; mt < 2; ++mt) {
                const int row = wr * 32 + mt * 16 + lr;
                const int pc = (kk * 4 + lk) ^ (row & 7);
                af[mt] = *(const bf16x8*)&As[cur][row * 64 + pc * 8];
            }
            #pragma unroll
            for (int nt = 0; nt < 4; ++nt) {
                const int col = wc * 64 + nt * 16 + lr;
                const int pc = (kk * 4 + lk) ^ (col & 7);
                bv[nt] = *(const bf16x8*)&Bs[cur][col * 64 + pc * 8];
            }
            #pragma unroll
            for (int mt = 0; mt < 2; ++mt)
                #pragma unroll
                for (int nt = 0; nt < 4; ++nt)
                    acc[mt][nt] = mfma16(af[mt], bv[nt], acc[mt][nt]);
        }
        __syncthreads();
    }

    #pragma unroll
    for (int mt = 0; mt < 2; ++mt) {
        #pragma unroll
        for (int nt = 0; nt < 4; ++nt) {
            const int col = n0 + wc * 64 + nt * 16 + lr;
            const float bvv = J.bias ? J.bias[col] : 0.f;
            #pragma unroll
            for (int r = 0; r < 4; ++r) {
                const int row = m0 + wr * 32 + mt * 16 + lk * 4 + r;
                float v = acc[mt][nt][r] + bvv;
                if (J.relu) v = fmaxf(v, 0.f);
                if (J.C)  J.C[(size_t)row * J.ldc + col] = v;
                if (J.Cb) J.Cb[(size_t)row * J.ldc + col] = f2b(v);
            }
        }
    }
}

// ---------------------------------------------------------------------------
// mid2: blocks [0,216) = VW MFMA-GEMM per (h, mtile, ntile);
//       [216,408) = S2e/T scores per (n,h);  [408,600) = node attn per (n,h)
// ---------------------------------------------------------------------------
__global__ __launch_bounds__(256)
void mid2_kernel(const unsigned short* __restrict__ QCb,
                 const unsigned short* __restrict__ LCb,
                 const unsigned short* __restrict__ Wet,
                 const float* __restrict__ e_bq,
                 const int* __restrict__ co_mask,
                 unsigned short* __restrict__ VWt,
                 float* __restrict__ S2e, float* __restrict__ Tb,
                 unsigned short* __restrict__ Ctxnb)
{
    __shared__ __align__(16) union USm {
        struct { unsigned short As[8192], Bs[8192]; } g;   // 32 KB (vw gemm)
        unsigned short Ct[128 * 136];                      // 34816 B (vw epilogue)
        struct { float sA[52][68], sB[24][68], sC[24][68]; unsigned char scm[1248]; } s;
    } U;
    const int bid = blockIdx.x;
    const int tid = threadIdx.x;

    if (bid < 216) {
        // ---- VW: C[(n,l),d] = Ve_h[384x64] @ Wo_h[64x768], tile 128x128 ----
        const int h = bid / 18, rm = bid % 18, mt = rm / 6, ntile = rm % 6;
        const int m0 = mt * 128, n0 = ntile * 128;
        const int lane = tid & 63, w = tid >> 6, wr = w >> 1, wc = w & 1;
        const int lr = lane & 15, lk = lane >> 4;
        #pragma unroll
        for (int q = 0; q < 4; ++q) {
            const int c = q * 256 + tid, row = c >> 3, p = (c & 7) ^ (row & 7);
            gl_lds16(LCb + (size_t)(m0 + row) * 3072 + 768 + h * 64 + p * 8, &U.g.As[c * 8]);
            gl_lds16(Wet + (size_t)(n0 + row) * 768 + h * 64 + p * 8, &U.g.Bs[c * 8]);
        }
        __syncthreads();
        f32x4 acc[4][4] = {};
        #pragma unroll
        for (int kk = 0; kk < 2; ++kk) {
            bf16x8 af[4], bv[4];
            #pragma unroll
            for (int m2 = 0; m2 < 4; ++m2) {
                const int row = wr * 64 + m2 * 16 + lr;
                const int pc = (kk * 4 + lk) ^ (row & 7);
                af[m2] = *(const bf16x8*)&U.g.As[row * 64 + pc * 8];
            }
            #pragma unroll
            for (int n2 = 0; n2 < 4; ++n2) {
                const int col = wc * 64 + n2 * 16 + lr;
                const int pc = (kk * 4 + lk) ^ (col & 7);
                bv[n2] = *(const bf16x8*)&U.g.Bs[col * 64 + pc * 8];
            }
            #pragma unroll
            for (int m2 = 0; m2 < 4; ++m2)
                #pragma unroll
                for (int n2 = 0; n2 < 4; ++n2)
                    acc[m2][n2] = mfma16(af[m2], bv[n2], acc[m2][n2]);
        }
        __syncthreads();
        // write C (bf16) to transpose buffer
        #pragma unroll
        for (int m2 = 0; m2 < 4; ++m2)
            #pragma unroll
            for (int n2 = 0; n2 < 4; ++n2) {
                const int col = wc * 64 + n2 * 16 + lr;
                #pragma unroll
                for (int r = 0; r < 4; ++r) {
                    const int row = wr * 64 + m2 * 16 + lk * 4 + r;
                    U.Ct[row * 136 + col] = f2b(acc[m2][n2][r]);
                }
            }
        __syncthreads();
        // swizzled 16B stores: chunk = 8 consecutive l at fixed d
        #pragma unroll
        for (int q = 0; q < 8; ++q) {
            const int item = q * 256 + tid;
            const int dl = item & 127, kg = item >> 7;
            const int m = m0 + kg * 8;
            const int nn = m / 24, l0 = m % 24;
            const int kc = (h * 24 + l0) >> 3;
            const int ks = kc >> 2;
            const int dg = n0 + dl;
            const int kpos = (kc & 3) ^ (dg & 3);
            u32x4 uu;
            #pragma unroll
            for (int e = 0; e < 4; ++e)
                uu[e] = (unsigned int)U.Ct[(kg * 8 + 2 * e) * 136 + dl]
                      | ((unsigned int)U.Ct[(kg * 8 + 2 * e + 1) * 136 + dl] << 16);
            *(u32x4*)(VWt + (size_t)nn * 221184 + ks * 24576 + dg * 32 + kpos * 8) = uu;
        }
    } else if (bid < 408) {
        // ---- S2e[n,h,q,l] = Qe.Ke ; T[n,h,l] = e_bq_h.Ke ----
        const int b = bid - 216;
        const int n = b / NHEAD, h = b % NHEAD;
        for (int p = tid; p < 52 * 64; p += 256) {
            const int q = p >> 6, d = p & 63;
            U.s.sA[q][d] = b2f(QCb[(size_t)(n * 52 + q) * 1536 + h * 64 + d]);
        }
        for (int p = tid; p < 24 * 64; p += 256) {
            const int l = p >> 6, d = p & 63;
            U.s.sB[l][d] = b2f(LCb[(size_t)(n * 24 + l) * 3072 + h * 64 + d]);
        }
        __syncthreads();
        for (int p = tid; p < 52 * 24; p += 256) {
            const int q = p / 24, l = p % 24;
            float s = 0.f;
            #pragma unroll
            for (int d = 0; d < 64; ++d) s += U.s.sA[q][d] * U.s.sB[l][d];
            S2e[((size_t)(n * NHEAD + h) * 52 + q) * 24 + l] = s;
        }
        if (tid < 24) {
            float s = 0.f;
            #pragma unroll
            for (int d = 0; d < 64; ++d) s += e_bq[h * 64 + d] * U.s.sB[tid][d];
            Tb[((size_t)n * NHEAD + h) * 24 + tid] = s;
        }
    } else {
        // ---- node attention: 4 lanes per query ----
        const int b = bid - 408;
        const int n = b / NHEAD, h = b % NHEAD;
        for (int p = tid; p < 24 * 64; p += 256) {
            const int l = p >> 6, d = p & 63;
            const unsigned short* Lr = LCb + (size_t)(n * 24 + l) * 3072;
            U.s.sB[l][d] = b2f(Lr[1536 + h * 64 + d]);
            U.s.sC[l][d] = b2f(Lr[2304 + h * 64 + d]);
        }
        for (int p = tid; p < 24 * 52; p += 256)
            U.s.scm[p] = (unsigned char)(co_mask[(size_t)n * 24 * 52 + p] > 0);
        __syncthreads();
        const int q = tid >> 2;
        const int qe = q < 52 ? q : 51;
        const int g16 = (tid & 3) * 16;
        float qv[16];
        {
            const unsigned short* qp = QCb + (size_t)(n * 52 + qe) * 1536 + 768 + h * 64 + g16;
            #pragma unroll
            for (int c = 0; c < 16; ++c) qv[c] = b2f(qp[c]);
        }
        float lg[24];
        #pragma unroll
        for (int l = 0; l < 24; ++l) {
            float s = 0.f;
            #pragma unroll
            for (int c4 = 0; c4 < 4; ++c4) {
                f32x4 kv = *(const f32x4*)&U.s.sB[l][g16 + c4 * 4];
                s += qv[c4 * 4 + 0] * kv[0] + qv[c4 * 4 + 1] * kv[1]
                   + qv[c4 * 4 + 2] * kv[2] + qv[c4 * 4 + 3] * kv[3];
            }
            s += __shfl_xor(s, 1);
            s += __shfl_xor(s, 2);
            lg[l] = s;
        }
        float x[24]; float mx = -1e30f;
        #pragma unroll
        for (int l = 0; l < 24; ++l) {
            const float v = U.s.scm[l * 52 + qe] ? lg[l] * 0.125f : -1e9f;
            x[l] = v; mx = fmaxf(mx, v);
        }
        float sum = 0.f;
        #pragma unroll
        for (int l = 0; l < 24; ++l) { x[l] = __expf(x[l] - mx); sum += x[l]; }
        const float inv = 1.f / sum;
        f32x4 ctx[4] = {};
        #pragma unroll
        for (int l = 0; l < 24; ++l) {
            const float a = x[l] * inv;
            #pragma unroll
            for (int c4 = 0; c4 < 4; ++c4) {
                f32x4 vv = *(const f32x4*)&U.s.sC[l][g16 + c4 * 4];
                ctx[c4] += a * vv;
            }
        }
        if (q < 52) {
            unsigned short* op = Ctxnb + (size_t)(n * 52 + q) * 768 + h * 64 + g16;
            u32x4 o0, o1;
            #pragma unroll
            for (int m = 0; m < 4; ++m) {
                o0[m] = pack2(ctx[m >> 1][(m & 1) * 2], ctx[m >> 1][(m & 1) * 2 + 1]);
                o1[m] = pack2(ctx[2 + (m >> 1)][(m & 1) * 2], ctx[2 + (m >> 1)][(m & 1) * 2 + 1]);
            }
            *(u32x4*)op = o0;
            *(u32x4*)(op + 8) = o1;
        }
    }
}

// ---------------------------------------------------------------------------
// Edge main v3: block per (n, i-pair, d-half) [XCD-swizzled], 512 thr / 8 waves.
// Two i's share all staged B tiles (halves VW L2 traffic). Wave w: i = w>>2,
// 96 cols. Softmax once per i into Pf[2] (row-XOR swz); fused max-over-j + e_bo.
// ---------------------------------------------------------------------------
__global__ __launch_bounds__(512)
void edge_kernel(const float* __restrict__ S2e, const float* __restrict__ Tb,
                 const int* __restrict__ co_mask,
                 const unsigned short* __restrict__ VWt,
                 const float* __restrict__ ebo, float* __restrict__ Edge)
{
    __shared__ __align__(16) unsigned short Pf[2][64 * 288];
    __shared__ __align__(16) unsigned short Bs[2][384 * 32];
    __shared__ float SiT[2][288];
    __shared__ unsigned char cmb[1248];
    const int bid = blockIdx.x;
    const int L = (bid & 7) * 104 + (bid >> 3);   // XCD-contiguous logical id
    const int n = L / 52;
    const int rr = L % 52;
    const int ip = rr >> 1, dh = rr & 1;
    const int i0 = ip * 2;
    const int tid = threadIdx.x;
    const unsigned short* VWn = VWt + (size_t)n * 221184 + dh * 12288;
    const float* S2n = S2e + (size_t)n * NHEAD * 52 * 24;

    // stage B ks=0 early (overlaps softmax)
    #pragma unroll
    for (int q = 0; q < 3; ++q) {
        const int c = q * 512 + tid;
        gl_lds16(VWn + c * 8, &Bs[0][c * 8]);
    }
    // zero pad rows 52..63 of both Pf buffers
    for (int p = tid; p < 864; p += 512) {
        const int buf = p / 432, qq = p % 432;
        const int row = 52 + qq / 36, cb = (qq % 36) * 16;
        *(u32x4*)((char*)&Pf[buf][0] + ((row * 576 + cb) ^ ((row & 3) << 4))) = (u32x4){0, 0, 0, 0};
    }
    for (int p = tid; p < 576; p += 512) {
        const int ii = p >= 288 ? 1 : 0;
        const int rl = p - ii * 288;
        const int h = rl / 24, l = rl % 24;
        SiT[ii][rl] = S2n[((size_t)h * 52 + i0 + ii) * 24 + l]
                    + Tb[((size_t)n * NHEAD + h) * 24 + l];
    }
    for (int p = tid; p < 1248; p += 512)
        cmb[p] = (unsigned char)(co_mask[(size_t)n * 1248 + p] > 0);
    __syncthreads();

    // softmax rows (ii, h, j) -> Pf[ii], bf16, row-XOR swizzle (j&3)<<4
    for (int p = tid; p < 1248; p += 512) {
        const int ii = p >= 624 ? 1 : 0;
        const int rl = p - ii * 624;
        const int h = rl / 52, j = rl % 52;
        const float* Sj = S2n + ((size_t)h * 52 + j) * 24;
        const float* st = &SiT[ii][h * 24];
        float x[24]; float mx = -1e30f;
        #pragma unroll
        for (int l = 0; l < 24; ++l) {
            float v = (st[l] - Sj[l]) * 0.125f;
            v = cmb[l * 52 + j] ? v : -1e9f;
            x[l] = v; mx = fmaxf(mx, v);
        }
        float sum = 0.f;
        #pragma unroll
        for (int l = 0; l < 24; ++l) { const float e = __expf(x[l] - mx); x[l] = e; sum += e; }
        const float inv = 1.f / sum;
        unsigned int u[12];
        #pragma unroll
        for (int c = 0; c < 12; ++c) u[c] = pack2(x[2 * c] * inv, x[2 * c + 1] * inv);
        char* base = (char*)&Pf[ii][0];
        const int rb = j * 576 + h * 48;
        const int sw = (j & 3) << 4;
        *(u32x4*)(base + ((rb) ^ sw))      = (u32x4){u[0], u[1], u[2], u[3]};
        *(u32x4*)(base + ((rb + 16) ^ sw)) = (u32x4){u[4], u[5], u[6], u[7]};
        *(u32x4*)(base + ((rb + 32) ^ sw)) = (u32x4){u[8], u[9], u[10], u[11]};
    }
    __syncthreads();

    const int lane = tid & 63, w = tid >> 6;
    const int iw = w >> 2, cg = (w & 3) * 96;
    const int lr = lane & 15, lk = lane >> 4;
    f32x4 acc[4][6] = {};
    for (int ks = 0; ks < 9; ++ks) {
        const int cur = ks & 1;
        if (ks < 8) {
            const unsigned short* src = VWn + (size_t)(ks + 1) * 24576;
            #pragma unroll
            for (int q = 0; q < 3; ++q) {
                const int c = q * 512 + tid;
                gl_lds16(src + c * 8, &Bs[cur ^ 1][c * 8]);
            }
        }
        bf16x8 af[4];
        #pragma unroll
        for (int mt = 0; mt < 4; ++mt) {
            const int row = mt * 16 + lr;
            af[mt] = *(const bf16x8*)((char*)&Pf[iw][0] +
                      ((row * 576 + ks * 64 + lk * 16) ^ ((row & 3) << 4)));
        }
        #pragma unroll
        for (int nt = 0; nt < 6; ++nt) {
            const int cl = cg + nt * 16 + lr;
            bf16x8 bv = *(const bf16x8*)&Bs[cur][cl * 32 + ((lk ^ (cl & 3)) << 3)];
            #pragma unroll
            for (int mt = 0; mt < 4; ++mt)
                acc[mt][nt] = mfma16(af[mt], bv, acc[mt][nt]);
        }
        __syncthreads();
    }

    #pragma unroll
    for (int nt = 0; nt < 6; ++nt) {
        float m = -1e30f;
        #pragma unroll
        for (int mt = 0; mt < 4; ++mt)
            #pragma unroll
            for (int r = 0; r < 4; ++r) {
                const int row = mt * 16 + lk * 4 + r;
                if (row < NOBJ) m = fmaxf(m, acc[mt][nt][r]);
            }
        m = fmaxf(m, __shfl_xor(m, 16));
        m = fmaxf(m, __shfl_xor(m, 32));
        if (lk == 0) {
            const int col = dh * 384 + cg + nt * 16 + lr;
            Edge[(size_t)(n * 52 + i0 + iw) * 768 + col] = m + ebo[col];
        }
    }
}

// ---------------------------------------------------------------------------
// ln_dual: rows 0..831 -> LN(obj+NodeP) to Fusedb[:,0:768];
//          rows 832..1663 -> LN(obj+Edge) to Fusedb[:,768:1536]
// ---------------------------------------------------------------------------
__global__ __launch_bounds__(256)
void ln_dual_kernel(const float* __restrict__ obj,
                    const float* __restrict__ NodeP, const float* __restrict__ EdgeB,
                    const float* __restrict__ gq, const float* __restrict__ bq,
                    const float* __restrict__ ge, const float* __restrict__ be,
                    unsigned short* __restrict__ Fusedb)
{
    __shared__ float red[8];
    const int job = blockIdx.x >= 832;
    const int row = blockIdx.x - (job ? 832 : 0);
    const int tid = threadIdx.x;
    const float* x2 = (job ? EdgeB : NodeP) + (size_t)row * 768;
    const float* x1 = obj + (size_t)row * 768;
    const float* g = job ? ge : gq;
    const float* bb = job ? be : bq;
    float v[3]; float s = 0.f;
    #pragma unroll
    for (int c = 0; c < 3; ++c) {
        const int col = tid + 256 * c;
        v[c] = x1[col] + x2[col]; s += v[c];
    }
    #pragma unroll
    for (int o = 32; o; o >>= 1) s += __shfl_xor(s, o);
    if ((tid & 63) == 0) red[tid >> 6] = s;
    __syncthreads();
    const float mean = (red[0] + red[1] + red[2] + red[3]) * (1.f / 768.f);
    float var = 0.f;
    #pragma unroll
    for (int c = 0; c < 3; ++c) { const float d = v[c] - mean; var += d * d; }
    #pragma unroll
    for (int o = 32; o; o >>= 1) var += __shfl_xor(var, o);
    __syncthreads();
    if ((tid & 63) == 0) red[4 + (tid >> 6)] = var;
    __syncthreads();
    const float vt = (red[4] + red[5] + red[6] + red[7]) * (1.f / 768.f);
    const float rs = rsqrtf(vt + 1e-5f);
    unsigned short* dst = Fusedb + (size_t)row * 1536 + (job ? 768 : 0);
    #pragma unroll
    for (int c = 0; c < 3; ++c) {
        const int col = tid + 256 * c;
        dst[col] = f2b((v[c] - mean) * rs * g[col] + bb[col]);
    }
}

// ---------------------------------------------------------------------------
// final LN: out = LN(Fusedb(bf16, stride 1536) + H2) (f32)
// ---------------------------------------------------------------------------
__global__ __launch_bounds__(256)
void ln2_kernel(const unsigned short* __restrict__ x1b,
                const float* __restrict__ x2,
                const float* __restrict__ g, const float* __restrict__ bb,
                float* __restrict__ dst)
{
    __shared__ float red[8];
    const int row = blockIdx.x, tid = threadIdx.x;
    float v[3]; float s = 0.f;
    #pragma unroll
    for (int c = 0; c < 3; ++c) {
        const int col = tid + 256 * c;
        v[c] = b2f(x1b[(size_t)row * 1536 + col]) + x2[(size_t)row * 768 + col];
        s += v[c];
    }
    #pragma unroll
    for (int o = 32; o; o >>= 1) s += __shfl_xor(s, o);
    if ((tid & 63) == 0) red[tid >> 6] = s;
    __syncthreads();
    const float mean = (red[0] + red[1] + red[2] + red[3]) * (1.f / 768.f);
    float var = 0.f;
    #pragma unroll
    for (int c = 0; c < 3; ++c) { const float d = v[c] - mean; var += d * d; }
    #pragma unroll
    for (int o = 32; o; o >>= 1) var += __shfl_xor(var, o);
    __syncthreads();
    if ((tid & 63) == 0) red[4 + (tid >> 6)] = var;
    __syncthreads();
    const float vt = (red[4] + red[5] + red[6] + red[7]) * (1.f / 768.f);
    const float rs = rsqrtf(vt + 1e-5f);
    #pragma unroll
    for (int c = 0; c < 3; ++c) {
        const int col = tid + 256 * c;
        dst[(size_t)row * 768 + col] = (v[c] - mean) * rs * g[col] + bb[col];
    }
}

// ---------------------------------------------------------------------------
extern "C" void kernel_launch(void* const* d_in, const int* in_sizes, int n_in,
                              void* d_out, int out_size, void* d_ws, size_t ws_size,
                              hipStream_t stream)
{
    (void)in_sizes; (void)n_in; (void)out_size; (void)ws_size;
    const float* lang  = (const float*)d_in[0];
    const float* obj   = (const float*)d_in[1];
    const int* co_mask = (const int*)d_in[4];
    const float* e_wq = (const float*)d_in[5];
    const float* e_bq = (const float*)d_in[6];
    const float* e_wk = (const float*)d_in[7];
    const float* e_bk = (const float*)d_in[8];
    const float* e_wv = (const float*)d_in[9];
    const float* e_bv = (const float*)d_in[10];
    const float* e_wo = (const float*)d_in[11];
    const float* e_bo = (const float*)d_in[12];
    const float* n_wq = (const float*)d_in[13];
    const float* n_bq = (const float*)d_in[14];
    const float* n_wk = (const float*)d_in[15];
    const float* n_bk = (const float*)d_in[16];
    const float* n_wv = (const float*)d_in[17];
    const float* n_bv = (const float*)d_in[18];
    const float* n_wo = (const float*)d_in[19];
    const float* n_bo = (const float*)d_in[20];
    const float* ffn_w1 = (const float*)d_in[21];
    const float* ffn_b1 = (const float*)d_in[22];
    const float* ffn_w2 = (const float*)d_in[23];
    const float* ffn_b2 = (const float*)d_in[24];
    const float* ln_e_g = (const float*)d_in[25];
    const float* ln_e_b = (const float*)d_in[26];
    const float* ln_q_g = (const float*)d_in[27];
    const float* ln_q_b = (const float*)d_in[28];
    const float* ln2_g = (const float*)d_in[29];
    const float* ln2_b = (const float*)d_in[30];
    float* out = (float*)d_out;

    // ---- workspace layout (byte offsets, lifetime-aliased; total 35.31 MB) ----
    char* wsb = (char*)d_ws;
    unsigned short* Wqt   = (unsigned short*)(wsb + 0);         // [1536][768] dead after proj
    unsigned short* Wlt   = (unsigned short*)(wsb + 2359296);   // [3072][768] dead after proj
    unsigned short* Wot   = (unsigned short*)(wsb + 7077888);   // [768][768]  dead after nodeP
    unsigned short* W1t   = (unsigned short*)(wsb + 8257536);   // [2048][1536] dead after FFN1
    unsigned short* W2t   = (unsigned short*)(wsb + 14548992);  // [768][2048] dead after FFN2
    unsigned short* Wet   = (unsigned short*)(wsb + 17694720);  // [768][768]  dead after mid2
    unsigned short* objb  = (unsigned short*)(wsb + 18874368);  // [832][768]  dead after proj
    unsigned short* langb = (unsigned short*)(wsb + 20152320);  // [384][768]  dead after proj
    float*          bqc   = (float*)(wsb + 20742144);           // [1536]
    float*          blc   = (float*)(wsb + 20748288);           // [3072]
    unsigned short* QCb   = (unsigned short*)(wsb + 20760576);  // [832][1536] dead after mid2
    unsigned short* LCb   = (unsigned short*)(wsb + 23316480);  // [384][3072] dead after mid2
    unsigned short* VWtp  = (unsigned short*)(wsb + 25675776);  // 16*9*24576  dead after edge
    unsigned short* Ctxnb = (unsigned short*)(wsb + 32753664);  // [832][768]  dead after nodeP
    // aliases (hosts dead before these are written)
    float* NodeP = (float*)(wsb + 0);           // over Wqt   (2,555,904)
    float* EdgeB = (float*)(wsb + 2555904);     // over Wqt/Wlt (2,555,904)
    float* S2e   = (float*)(wsb + 18874368);    // over objb  (958,464)
    float* Tb    = (float*)(wsb + 19832832);    // over objb  (18,432)
    unsigned short* H1b = (unsigned short*)(wsb + 20760576);  // over QCb/LCb (3,407,872)
    float* H2    = (float*)(wsb + 25675776);    // over VWt   (2,555,904)
    unsigned short* Fusedb = (unsigned short*)(wsb + 32753664); // over Ctxnb+ (2,555,904)

    dim3 blk(256);
    // 1: pack all weights (transposed bf16) + activations + fused biases
    pack_all_kernel<<<3221, blk, 0, stream>>>(
        e_wq, n_wq, e_wk, e_wv, n_wk, n_wv, n_wo, e_wo, ffn_w1, ffn_w2,
        Wqt, Wqt + 768 * 768, Wlt, Wlt + 768 * 768, Wlt + 2 * 768 * 768,
        Wlt + 3 * 768 * 768, Wot, Wet, W1t, W2t,
        obj, lang, n_bq, e_bk, e_bv, n_bk, n_bv, objb, langb, bqc, blc);
    // 2: both input projections in one launch
    {
        GemmJob p0 = {objb, Wqt, bqc, nullptr, QCb, 768, 1536, 768, 12, 156, 0};
        GemmJob p1 = {langb, Wlt, blc, nullptr, LCb, 768, 3072, 768, 24, 144, 0};
        gemm_tn<<<300, blk, 0, stream>>>(p0, p1);
    }
    // 3: VW (MFMA) + S2e/T + node attention
    mid2_kernel<<<600, blk, 0, stream>>>(QCb, LCb, Wet, e_bq, co_mask, VWtp, S2e, Tb, Ctxnb);
    // 4: node output projection
    {
        GemmJob p0 = {Ctxnb, Wot, n_bo, NodeP, nullptr, 768, 768, 768, 6, 78, 0};
        gemm_tn<<<78, blk, 0, stream>>>(p0, p0);
    }
    // 5: edge main
    edge_kernel<<<832, dim3(512), 0, stream>>>(S2e, Tb, co_mask, VWtp, e_bo, EdgeB);
    // 6: both fuse layernorms
    ln_dual_kernel<<<1664, blk, 0, stream>>>(obj, NodeP, EdgeB, ln_q_g, ln_q_b,
                                             ln_e_g, ln_e_b, Fusedb);
    // 7-8: FFN
    {
        GemmJob p0 = {Fusedb, W1t, ffn_b1, nullptr, H1b, 1536, 2048, 1536, 16, 208, 1};
        gemm_tn<<<208, blk, 0, stream>>>(p0, p0);
    }
    {
        GemmJob p0 = {H1b, W2t, ffn_b2, H2, nullptr, 2048, 768, 2048, 6, 78, 0};
        gemm_tn<<<78, blk, 0, stream>>>(p0, p0);
    }
    // 9: final LN
    ln2_kernel<<<832, blk, 0, stream>>>(Fusedb, H2, ln2_g, ln2_b, out);
}

// Round 5
// 164.426 us; speedup vs baseline: 3.1782x; 1.0082x over previous
//
#include <hip/hip_runtime.h>
#include <math.h>

#define NOBJ 52
#define LL 24
#define NHEAD 12

typedef __attribute__((ext_vector_type(8))) short bf16x8;
typedef __attribute__((ext_vector_type(4))) float f32x4;
typedef __attribute__((ext_vector_type(4))) unsigned int u32x4;
typedef __attribute__((ext_vector_type(2))) unsigned int u32x2;

__device__ __forceinline__ unsigned short f2b(float x) {
    union { float f; unsigned int u; } v; v.f = x;
    unsigned int r = v.u + 0x7fffu + ((v.u >> 16) & 1u);
    return (unsigned short)(r >> 16);
}
__device__ __forceinline__ float b2f(unsigned short u) {
    union { unsigned int u; float f; } v; v.u = ((unsigned int)u) << 16;
    return v.f;
}
__device__ __forceinline__ unsigned int pack2(float a, float b) {
    return (unsigned int)f2b(a) | ((unsigned int)f2b(b) << 16);
}
__device__ __forceinline__ f32x4 mfma16(bf16x8 a, bf16x8 b, f32x4 c) {
    return __builtin_amdgcn_mfma_f32_16x16x32_bf16(a, b, c, 0, 0, 0);
}
__device__ __forceinline__ void gl_lds16(const void* g, void* lds) {
    __builtin_amdgcn_global_load_lds(
        (const __attribute__((address_space(1))) unsigned int*)g,
        (__attribute__((address_space(3))) unsigned int*)lds, 16, 0, 0);
}

// ---------------------------------------------------------------------------
// 64x64 transpose tile: f32 [K][N] -> bf16 [N][K]
// ---------------------------------------------------------------------------
__device__ __forceinline__ void transpose_tile(const float* __restrict__ src,
    unsigned short* __restrict__ dst, int K, int N, int t, char* smem)
{
    float (*ts)[65] = (float(*)[65])smem;
    const int tid = threadIdx.x;
    const int ntk = K >> 6;
    const int k0 = (t % ntk) << 6, n0 = (t / ntk) << 6;
    const int tx = tid & 63, ty = tid >> 6;
    #pragma unroll
    for (int i2 = 0; i2 < 16; ++i2) {
        const int row = i2 * 4 + ty;
        ts[row][tx] = src[(size_t)(k0 + row) * N + n0 + tx];
    }
    __syncthreads();
    #pragma unroll
    for (int i2 = 0; i2 < 16; ++i2) {
        const int row = i2 * 4 + ty;
        dst[(size_t)(n0 + row) * K + k0 + tx] = f2b(ts[tx][row]);
    }
}

// ---------------------------------------------------------------------------
// pack1: 8 square 768x768 weight transposes + activation/bias pack
// ---------------------------------------------------------------------------
__global__ __launch_bounds__(256)
void pack1_kernel(const float* s0, const float* s1, const float* s2,
                  const float* s3, const float* s4, const float* s5,
                  const float* s6, const float* s7,
                  unsigned short* d0, unsigned short* d1, unsigned short* d2,
                  unsigned short* d3, unsigned short* d4, unsigned short* d5,
                  unsigned short* d6, unsigned short* d7,
                  const float* obj, const float* lang, const float* n_bq,
                  const float* e_bk, const float* e_bv,
                  const float* n_bk, const float* n_bv,
                  unsigned short* objb, unsigned short* langb,
                  float* bqc, float* blc)
{
    __shared__ __align__(16) char smem[16640];
    const int bid = blockIdx.x;
    const int tid = threadIdx.x;
    if (bid < 1152) {
        const int job = bid / 144, t = bid % 144;
        const float* src;
        unsigned short* dst;
        switch (job) {
            case 0: src = s0; dst = d0; break;
            case 1: src = s1; dst = d1; break;
            case 2: src = s2; dst = d2; break;
            case 3: src = s3; dst = d3; break;
            case 4: src = s4; dst = d4; break;
            case 5: src = s5; dst = d5; break;
            case 6: src = s6; dst = d6; break;
            default: src = s7; dst = d7; break;
        }
        transpose_tile(src, dst, 768, 768, t, smem);
    } else {
        const int base = ((bid - 1152) * 256 + tid) * 4;
        const int T0 = 638976, T1 = 933888, T2 = 935424, T3 = 938496;
        if (base >= T3) return;
        if (base < T0) {
            f32x4 v = *(const f32x4*)(obj + base);
            *(u32x2*)(objb + base) = (u32x2){pack2(v[0], v[1]), pack2(v[2], v[3])};
        } else if (base < T1) {
            const int j = base - T0;
            f32x4 v = *(const f32x4*)(lang + j);
            *(u32x2*)(langb + j) = (u32x2){pack2(v[0], v[1]), pack2(v[2], v[3])};
        } else if (base < T2) {
            const int j = base - T1;
            if (j < 768) { *(f32x4*)(bqc + j) = (f32x4){0.f, 0.f, 0.f, 0.f}; }
            else         { *(f32x4*)(bqc + j) = *(const f32x4*)(n_bq + j - 768); }
        } else {
            const int j = base - T2;
            const int s = j / 768, c = j % 768;
            const float* p = (s == 0) ? e_bk : (s == 1) ? e_bv : (s == 2) ? n_bk : n_bv;
            *(f32x4*)(blc + j) = *(const f32x4*)(p + c);
        }
    }
}

// ---------------------------------------------------------------------------
// Generic GEMM body: C[M,N] = A[M,K](bf16) @ Bt[N,K]^T + bias (+relu).
// 64x128 tile, BK=64, dbuf global_load_lds, chunk-XOR swizzle. 256 thr.
// ---------------------------------------------------------------------------
struct GemmJob {
    const unsigned short* A; const unsigned short* Bt; const float* bias;
    float* C; unsigned short* Cb;
    int lda, ldc, K, nbx, nb, relu;
};

__device__ __forceinline__ void gemm_body(const GemmJob J, int bid, char* smem)
{
    unsigned short* As = (unsigned short*)smem;             // 2 x 4096
    unsigned short* Bs = (unsigned short*)(smem + 16384);   // 2 x 8192
    const int n0 = (bid % J.nbx) * 128, m0 = (bid / J.nbx) * 64;
    const int tid = threadIdx.x;
    const int lane = tid & 63;
    const int w = tid >> 6, wr = w >> 1, wc = w & 1;
    const int lr = lane & 15, lk = lane >> 4;
    const int lda = J.lda, K = J.K;
    const unsigned short* Ab = J.A + (size_t)m0 * lda;
    const unsigned short* Bb = J.Bt + (size_t)n0 * K;

    f32x4 acc[2][4] = {};
    const int NT = K >> 6;

    #pragma unroll
    for (int q = 0; q < 2; ++q) {
        const int c = q * 256 + tid, row = c >> 3, p = (c & 7) ^ (row & 7);
        gl_lds16(Ab + (size_t)row * lda + p * 8, As + c * 8);
    }
    #pragma unroll
    for (int q = 0; q < 4; ++q) {
        const int c = q * 256 + tid, row = c >> 3, p = (c & 7) ^ (row & 7);
        gl_lds16(Bb + (size_t)row * K + p * 8, Bs + c * 8);
    }
    __syncthreads();

    for (int t = 0; t < NT; ++t) {
        const int cur = t & 1;
        if (t + 1 < NT) {
            const int k0 = (t + 1) << 6;
            #pragma unroll
            for (int q = 0; q < 2; ++q) {
                const int c = q * 256 + tid, row = c >> 3, p = (c & 7) ^ (row & 7);
                gl_lds16(Ab + (size_t)row * lda + k0 + p * 8, As + (cur ^ 1) * 4096 + c * 8);
            }
            #pragma unroll
            for (int q = 0; q < 4; ++q) {
                const int c = q * 256 + tid, row = c >> 3, p = (c & 7) ^ (row & 7);
                gl_lds16(Bb + (size_t)row * K + k0 + p * 8, Bs + (cur ^ 1) * 8192 + c * 8);
            }
        }
        #pragma unroll
        for (int kk = 0; kk < 2; ++kk) {
            bf16x8 af[2], bv[4];
            #pragma unroll
            for (int mt = 0; mt < 2; ++mt) {
                const int row = wr * 32 + mt * 16 + lr;
                const int pc = (kk * 4 + lk) ^ (row & 7);
                af[mt] = *(const bf16x8*)(As + cur * 4096 + row * 64 + pc * 8);
            }
            #pragma unroll
            for (int nt = 0; nt < 4; ++nt) {
                const int col = wc * 64 + nt * 16 + lr;
                const int pc = (kk * 4 + lk) ^ (col & 7);
                bv[nt] = *(const bf16x8*)(Bs + cur * 8192 + col * 64 + pc * 8);
            }
            #pragma unroll
            for (int mt = 0; mt < 2; ++mt)
                #pragma unroll
                for (int nt = 0; nt < 4; ++nt)
                    acc[mt][nt] = mfma16(af[mt], bv[nt], acc[mt][nt]);
        }
        __syncthreads();
    }

    #pragma unroll
    for (int mt = 0; mt < 2; ++mt) {
        #pragma unroll
        for (int nt = 0; nt < 4; ++nt) {
            const int col = n0 + wc * 64 + nt * 16 + lr;
            const float bvv = J.bias ? J.bias[col] : 0.f;
            #pragma unroll
            for (int r = 0; r < 4; ++r) {
                const int row = m0 + wr * 32 + mt * 16 + lk * 4 + r;
                float v = acc[mt][nt][r] + bvv;
                if (J.relu) v = fmaxf(v, 0.f);
                if (J.C)  J.C[(size_t)row * J.ldc + col] = v;
                if (J.Cb) J.Cb[(size_t)row * J.ldc + col] = f2b(v);
            }
        }
    }
}

__global__ __launch_bounds__(256)
void gemm_tn(GemmJob j0, GemmJob j1)
{
    __shared__ __align__(16) char smem[49152];
    const int bid = blockIdx.x;
    if (bid < j0.nb) gemm_body(j0, bid, smem);
    else gemm_body(j1, bid - j0.nb, smem);
}

// ---------------------------------------------------------------------------
// softmax body: per chunk-local (n,i) compute 624 rows (h,j) of edge softmax,
// write tight P tile [52][288] bf16 (row stride 576 B) to global.
// ---------------------------------------------------------------------------
__device__ __forceinline__ void softmax_body(
    int cn0, int bi, unsigned short* __restrict__ P,
    const float* __restrict__ S2e, const float* __restrict__ Tb,
    const int* __restrict__ co_mask, char* smem)
{
    unsigned short* Ps = (unsigned short*)smem;                    // [52][288]
    float* SiT = (float*)(smem + 29952);                           // [288]
    unsigned char* cmb = (unsigned char*)(smem + 29952 + 1152);    // [1248]
    const int tid = threadIdx.x;
    const int n = cn0 + bi / 52, i = bi % 52;
    const float* S2n = S2e + (size_t)n * NHEAD * 52 * 24;
    for (int p = tid; p < 288; p += 256) {
        const int h = p / 24, l = p % 24;
        SiT[p] = S2n[((size_t)h * 52 + i) * 24 + l] + Tb[((size_t)n * NHEAD + h) * 24 + l];
    }
    for (int p = tid; p < 1248; p += 256)
        cmb[p] = (unsigned char)(co_mask[(size_t)n * 1248 + p] > 0);
    __syncthreads();
    for (int p = tid; p < 624; p += 256) {
        const int h = p / 52, j = p % 52;
        const float* Sj = S2n + ((size_t)h * 52 + j) * 24;
        const float* st = SiT + h * 24;
        float x[24]; float mx = -1e30f;
        #pragma unroll
        for (int l = 0; l < 24; ++l) {
            float v = (st[l] - Sj[l]) * 0.125f;
            v = cmb[l * 52 + j] ? v : -1e9f;
            x[l] = v; mx = fmaxf(mx, v);
        }
        float sum = 0.f;
        #pragma unroll
        for (int l = 0; l < 24; ++l) { const float e = __expf(x[l] - mx); x[l] = e; sum += e; }
        const float inv = 1.f / sum;
        u32x4* dst = (u32x4*)(Ps + j * 288 + h * 24);
        u32x4 u0, u1, u2;
        #pragma unroll
        for (int c = 0; c < 4; ++c) {
            u0[c] = pack2(x[2 * c] * inv, x[2 * c + 1] * inv);
            u1[c] = pack2(x[8 + 2 * c] * inv, x[9 + 2 * c] * inv);
            u2[c] = pack2(x[16 + 2 * c] * inv, x[17 + 2 * c] * inv);
        }
        dst[0] = u0; dst[1] = u1; dst[2] = u2;
    }
    __syncthreads();
    unsigned short* dstG = P + (size_t)bi * 14976;
    for (int p = tid; p < 1872; p += 256)
        *(u32x4*)(dstG + p * 8) = *(const u32x4*)(Ps + p * 8);
}

// ---------------------------------------------------------------------------
// edge GEMM body: block = (n-local, i-pair, d-quarter). C[64x192] = P @ VW,
// dbuf gl_lds for A (P) and B (pre-permuted VWt), fused max-over-j + e_bo.
// 256 thr / 4 waves = 2i x 2 col-groups(96). Conflict-free ((x>>1)&3) keys.
// ---------------------------------------------------------------------------
__device__ __forceinline__ void edge_body(
    int cn0, int bid, const unsigned short* __restrict__ P,
    const unsigned short* __restrict__ VWt, const float* __restrict__ ebo,
    unsigned short* __restrict__ EdgeBb, char* smem)
{
    unsigned short* As = (unsigned short*)smem;             // 2 x 4096
    unsigned short* Bs = (unsigned short*)(smem + 16384);   // 2 x 6144
    const int tid = threadIdx.x;
    const int sw = (bid & 7) * 52 + (bid >> 3);             // XCD-contiguous n
    const int nl = sw / 104;
    const int r104 = sw % 104;
    const int ip = r104 >> 2, dq = r104 & 3;
    const int n = cn0 + nl;
    const int i0 = ip * 2;
    const unsigned short* Pn = P + (size_t)(nl * 52 + i0) * 14976;
    const unsigned short* Bsrc = VWt + (size_t)n * 221184 + dq * 6144;

    const int ca0 = tid, ca1 = 256 + tid;
    const int ro0 = (ca0 >> 2) & 63, kp0 = ca0 & 3;
    const int ro1 = (ca1 >> 2) & 63, kp1 = ca1 & 3;
    const int sa0 = (ca0 >> 8) * 14976 + ro0 * 288 + ((kp0 ^ ((ro0 >> 1) & 3)) << 3);
    const int sa1 = (ca1 >> 8) * 14976 + ro1 * 288 + ((kp1 ^ ((ro1 >> 1) & 3)) << 3);

    gl_lds16(Pn + sa0, As + ca0 * 8);
    gl_lds16(Pn + sa1, As + ca1 * 8);
    #pragma unroll
    for (int q = 0; q < 3; ++q) {
        const int c = q * 256 + tid;
        gl_lds16(Bsrc + c * 8, Bs + c * 8);
    }
    __syncthreads();

    const int lane = tid & 63, w = tid >> 6;
    const int iw = w >> 1, cg = (w & 1) * 96;
    const int lr = lane & 15, lk = lane >> 4;
    f32x4 acc[4][6] = {};
    for (int ks = 0; ks < 9; ++ks) {
        const int cur = ks & 1;
        if (ks < 8) {
            const int nb = cur ^ 1;
            gl_lds16(Pn + sa0 + (ks + 1) * 32, As + nb * 4096 + ca0 * 8);
            gl_lds16(Pn + sa1 + (ks + 1) * 32, As + nb * 4096 + ca1 * 8);
            #pragma unroll
            for (int q = 0; q < 3; ++q) {
                const int c = q * 256 + tid;
                gl_lds16(Bsrc + (size_t)(ks + 1) * 24576 + c * 8, Bs + nb * 6144 + c * 8);
            }
        }
        bf16x8 af[4];
        #pragma unroll
        for (int mt = 0; mt < 4; ++mt) {
            const int row = mt * 16 + lr;
            af[mt] = *(const bf16x8*)(As + cur * 4096 + iw * 2048 + row * 32
                                      + ((lk ^ ((row >> 1) & 3)) << 3));
        }
        #pragma unroll
        for (int nt = 0; nt < 6; ++nt) {
            const int cl = cg + nt * 16 + lr;
            bf16x8 bv = *(const bf16x8*)(Bs + cur * 6144 + cl * 32
                                         + ((lk ^ ((cl >> 1) & 3)) << 3));
            #pragma unroll
            for (int mt = 0; mt < 4; ++mt)
                acc[mt][nt] = mfma16(af[mt], bv, acc[mt][nt]);
        }
        __syncthreads();
    }

    #pragma unroll
    for (int nt = 0; nt < 6; ++nt) {
        float m = -1e30f;
        #pragma unroll
        for (int mt = 0; mt < 4; ++mt)
            #pragma unroll
            for (int r = 0; r < 4; ++r) {
                const int row = mt * 16 + lk * 4 + r;
                if (row < NOBJ) m = fmaxf(m, acc[mt][nt][r]);
            }
        m = fmaxf(m, __shfl_xor(m, 16));
        m = fmaxf(m, __shfl_xor(m, 32));
        if (lk == 0) {
            const int col = dq * 192 + cg + nt * 16 + lr;
            EdgeBb[(size_t)(n * 52 + i0 + iw) * 768 + col] = f2b(m + ebo[col]);
        }
    }
}

// ---------------------------------------------------------------------------
// L4: nodeP gemm (78 blocks) + softmax chunk0 (208 blocks)
// ---------------------------------------------------------------------------
__global__ __launch_bounds__(256)
void l4_kernel(GemmJob jn, unsigned short* P0,
               const float* __restrict__ S2e, const float* __restrict__ Tb,
               const int* __restrict__ co_mask)
{
    __shared__ __align__(16) char smem[49152];
    const int bid = blockIdx.x;
    if (bid < jn.nb) gemm_body(jn, bid, smem);
    else softmax_body(0, bid - jn.nb, P0, S2e, Tb, co_mask, smem);
}

// ---------------------------------------------------------------------------
// L5-L8: edge chunk (416 blocks) + optional softmax of next chunk (208)
// ---------------------------------------------------------------------------
__global__ __launch_bounds__(256)
void edge_sm_kernel(int en0, const unsigned short* __restrict__ Pe,
                    int sn0, unsigned short* __restrict__ Ps, int smN,
                    const unsigned short* __restrict__ VWt,
                    const float* __restrict__ ebo,
                    unsigned short* __restrict__ EdgeBb,
                    const float* __restrict__ S2e, const float* __restrict__ Tb,
                    const int* __restrict__ co_mask)
{
    __shared__ __align__(16) char smem[40960];
    const int bid = blockIdx.x;
    if (bid < 416) edge_body(en0, bid, Pe, VWt, ebo, EdgeBb, smem);
    else if (bid - 416 < smN) softmax_body(sn0, bid - 416, Ps, S2e, Tb, co_mask, smem);
}

// ---------------------------------------------------------------------------
// mid2: blocks [0,216) = VW MFMA-GEMM; [216,408) = S2e/T; [408,600) = node attn
// ---------------------------------------------------------------------------
__global__ __launch_bounds__(256)
void mid2_kernel(const unsigned short* __restrict__ QCb,
                 const unsigned short* __restrict__ LCb,
                 const unsigned short* __restrict__ Wet,
                 const float* __restrict__ e_bq,
                 const int* __restrict__ co_mask,
                 unsigned short* __restrict__ VWt,
                 float* __restrict__ S2e, float* __restrict__ Tb,
                 unsigned short* __restrict__ Ctxnb)
{
    __shared__ __align__(16) union USm {
        struct { unsigned short As[8192], Bs[8192]; } g;
        unsigned short Ct[128 * 136];
        struct { float sA[52][68], sB[24][68], sC[24][68]; unsigned char scm[1248]; } s;
    } U;
    const int bid = blockIdx.x;
    const int tid = threadIdx.x;

    if (bid < 216) {
        const int h = bid / 18, rm = bid % 18, mt = rm / 6, ntile = rm % 6;
        const int m0 = mt * 128, n0 = ntile * 128;
        const int lane = tid & 63, w = tid >> 6, wr = w >> 1, wc = w & 1;
        const int lr = lane & 15, lk = lane >> 4;
        #pragma unroll
        for (int q = 0; q < 4; ++q) {
            const int c = q * 256 + tid, row = c >> 3, p = (c & 7) ^ (row & 7);
            gl_lds16(LCb + (size_t)(m0 + row) * 3072 + 768 + h * 64 + p * 8, &U.g.As[c * 8]);
            gl_lds16(Wet + (size_t)(n0 + row) * 768 + h * 64 + p * 8, &U.g.Bs[c * 8]);
        }
        __syncthreads();
        f32x4 acc[4][4] = {};
        #pragma unroll
        for (int kk = 0; kk < 2; ++kk) {
            bf16x8 af[4], bv[4];
            #pragma unroll
            for (int m2 = 0; m2 < 4; ++m2) {
                const int row = wr * 64 + m2 * 16 + lr;
                const int pc = (kk * 4 + lk) ^ (row & 7);
                af[m2] = *(const bf16x8*)&U.g.As[row * 64 + pc * 8];
            }
            #pragma unroll
            for (int n2 = 0; n2 < 4; ++n2) {
                const int col = wc * 64 + n2 * 16 + lr;
                const int pc = (kk * 4 + lk) ^ (col & 7);
                bv[n2] = *(const bf16x8*)&U.g.Bs[col * 64 + pc * 8];
            }
            #pragma unroll
            for (int m2 = 0; m2 < 4; ++m2)
                #pragma unroll
                for (int n2 = 0; n2 < 4; ++n2)
                    acc[m2][n2] = mfma16(af[m2], bv[n2], acc[m2][n2]);
        }
        __syncthreads();
        #pragma unroll
        for (int m2 = 0; m2 < 4; ++m2)
            #pragma unroll
            for (int n2 = 0; n2 < 4; ++n2) {
                const int col = wc * 64 + n2 * 16 + lr;
                #pragma unroll
                for (int r = 0; r < 4; ++r) {
                    const int row = wr * 64 + m2 * 16 + lk * 4 + r;
                    U.Ct[row * 136 + col] = f2b(acc[m2][n2][r]);
                }
            }
        __syncthreads();
        #pragma unroll
        for (int q = 0; q < 8; ++q) {
            const int item = q * 256 + tid;
            const int dl = item & 127, kg = item >> 7;
            const int m = m0 + kg * 8;
            const int nn = m / 24, l0 = m % 24;
            const int kc = (h * 24 + l0) >> 3;
            const int ks = kc >> 2;
            const int dg = n0 + dl;
            const int kpos = (kc & 3) ^ ((dg >> 1) & 3);
            u32x4 uu;
            #pragma unroll
            for (int e = 0; e < 4; ++e)
                uu[e] = (unsigned int)U.Ct[(kg * 8 + 2 * e) * 136 + dl]
                      | ((unsigned int)U.Ct[(kg * 8 + 2 * e + 1) * 136 + dl] << 16);
            *(u32x4*)(VWt + (size_t)nn * 221184 + ks * 24576 + dg * 32 + kpos * 8) = uu;
        }
    } else if (bid < 408) {
        const int b = bid - 216;
        const int n = b / NHEAD, h = b % NHEAD;
        for (int p = tid; p < 52 * 64; p += 256) {
            const int q = p >> 6, d = p & 63;
            U.s.sA[q][d] = b2f(QCb[(size_t)(n * 52 + q) * 1536 + h * 64 + d]);
        }
        for (int p = tid; p < 24 * 64; p += 256) {
            const int l = p >> 6, d = p & 63;
            U.s.sB[l][d] = b2f(LCb[(size_t)(n * 24 + l) * 3072 + h * 64 + d]);
        }
        __syncthreads();
        for (int p = tid; p < 52 * 24; p += 256) {
            const int q = p / 24, l = p % 24;
            float s = 0.f;
            #pragma unroll
            for (int d = 0; d < 64; ++d) s += U.s.sA[q][d] * U.s.sB[l][d];
            S2e[((size_t)(n * NHEAD + h) * 52 + q) * 24 + l] = s;
        }
        if (tid < 24) {
            float s = 0.f;
            #pragma unroll
            for (int d = 0; d < 64; ++d) s += e_bq[h * 64 + d] * U.s.sB[tid][d];
            Tb[((size_t)n * NHEAD + h) * 24 + tid] = s;
        }
    } else {
        const int b = bid - 408;
        const int n = b / NHEAD, h = b % NHEAD;
        for (int p = tid; p < 24 * 64; p += 256) {
            const int l = p >> 6, d = p & 63;
            const unsigned short* Lr = LCb + (size_t)(n * 24 + l) * 3072;
            U.s.sB[l][d] = b2f(Lr[1536 + h * 64 + d]);
            U.s.sC[l][d] = b2f(Lr[2304 + h * 64 + d]);
        }
        for (int p = tid; p < 24 * 52; p += 256)
            U.s.scm[p] = (unsigned char)(co_mask[(size_t)n * 24 * 52 + p] > 0);
        __syncthreads();
        const int q = tid >> 2;
        const int qe = q < 52 ? q : 51;
        const int g16 = (tid & 3) * 16;
        float qv[16];
        {
            const unsigned short* qp = QCb + (size_t)(n * 52 + qe) * 1536 + 768 + h * 64 + g16;
            #pragma unroll
            for (int c = 0; c < 16; ++c) qv[c] = b2f(qp[c]);
        }
        float lg[24];
        #pragma unroll
        for (int l = 0; l < 24; ++l) {
            float s = 0.f;
            #pragma unroll
            for (int c4 = 0; c4 < 4; ++c4) {
                f32x4 kv = *(const f32x4*)&U.s.sB[l][g16 + c4 * 4];
                s += qv[c4 * 4 + 0] * kv[0] + qv[c4 * 4 + 1] * kv[1]
                   + qv[c4 * 4 + 2] * kv[2] + qv[c4 * 4 + 3] * kv[3];
            }
            s += __shfl_xor(s, 1);
            s += __shfl_xor(s, 2);
            lg[l] = s;
        }
        float x[24]; float mx = -1e30f;
        #pragma unroll
        for (int l = 0; l < 24; ++l) {
            const float v = U.s.scm[l * 52 + qe] ? lg[l] * 0.125f : -1e9f;
            x[l] = v; mx = fmaxf(mx, v);
        }
        float sum = 0.f;
        #pragma unroll
        for (int l = 0; l < 24; ++l) { x[l] = __expf(x[l] - mx); sum += x[l]; }
        const float inv = 1.f / sum;
        f32x4 ctx[4] = {};
        #pragma unroll
        for (int l = 0; l < 24; ++l) {
            const float a = x[l] * inv;
            #pragma unroll
            for (int c4 = 0; c4 < 4; ++c4) {
                f32x4 vv = *(const f32x4*)&U.s.sC[l][g16 + c4 * 4];
                ctx[c4] += a * vv;
            }
        }
        if (q < 52) {
            unsigned short* op = Ctxnb + (size_t)(n * 52 + q) * 768 + h * 64 + g16;
            u32x4 o0, o1;
            #pragma unroll
            for (int m = 0; m < 4; ++m) {
                o0[m] = pack2(ctx[m >> 1][(m & 1) * 2], ctx[m >> 1][(m & 1) * 2 + 1]);
                o1[m] = pack2(ctx[2 + (m >> 1)][(m & 1) * 2], ctx[2 + (m >> 1)][(m & 1) * 2 + 1]);
            }
            *(u32x4*)op = o0;
            *(u32x4*)(op + 8) = o1;
        }
    }
}

// ---------------------------------------------------------------------------
// ln_dual body (bf16 x2) + L9 kernel (ln_dual + FFN weight pack)
// ---------------------------------------------------------------------------
__device__ __forceinline__ void ln_dual_body(
    const float* __restrict__ obj,
    const unsigned short* __restrict__ NodePb, const unsigned short* __restrict__ EdgeBb,
    const float* __restrict__ gq, const float* __restrict__ bq,
    const float* __restrict__ ge, const float* __restrict__ be,
    unsigned short* __restrict__ Fusedb, int bid, char* smem)
{
    float* red = (float*)smem;
    const int job = bid >= 832;
    const int row = bid - (job ? 832 : 0);
    const int tid = threadIdx.x;
    const unsigned short* x2 = (job ? EdgeBb : NodePb) + (size_t)row * 768;
    const float* x1 = obj + (size_t)row * 768;
    const float* g = job ? ge : gq;
    const float* bb = job ? be : bq;
    float v[3]; float s = 0.f;
    #pragma unroll
    for (int c = 0; c < 3; ++c) {
        const int col = tid + 256 * c;
        v[c] = x1[col] + b2f(x2[col]); s += v[c];
    }
    #pragma unroll
    for (int o = 32; o; o >>= 1) s += __shfl_xor(s, o);
    if ((tid & 63) == 0) red[tid >> 6] = s;
    __syncthreads();
    const float mean = (red[0] + red[1] + red[2] + red[3]) * (1.f / 768.f);
    float var = 0.f;
    #pragma unroll
    for (int c = 0; c < 3; ++c) { const float d = v[c] - mean; var += d * d; }
    #pragma unroll
    for (int o = 32; o; o >>= 1) var += __shfl_xor(var, o);
    __syncthreads();
    if ((tid & 63) == 0) red[4 + (tid >> 6)] = var;
    __syncthreads();
    const float vt = (red[4] + red[5] + red[6] + red[7]) * (1.f / 768.f);
    const float rs = rsqrtf(vt + 1e-5f);
    unsigned short* dst = Fusedb + (size_t)row * 1536 + (job ? 768 : 0);
    #pragma unroll
    for (int c = 0; c < 3; ++c) {
        const int col = tid + 256 * c;
        dst[col] = f2b((v[c] - mean) * rs * g[col] + bb[col]);
    }
}

__global__ __launch_bounds__(256)
void l9_kernel(const float* __restrict__ obj,
               const unsigned short* __restrict__ NodePb,
               const unsigned short* __restrict__ EdgeBb,
               const float* gq, const float* bq, const float* ge, const float* be,
               unsigned short* __restrict__ Fusedb,
               const float* w1, const float* w2,
               unsigned short* W1t, unsigned short* W2t)
{
    __shared__ __align__(16) char smem[16640];
    const int bid = blockIdx.x;
    if (bid < 1664) {
        ln_dual_body(obj, NodePb, EdgeBb, gq, bq, ge, be, Fusedb, bid, smem);
    } else {
        const int t = bid - 1664;
        if (t < 768) transpose_tile(w1, W1t, 1536, 2048, t, smem);
        else transpose_tile(w2, W2t, 2048, 768, t - 768, smem);
    }
}

// ---------------------------------------------------------------------------
// final LN: out = LN(Fusedb(bf16, stride 1536) + H2(f32))
// ---------------------------------------------------------------------------
__global__ __launch_bounds__(256)
void ln2_kernel(const unsigned short* __restrict__ x1b,
                const float* __restrict__ x2,
                const float* __restrict__ g, const float* __restrict__ bb,
                float* __restrict__ dst)
{
    __shared__ float red[8];
    const int row = blockIdx.x, tid = threadIdx.x;
    float v[3]; float s = 0.f;
    #pragma unroll
    for (int c = 0; c < 3; ++c) {
        const int col = tid + 256 * c;
        v[c] = b2f(x1b[(size_t)row * 1536 + col]) + x2[(size_t)row * 768 + col];
        s += v[c];
    }
    #pragma unroll
    for (int o = 32; o; o >>= 1) s += __shfl_xor(s, o);
    if ((tid & 63) == 0) red[tid >> 6] = s;
    __syncthreads();
    const float mean = (red[0] + red[1] + red[2] + red[3]) * (1.f / 768.f);
    float var = 0.f;
    #pragma unroll
    for (int c = 0; c < 3; ++c) { const float d = v[c] - mean; var += d * d; }
    #pragma unroll
    for (int o = 32; o; o >>= 1) var += __shfl_xor(var, o);
    __syncthreads();
    if ((tid & 63) == 0) red[4 + (tid >> 6)] = var;
    __syncthreads();
    const float vt = (red[4] + red[5] + red[6] + red[7]) * (1.f / 768.f);
    const float rs = rsqrtf(vt + 1e-5f);
    #pragma unroll
    for (int c = 0; c < 3; ++c) {
        const int col = tid + 256 * c;
        dst[(size_t)row * 768 + col] = (v[c] - mean) * rs * g[col] + bb[col];
    }
}

// ---------------------------------------------------------------------------
extern "C" void kernel_launch(void* const* d_in, const int* in_sizes, int n_in,
                              void* d_out, int out_size, void* d_ws, size_t ws_size,
                              hipStream_t stream)
{
    (void)in_sizes; (void)n_in; (void)out_size; (void)ws_size;
    const float* lang  = (const float*)d_in[0];
    const float* obj   = (const float*)d_in[1];
    const int* co_mask = (const int*)d_in[4];
    const float* e_wq = (const float*)d_in[5];
    const float* e_bq = (const float*)d_in[6];
    const float* e_wk = (const float*)d_in[7];
    const float* e_bk = (const float*)d_in[8];
    const float* e_wv = (const float*)d_in[9];
    const float* e_bv = (const float*)d_in[10];
    const float* e_wo = (const float*)d_in[11];
    const float* e_bo = (const float*)d_in[12];
    const float* n_wq = (const float*)d_in[13];
    const float* n_bq = (const float*)d_in[14];
    const float* n_wk = (const float*)d_in[15];
    const float* n_bk = (const float*)d_in[16];
    const float* n_wv = (const float*)d_in[17];
    const float* n_bv = (const float*)d_in[18];
    const float* n_wo = (const float*)d_in[19];
    const float* n_bo = (const float*)d_in[20];
    const float* ffn_w1 = (const float*)d_in[21];
    const float* ffn_b1 = (const float*)d_in[22];
    const float* ffn_w2 = (const float*)d_in[23];
    const float* ffn_b2 = (const float*)d_in[24];
    const float* ln_e_g = (const float*)d_in[25];
    const float* ln_e_b = (const float*)d_in[26];
    const float* ln_q_g = (const float*)d_in[27];
    const float* ln_q_b = (const float*)d_in[28];
    const float* ln2_g = (const float*)d_in[29];
    const float* ln2_b = (const float*)d_in[30];
    float* out = (float*)d_out;

    // ---- workspace layout (byte offsets; lifetime-aliased; peak 29.3 MB) ----
    char* wsb = (char*)d_ws;
    unsigned short* Wqt   = (unsigned short*)(wsb + 0);          // dead after proj
    unsigned short* Wlt   = (unsigned short*)(wsb + 2359296);    // dead after proj
    unsigned short* Wot   = (unsigned short*)(wsb + 7077888);    // dead after L4
    unsigned short* Wet   = (unsigned short*)(wsb + 8257536);    // dead after mid2
    unsigned short* objb  = (unsigned short*)(wsb + 9437184);    // dead after proj
    unsigned short* langb = (unsigned short*)(wsb + 10715136);   // dead after proj
    float*          bqc   = (float*)(wsb + 11304960);
    float*          blc   = (float*)(wsb + 11311104);
    unsigned short* QCb   = (unsigned short*)(wsb + 11323392);   // dead after mid2
    unsigned short* LCb   = (unsigned short*)(wsb + 13879296);   // dead after mid2
    float*          S2e   = (float*)(wsb + 16238592);            // dead after L7
    float*          Tb    = (float*)(wsb + 17197056);
    unsigned short* Ctxnb = (unsigned short*)(wsb + 17215488);   // dead after L4
    unsigned short* VWt   = (unsigned short*)(wsb + 18493440);   // dead after L8
    unsigned short* NodePb= (unsigned short*)(wsb + 25571328);   // dead after L9
    unsigned short* EdgeBb= (unsigned short*)(wsb + 26849280);   // dead after L9
    unsigned short* Fusedb= (unsigned short*)(wsb + 28127232);   // end 30,683,136
    // aliases over dead regions
    unsigned short* Pb0 = (unsigned short*)(wsb + 0);            // 6,230,016 (Wqt/Wlt)
    unsigned short* Pb1 = (unsigned short*)(wsb + 8257536);      // 6,230,016 (Wet..LCb)
    unsigned short* W1t = (unsigned short*)(wsb + 0);            // L9+ (over Pb0)
    unsigned short* W2t = (unsigned short*)(wsb + 7077888);      // L9+ (over Wot/Pb1 head)
    unsigned short* H1b = (unsigned short*)(wsb + 13879296);     // L10+ (over LCb/S2e)
    float*          H2  = (float*)(wsb + 10715136);              // L11+ (over langb..QCb)

    dim3 blk(256);
    // L1: pack early weights + activations
    pack1_kernel<<<2069, blk, 0, stream>>>(
        e_wq, n_wq, e_wk, e_wv, n_wk, n_wv, n_wo, e_wo,
        Wqt, Wqt + 589824, Wlt, Wlt + 589824, Wlt + 2 * 589824, Wlt + 3 * 589824,
        Wot, Wet,
        obj, lang, n_bq, e_bk, e_bv, n_bk, n_bv, objb, langb, bqc, blc);
    // L2: both input projections
    {
        GemmJob p0 = {objb, Wqt, bqc, nullptr, QCb, 768, 1536, 768, 12, 156, 0};
        GemmJob p1 = {langb, Wlt, blc, nullptr, LCb, 768, 3072, 768, 24, 144, 0};
        gemm_tn<<<300, blk, 0, stream>>>(p0, p1);
    }
    // L3: VW (MFMA) + S2e/T + node attention
    mid2_kernel<<<600, blk, 0, stream>>>(QCb, LCb, Wet, e_bq, co_mask, VWt, S2e, Tb, Ctxnb);
    // L4: node output projection + softmax chunk 0
    {
        GemmJob jn = {Ctxnb, Wot, n_bo, nullptr, NodePb, 768, 768, 768, 6, 78, 0};
        l4_kernel<<<286, blk, 0, stream>>>(jn, Pb0, S2e, Tb, co_mask);
    }
    // L5-L8: edge chunk k + softmax chunk k+1 (ping-pong P buffers)
    edge_sm_kernel<<<624, blk, 0, stream>>>(0,  Pb0, 4,  Pb1, 208, VWt, e_bo, EdgeBb, S2e, Tb, co_mask);
    edge_sm_kernel<<<624, blk, 0, stream>>>(4,  Pb1, 8,  Pb0, 208, VWt, e_bo, EdgeBb, S2e, Tb, co_mask);
    edge_sm_kernel<<<624, blk, 0, stream>>>(8,  Pb0, 12, Pb1, 208, VWt, e_bo, EdgeBb, S2e, Tb, co_mask);
    edge_sm_kernel<<<416, blk, 0, stream>>>(12, Pb1, 0,  Pb0, 0,   VWt, e_bo, EdgeBb, S2e, Tb, co_mask);
    // L9: both fuse layernorms + FFN weight packing
    l9_kernel<<<2816, blk, 0, stream>>>(obj, NodePb, EdgeBb, ln_q_g, ln_q_b,
                                        ln_e_g, ln_e_b, Fusedb, ffn_w1, ffn_w2, W1t, W2t);
    // L10-L11: FFN
    {
        GemmJob p0 = {Fusedb, W1t, ffn_b1, nullptr, H1b, 1536, 2048, 1536, 16, 208, 1};
        gemm_tn<<<208, blk, 0, stream>>>(p0, p0);
    }
    {
        GemmJob p0 = {H1b, W2t, ffn_b2, H2, nullptr, 2048, 768, 2048, 6, 78, 0};
        gemm_tn<<<78, blk, 0, stream>>>(p0, p0);
    }
    // L12: final LN
    ln2_kernel<<<832, blk, 0, stream>>>(Fusedb, H2, ln2_g, ln2_b, out);
}

// Round 6
// 137.739 us; speedup vs baseline: 3.7940x; 1.1938x over previous
//
#include <hip/hip_runtime.h>
#include <math.h>

#define NOBJ 52
#define LL 24
#define NHEAD 12

typedef __attribute__((ext_vector_type(8))) short bf16x8;
typedef __attribute__((ext_vector_type(4))) float f32x4;
typedef __attribute__((ext_vector_type(4))) unsigned int u32x4;
typedef __attribute__((ext_vector_type(2))) unsigned int u32x2;

__device__ __forceinline__ unsigned short f2b(float x) {
    union { float f; unsigned int u; } v; v.f = x;
    unsigned int r = v.u + 0x7fffu + ((v.u >> 16) & 1u);
    return (unsigned short)(r >> 16);
}
__device__ __forceinline__ float b2f(unsigned short u) {
    union { unsigned int u; float f; } v; v.u = ((unsigned int)u) << 16;
    return v.f;
}
__device__ __forceinline__ unsigned int pack2(float a, float b) {
    return (unsigned int)f2b(a) | ((unsigned int)f2b(b) << 16);
}
__device__ __forceinline__ f32x4 mfma16(bf16x8 a, bf16x8 b, f32x4 c) {
    return __builtin_amdgcn_mfma_f32_16x16x32_bf16(a, b, c, 0, 0, 0);
}
__device__ __forceinline__ void gl_lds16(const void* g, void* lds) {
    __builtin_amdgcn_global_load_lds(
        (const __attribute__((address_space(1))) unsigned int*)g,
        (__attribute__((address_space(3))) unsigned int*)lds, 16, 0, 0);
}

// ---------------------------------------------------------------------------
// 64x64 transpose tile: f32 [K][N] -> bf16 [N][K]
// ---------------------------------------------------------------------------
__device__ __forceinline__ void transpose_tile(const float* __restrict__ src,
    unsigned short* __restrict__ dst, int K, int N, int t, char* smem)
{
    float (*ts)[65] = (float(*)[65])smem;
    const int tid = threadIdx.x;
    const int ntk = K >> 6;
    const int k0 = (t % ntk) << 6, n0 = (t / ntk) << 6;
    const int tx = tid & 63, ty = tid >> 6;
    #pragma unroll
    for (int i2 = 0; i2 < 16; ++i2) {
        const int row = i2 * 4 + ty;
        ts[row][tx] = src[(size_t)(k0 + row) * N + n0 + tx];
    }
    __syncthreads();
    #pragma unroll
    for (int i2 = 0; i2 < 16; ++i2) {
        const int row = i2 * 4 + ty;
        dst[(size_t)(n0 + row) * K + k0 + tx] = f2b(ts[tx][row]);
    }
}

// ---------------------------------------------------------------------------
// pack_all: 8 square weight transposes + ffn_w1 + ffn_w2 + activations/biases
// blocks [0,1152) squares; [1152,1920) w1; [1920,2304) w2; [2304,3221) acts
// ---------------------------------------------------------------------------
__global__ __launch_bounds__(256)
void pack_all_kernel(const float* s0, const float* s1, const float* s2,
                     const float* s3, const float* s4, const float* s5,
                     const float* s6, const float* s7,
                     const float* s8, const float* s9,
                     unsigned short* d0, unsigned short* d1, unsigned short* d2,
                     unsigned short* d3, unsigned short* d4, unsigned short* d5,
                     unsigned short* d6, unsigned short* d7,
                     unsigned short* d8, unsigned short* d9,
                     const float* obj, const float* lang, const float* n_bq,
                     const float* e_bk, const float* e_bv,
                     const float* n_bk, const float* n_bv,
                     unsigned short* objb, unsigned short* langb,
                     float* bqc, float* blc)
{
    __shared__ __align__(16) char smem[16640];
    const int bid = blockIdx.x;
    const int tid = threadIdx.x;
    if (bid < 2304) {
        const float* src; unsigned short* dst; int K, N, t;
        if (bid < 1152) {
            const int job = bid / 144; t = bid % 144; K = 768; N = 768;
            switch (job) {
                case 0: src = s0; dst = d0; break;
                case 1: src = s1; dst = d1; break;
                case 2: src = s2; dst = d2; break;
                case 3: src = s3; dst = d3; break;
                case 4: src = s4; dst = d4; break;
                case 5: src = s5; dst = d5; break;
                case 6: src = s6; dst = d6; break;
                default: src = s7; dst = d7; break;
            }
        } else if (bid < 1920) { t = bid - 1152; K = 1536; N = 2048; src = s8; dst = d8; }
        else                   { t = bid - 1920; K = 2048; N = 768;  src = s9; dst = d9; }
        transpose_tile(src, dst, K, N, t, smem);
    } else {
        const int base = ((bid - 2304) * 256 + tid) * 4;
        const int T0 = 638976, T1 = 933888, T2 = 935424, T3 = 938496;
        if (base >= T3) return;
        if (base < T0) {
            f32x4 v = *(const f32x4*)(obj + base);
            *(u32x2*)(objb + base) = (u32x2){pack2(v[0], v[1]), pack2(v[2], v[3])};
        } else if (base < T1) {
            const int j = base - T0;
            f32x4 v = *(const f32x4*)(lang + j);
            *(u32x2*)(langb + j) = (u32x2){pack2(v[0], v[1]), pack2(v[2], v[3])};
        } else if (base < T2) {
            const int j = base - T1;
            if (j < 768) { *(f32x4*)(bqc + j) = (f32x4){0.f, 0.f, 0.f, 0.f}; }
            else         { *(f32x4*)(bqc + j) = *(const f32x4*)(n_bq + j - 768); }
        } else {
            const int j = base - T2;
            const int s = j / 768, c = j % 768;
            const float* p = (s == 0) ? e_bk : (s == 1) ? e_bv : (s == 2) ? n_bk : n_bv;
            *(f32x4*)(blc + j) = *(const f32x4*)(p + c);
        }
    }
}

// ---------------------------------------------------------------------------
// Generic GEMM: C[M,N] = A[M,K](bf16) @ Bt[N,K]^T + bias (+relu).
// 64x128 tile, BK=64, dbuf global_load_lds, chunk-XOR swizzle. 256 thr.
// swz: XCD-grouped column-major block order (requires nb%8==0).
// ---------------------------------------------------------------------------
struct GemmJob {
    const unsigned short* A; const unsigned short* Bt; const float* bias;
    float* C; unsigned short* Cb;
    int lda, ldc, K, nbx, nb, relu, swz;
};

__device__ __forceinline__ void gemm_body(const GemmJob J, int bid, char* smem)
{
    unsigned short* As = (unsigned short*)smem;             // 2 x 4096
    unsigned short* Bs = (unsigned short*)(smem + 16384);   // 2 x 8192
    int bx, by;
    if (J.swz) {
        const int cpx = J.nb >> 3;
        const int gid = (bid & 7) * cpx + (bid >> 3);
        const int nbm = J.nb / J.nbx;
        bx = gid / nbm; by = gid % nbm;
    } else { bx = bid % J.nbx; by = bid / J.nbx; }
    const int n0 = bx * 128, m0 = by * 64;
    const int tid = threadIdx.x;
    const int lane = tid & 63;
    const int w = tid >> 6, wr = w >> 1, wc = w & 1;
    const int lr = lane & 15, lk = lane >> 4;
    const int lda = J.lda, K = J.K;
    const unsigned short* Ab = J.A + (size_t)m0 * lda;
    const unsigned short* Bb = J.Bt + (size_t)n0 * K;

    f32x4 acc[2][4] = {};
    const int NT = K >> 6;

    #pragma unroll
    for (int q = 0; q < 2; ++q) {
        const int c = q * 256 + tid, row = c >> 3, p = (c & 7) ^ (row & 7);
        gl_lds16(Ab + (size_t)row * lda + p * 8, As + c * 8);
    }
    #pragma unroll
    for (int q = 0; q < 4; ++q) {
        const int c = q * 256 + tid, row = c >> 3, p = (c & 7) ^ (row & 7);
        gl_lds16(Bb + (size_t)row * K + p * 8, Bs + c * 8);
    }
    __syncthreads();

    for (int t = 0; t < NT; ++t) {
        const int cur = t & 1;
        if (t + 1 < NT) {
            const int k0 = (t + 1) << 6;
            #pragma unroll
            for (int q = 0; q < 2; ++q) {
                const int c = q * 256 + tid, row = c >> 3, p = (c & 7) ^ (row & 7);
                gl_lds16(Ab + (size_t)row * lda + k0 + p * 8, As + (cur ^ 1) * 4096 + c * 8);
            }
            #pragma unroll
            for (int q = 0; q < 4; ++q) {
                const int c = q * 256 + tid, row = c >> 3, p = (c & 7) ^ (row & 7);
                gl_lds16(Bb + (size_t)row * K + k0 + p * 8, Bs + (cur ^ 1) * 8192 + c * 8);
            }
        }
        #pragma unroll
        for (int kk = 0; kk < 2; ++kk) {
            bf16x8 af[2], bv[4];
            #pragma unroll
            for (int mt = 0; mt < 2; ++mt) {
                const int row = wr * 32 + mt * 16 + lr;
                const int pc = (kk * 4 + lk) ^ (row & 7);
                af[mt] = *(const bf16x8*)(As + cur * 4096 + row * 64 + pc * 8);
            }
            #pragma unroll
            for (int nt = 0; nt < 4; ++nt) {
                const int col = wc * 64 + nt * 16 + lr;
                const int pc = (kk * 4 + lk) ^ (col & 7);
                bv[nt] = *(const bf16x8*)(Bs + cur * 8192 + col * 64 + pc * 8);
            }
            #pragma unroll
            for (int mt = 0; mt < 2; ++mt)
                #pragma unroll
                for (int nt = 0; nt < 4; ++nt)
                    acc[mt][nt] = mfma16(af[mt], bv[nt], acc[mt][nt]);
        }
        __syncthreads();
    }

    #pragma unroll
    for (int mt = 0; mt < 2; ++mt) {
        #pragma unroll
        for (int nt = 0; nt < 4; ++nt) {
            const int col = n0 + wc * 64 + nt * 16 + lr;
            const float bvv = J.bias ? J.bias[col] : 0.f;
            #pragma unroll
            for (int r = 0; r < 4; ++r) {
                const int row = m0 + wr * 32 + mt * 16 + lk * 4 + r;
                float v = acc[mt][nt][r] + bvv;
                if (J.relu) v = fmaxf(v, 0.f);
                if (J.C)  J.C[(size_t)row * J.ldc + col] = v;
                if (J.Cb) J.Cb[(size_t)row * J.ldc + col] = f2b(v);
            }
        }
    }
}

__global__ __launch_bounds__(256)
void gemm_tn(GemmJob j0, GemmJob j1)
{
    __shared__ __align__(16) char smem[49152];
    const int bid = blockIdx.x;
    if (bid < j0.nb) gemm_body(j0, bid, smem);
    else gemm_body(j1, bid - j0.nb, smem);
}

// ---------------------------------------------------------------------------
// mid3: [0,216) VWe GEMM; [216,432) VWn GEMM; [432,624) S2e+T; [624,816) S2n
// VW GEMM: C[(n,l),d] = V_h[384x64] @ W_h[64x768] -> swizzled bf16 layout
// ---------------------------------------------------------------------------
__global__ __launch_bounds__(256)
void mid3_kernel(const unsigned short* __restrict__ QCb,
                 const unsigned short* __restrict__ LCb,
                 const unsigned short* __restrict__ Wet,
                 const unsigned short* __restrict__ Wot,
                 const float* __restrict__ e_bq,
                 unsigned short* __restrict__ VWe,
                 unsigned short* __restrict__ VWn,
                 float* __restrict__ S2e, float* __restrict__ Tb,
                 float* __restrict__ S2n)
{
    __shared__ __align__(16) union USm {
        struct { unsigned short As[8192], Bs[8192]; } g;
        unsigned short Ct[128 * 136];
        struct { float sA[52][68], sB[24][68]; } s;
    } U;
    const int bid = blockIdx.x;
    const int tid = threadIdx.x;

    if (bid < 432) {
        const int sub = bid >= 216;
        const int b = sub ? bid - 216 : bid;
        const int aoff = sub ? 2304 : 768;
        const unsigned short* Bt = sub ? Wot : Wet;
        unsigned short* Vout = sub ? VWn : VWe;

        const int h = b / 18, rm = b % 18, mt = rm / 6, ntile = rm % 6;
        const int m0 = mt * 128, n0 = ntile * 128;
        const int lane = tid & 63, w = tid >> 6, wr = w >> 1, wc = w & 1;
        const int lr = lane & 15, lk = lane >> 4;
        #pragma unroll
        for (int q = 0; q < 4; ++q) {
            const int c = q * 256 + tid, row = c >> 3, p = (c & 7) ^ (row & 7);
            gl_lds16(LCb + (size_t)(m0 + row) * 3072 + aoff + h * 64 + p * 8, &U.g.As[c * 8]);
            gl_lds16(Bt + (size_t)(n0 + row) * 768 + h * 64 + p * 8, &U.g.Bs[c * 8]);
        }
        __syncthreads();
        f32x4 acc[4][4] = {};
        #pragma unroll
        for (int kk = 0; kk < 2; ++kk) {
            bf16x8 af[4], bv[4];
            #pragma unroll
            for (int m2 = 0; m2 < 4; ++m2) {
                const int row = wr * 64 + m2 * 16 + lr;
                const int pc = (kk * 4 + lk) ^ (row & 7);
                af[m2] = *(const bf16x8*)&U.g.As[row * 64 + pc * 8];
            }
            #pragma unroll
            for (int n2 = 0; n2 < 4; ++n2) {
                const int col = wc * 64 + n2 * 16 + lr;
                const int pc = (kk * 4 + lk) ^ (col & 7);
                bv[n2] = *(const bf16x8*)&U.g.Bs[col * 64 + pc * 8];
            }
            #pragma unroll
            for (int m2 = 0; m2 < 4; ++m2)
                #pragma unroll
                for (int n2 = 0; n2 < 4; ++n2)
                    acc[m2][n2] = mfma16(af[m2], bv[n2], acc[m2][n2]);
        }
        __syncthreads();
        #pragma unroll
        for (int m2 = 0; m2 < 4; ++m2)
            #pragma unroll
            for (int n2 = 0; n2 < 4; ++n2) {
                const int col = wc * 64 + n2 * 16 + lr;
                #pragma unroll
                for (int r = 0; r < 4; ++r) {
                    const int row = wr * 64 + m2 * 16 + lk * 4 + r;
                    U.Ct[row * 136 + col] = f2b(acc[m2][n2][r]);
                }
            }
        __syncthreads();
        #pragma unroll
        for (int q = 0; q < 8; ++q) {
            const int item = q * 256 + tid;
            const int dl = item & 127, kg = item >> 7;
            const int m = m0 + kg * 8;
            const int nn = m / 24, l0 = m % 24;
            const int kc = (h * 24 + l0) >> 3;
            const int ks = kc >> 2;
            const int dg = n0 + dl;
            const int kpos = (kc & 3) ^ ((dg >> 1) & 3);
            u32x4 uu;
            #pragma unroll
            for (int e = 0; e < 4; ++e)
                uu[e] = (unsigned int)U.Ct[(kg * 8 + 2 * e) * 136 + dl]
                      | ((unsigned int)U.Ct[(kg * 8 + 2 * e + 1) * 136 + dl] << 16);
            *(u32x4*)(Vout + (size_t)nn * 221184 + ks * 24576 + dg * 32 + kpos * 8) = uu;
        }
    } else {
        const int sub = bid >= 624;               // 0: S2e(+T), 1: S2n
        const int b = bid - (sub ? 624 : 432);
        const int n = b / NHEAD, h = b % NHEAD;
        const int qoff = sub ? 768 : 0, koff = sub ? 1536 : 0;
        float* Sout = sub ? S2n : S2e;
        for (int p = tid; p < 52 * 64; p += 256) {
            const int q = p >> 6, d = p & 63;
            U.s.sA[q][d] = b2f(QCb[(size_t)(n * 52 + q) * 1536 + qoff + h * 64 + d]);
        }
        for (int p = tid; p < 24 * 64; p += 256) {
            const int l = p >> 6, d = p & 63;
            U.s.sB[l][d] = b2f(LCb[(size_t)(n * 24 + l) * 3072 + koff + h * 64 + d]);
        }
        __syncthreads();
        for (int p = tid; p < 52 * 24; p += 256) {
            const int q = p / 24, l = p % 24;
            float s = 0.f;
            #pragma unroll
            for (int d = 0; d < 64; ++d) s += U.s.sA[q][d] * U.s.sB[l][d];
            Sout[((size_t)(n * NHEAD + h) * 52 + q) * 24 + l] = s;
        }
        if (!sub && tid < 24) {
            float s = 0.f;
            #pragma unroll
            for (int d = 0; d < 64; ++d) s += e_bq[h * 64 + d] * U.s.sB[tid][d];
            Tb[((size_t)n * NHEAD + h) * 24 + tid] = s;
        }
    }
}

// ---------------------------------------------------------------------------
// sm_kernel: [0,832) edge softmax per (n,i) -> Pe; [832,848) node softmax -> Pn
// ---------------------------------------------------------------------------
__global__ __launch_bounds__(256)
void sm_kernel(const float* __restrict__ S2e, const float* __restrict__ Tb,
               const float* __restrict__ S2n, const int* __restrict__ co_mask,
               unsigned short* __restrict__ Pe, unsigned short* __restrict__ Pn)
{
    __shared__ __align__(16) unsigned short Ps[52 * 288];
    __shared__ float SiT[288];
    __shared__ unsigned char cmb[1248];
    const int bid = blockIdx.x;
    const int tid = threadIdx.x;

    if (bid < 832) {
        const int n = bid / 52, i = bid % 52;
        const float* S2x = S2e + (size_t)n * NHEAD * 52 * 24;
        for (int p = tid; p < 288; p += 256) {
            const int h = p / 24, l = p % 24;
            SiT[p] = S2x[((size_t)h * 52 + i) * 24 + l] + Tb[((size_t)n * NHEAD + h) * 24 + l];
        }
        for (int p = tid; p < 1248; p += 256)
            cmb[p] = (unsigned char)(co_mask[(size_t)n * 1248 + p] > 0);
        __syncthreads();
        for (int p = tid; p < 624; p += 256) {
            const int h = p / 52, j = p % 52;
            const float* Sj = S2x + ((size_t)h * 52 + j) * 24;
            const float* st = SiT + h * 24;
            float x[24]; float mx = -1e30f;
            #pragma unroll
            for (int l = 0; l < 24; ++l) {
                float v = (st[l] - Sj[l]) * 0.125f;
                v = cmb[l * 52 + j] ? v : -1e9f;
                x[l] = v; mx = fmaxf(mx, v);
            }
            float sum = 0.f;
            #pragma unroll
            for (int l = 0; l < 24; ++l) { const float e = __expf(x[l] - mx); x[l] = e; sum += e; }
            const float inv = 1.f / sum;
            u32x4* dst = (u32x4*)(Ps + j * 288 + h * 24);
            u32x4 u0, u1, u2;
            #pragma unroll
            for (int c = 0; c < 4; ++c) {
                u0[c] = pack2(x[2 * c] * inv, x[2 * c + 1] * inv);
                u1[c] = pack2(x[8 + 2 * c] * inv, x[9 + 2 * c] * inv);
                u2[c] = pack2(x[16 + 2 * c] * inv, x[17 + 2 * c] * inv);
            }
            dst[0] = u0; dst[1] = u1; dst[2] = u2;
        }
        __syncthreads();
        unsigned short* dstG = Pe + (size_t)bid * 14976;
        for (int p = tid; p < 1872; p += 256)
            *(u32x4*)(dstG + p * 8) = *(const u32x4*)(Ps + p * 8);
    } else {
        const int n = bid - 832;
        const float* S2x = S2n + (size_t)n * NHEAD * 52 * 24;
        for (int p = tid; p < 1248; p += 256)
            cmb[p] = (unsigned char)(co_mask[(size_t)n * 1248 + p] > 0);
        __syncthreads();
        for (int p = tid; p < 624; p += 256) {
            const int h = p / 52, q = p % 52;
            const float* Sq = S2x + ((size_t)h * 52 + q) * 24;
            float x[24]; float mx = -1e30f;
            #pragma unroll
            for (int l = 0; l < 24; ++l) {
                float v = Sq[l] * 0.125f;
                v = cmb[l * 52 + q] ? v : -1e9f;
                x[l] = v; mx = fmaxf(mx, v);
            }
            float sum = 0.f;
            #pragma unroll
            for (int l = 0; l < 24; ++l) { const float e = __expf(x[l] - mx); x[l] = e; sum += e; }
            const float inv = 1.f / sum;
            u32x4* dst = (u32x4*)(Ps + q * 288 + h * 24);
            u32x4 u0, u1, u2;
            #pragma unroll
            for (int c = 0; c < 4; ++c) {
                u0[c] = pack2(x[2 * c] * inv, x[2 * c + 1] * inv);
                u1[c] = pack2(x[8 + 2 * c] * inv, x[9 + 2 * c] * inv);
                u2[c] = pack2(x[16 + 2 * c] * inv, x[17 + 2 * c] * inv);
            }
            dst[0] = u0; dst[1] = u1; dst[2] = u2;
        }
        __syncthreads();
        unsigned short* dstG = Pn + (size_t)n * 14976;
        for (int p = tid; p < 1872; p += 256)
            *(u32x4*)(dstG + p * 8) = *(const u32x4*)(Ps + p * 8);
    }
}

// ---------------------------------------------------------------------------
// av_kernel: [0,1664) edge A@VWe blocks (n, i-pair, d-quarter) with fused
// max-over-j + e_bo; [1664,1728) node A@VWn blocks (n, d-quarter) writing
// all rows + n_bo. 256 thr, dbuf gl_lds, conflict-free ((x>>1)&3) keys.
// ---------------------------------------------------------------------------
__global__ __launch_bounds__(256)
void av_kernel(const unsigned short* __restrict__ Pe,
               const unsigned short* __restrict__ Pn,
               const unsigned short* __restrict__ VWe,
               const unsigned short* __restrict__ VWn,
               const float* __restrict__ ebo, const float* __restrict__ nbo,
               unsigned short* __restrict__ EdgeBb,
               unsigned short* __restrict__ NodePb)
{
    __shared__ __align__(16) char smem[40960];
    unsigned short* As = (unsigned short*)smem;             // 2 x 4096
    unsigned short* Bs = (unsigned short*)(smem + 16384);   // 2 x 6144
    const int bid = blockIdx.x;
    const int tid = threadIdx.x;
    const int lane = tid & 63, w = tid >> 6;
    const int lr = lane & 15, lk = lane >> 4;

    if (bid < 1664) {
        const int sw = (bid & 7) * 208 + (bid >> 3);        // XCD-contiguous
        const int n = sw / 104;
        const int r104 = sw % 104;
        const int ip = r104 >> 2, dq = r104 & 3;
        const int i0 = ip * 2;
        const unsigned short* Pa = Pe + (size_t)(n * 52 + i0) * 14976;
        const unsigned short* Bsrc = VWe + (size_t)n * 221184 + dq * 6144;

        const int ca0 = tid, ca1 = 256 + tid;
        const int ro0 = (ca0 >> 2) & 63, kp0 = ca0 & 3;
        const int ro1 = (ca1 >> 2) & 63, kp1 = ca1 & 3;
        const int sa0 = (ca0 >> 8) * 14976 + ro0 * 288 + ((kp0 ^ ((ro0 >> 1) & 3)) << 3);
        const int sa1 = (ca1 >> 8) * 14976 + ro1 * 288 + ((kp1 ^ ((ro1 >> 1) & 3)) << 3);

        gl_lds16(Pa + sa0, As + ca0 * 8);
        gl_lds16(Pa + sa1, As + ca1 * 8);
        #pragma unroll
        for (int q = 0; q < 3; ++q) {
            const int c = q * 256 + tid;
            gl_lds16(Bsrc + c * 8, Bs + c * 8);
        }
        __syncthreads();

        const int iw = w >> 1, cg = (w & 1) * 96;
        f32x4 acc[4][6] = {};
        for (int ks = 0; ks < 9; ++ks) {
            const int cur = ks & 1;
            if (ks < 8) {
                const int nb = cur ^ 1;
                gl_lds16(Pa + sa0 + (ks + 1) * 32, As + nb * 4096 + ca0 * 8);
                gl_lds16(Pa + sa1 + (ks + 1) * 32, As + nb * 4096 + ca1 * 8);
                #pragma unroll
                for (int q = 0; q < 3; ++q) {
                    const int c = q * 256 + tid;
                    gl_lds16(Bsrc + (size_t)(ks + 1) * 24576 + c * 8, Bs + nb * 6144 + c * 8);
                }
            }
            bf16x8 af[4];
            #pragma unroll
            for (int mt = 0; mt < 4; ++mt) {
                const int row = mt * 16 + lr;
                af[mt] = *(const bf16x8*)(As + cur * 4096 + iw * 2048 + row * 32
                                          + ((lk ^ ((row >> 1) & 3)) << 3));
            }
            #pragma unroll
            for (int nt = 0; nt < 6; ++nt) {
                const int cl = cg + nt * 16 + lr;
                bf16x8 bv = *(const bf16x8*)(Bs + cur * 6144 + cl * 32
                                             + ((lk ^ ((cl >> 1) & 3)) << 3));
                #pragma unroll
                for (int mt = 0; mt < 4; ++mt)
                    acc[mt][nt] = mfma16(af[mt], bv, acc[mt][nt]);
            }
            __syncthreads();
        }

        #pragma unroll
        for (int nt = 0; nt < 6; ++nt) {
            float m = -1e30f;
            #pragma unroll
            for (int mt = 0; mt < 4; ++mt)
                #pragma unroll
                for (int r = 0; r < 4; ++r) {
                    const int row = mt * 16 + lk * 4 + r;
                    if (row < NOBJ) m = fmaxf(m, acc[mt][nt][r]);
                }
            m = fmaxf(m, __shfl_xor(m, 16));
            m = fmaxf(m, __shfl_xor(m, 32));
            if (lk == 0) {
                const int col = dq * 192 + cg + nt * 16 + lr;
                EdgeBb[(size_t)(n * 52 + i0 + iw) * 768 + col] = f2b(m + ebo[col]);
            }
        }
    } else {
        const int t = bid - 1664;
        const int n = t >> 2, dq = t & 3;
        const unsigned short* Pa = Pn + (size_t)n * 14976;
        const unsigned short* Bsrc = VWn + (size_t)n * 221184 + dq * 6144;

        const int ro = (tid >> 2) & 63, kp = tid & 3;
        const int sa = ro * 288 + ((kp ^ ((ro >> 1) & 3)) << 3);

        gl_lds16(Pa + sa, As + tid * 8);
        #pragma unroll
        for (int q = 0; q < 3; ++q) {
            const int c = q * 256 + tid;
            gl_lds16(Bsrc + c * 8, Bs + c * 8);
        }
        __syncthreads();

        const int cg = w * 48;
        f32x4 acc[4][3] = {};
        for (int ks = 0; ks < 9; ++ks) {
            const int cur = ks & 1;
            if (ks < 8) {
                const int nb = cur ^ 1;
                gl_lds16(Pa + sa + (ks + 1) * 32, As + nb * 4096 + tid * 8);
                #pragma unroll
                for (int q = 0; q < 3; ++q) {
                    const int c = q * 256 + tid;
                    gl_lds16(Bsrc + (size_t)(ks + 1) * 24576 + c * 8, Bs + nb * 6144 + c * 8);
                }
            }
            bf16x8 af[4];
            #pragma unroll
            for (int mt = 0; mt < 4; ++mt) {
                const int row = mt * 16 + lr;
                af[mt] = *(const bf16x8*)(As + cur * 4096 + row * 32
                                          + ((lk ^ ((row >> 1) & 3)) << 3));
            }
            #pragma unroll
            for (int nt = 0; nt < 3; ++nt) {
                const int cl = cg + nt * 16 + lr;
                bf16x8 bv = *(const bf16x8*)(Bs + cur * 6144 + cl * 32
                                             + ((lk ^ ((cl >> 1) & 3)) << 3));
                #pragma unroll
                for (int mt = 0; mt < 4; ++mt)
                    acc[mt][nt] = mfma16(af[mt], bv, acc[mt][nt]);
            }
            __syncthreads();
        }

        #pragma unroll
        for (int nt = 0; nt < 3; ++nt) {
            const int col = dq * 192 + cg + nt * 16 + lr;
            const float bv = nbo[col];
            #pragma unroll
            for (int mt = 0; mt < 4; ++mt)
                #pragma unroll
                for (int r = 0; r < 4; ++r) {
                    const int row = mt * 16 + lk * 4 + r;
                    if (row < NOBJ)
                        NodePb[(size_t)(n * 52 + row) * 768 + col] = f2b(acc[mt][nt][r] + bv);
                }
        }
    }
}

// ---------------------------------------------------------------------------
// ln_dual: rows 0..831 -> LN(obj+NodePb) to Fusedb[:,0:768];
//          rows 832..1663 -> LN(obj+EdgeBb) to Fusedb[:,768:1536]
// ---------------------------------------------------------------------------
__global__ __launch_bounds__(256)
void ln_dual_kernel(const float* __restrict__ obj,
                    const unsigned short* __restrict__ NodePb,
                    const unsigned short* __restrict__ EdgeBb,
                    const float* __restrict__ gq, const float* __restrict__ bq,
                    const float* __restrict__ ge, const float* __restrict__ be,
                    unsigned short* __restrict__ Fusedb)
{
    __shared__ float red[8];
    const int job = blockIdx.x >= 832;
    const int row = blockIdx.x - (job ? 832 : 0);
    const int tid = threadIdx.x;
    const unsigned short* x2 = (job ? EdgeBb : NodePb) + (size_t)row * 768;
    const float* x1 = obj + (size_t)row * 768;
    const float* g = job ? ge : gq;
    const float* bb = job ? be : bq;
    float v[3]; float s = 0.f;
    #pragma unroll
    for (int c = 0; c < 3; ++c) {
        const int col = tid + 256 * c;
        v[c] = x1[col] + b2f(x2[col]); s += v[c];
    }
    #pragma unroll
    for (int o = 32; o; o >>= 1) s += __shfl_xor(s, o);
    if ((tid & 63) == 0) red[tid >> 6] = s;
    __syncthreads();
    const float mean = (red[0] + red[1] + red[2] + red[3]) * (1.f / 768.f);
    float var = 0.f;
    #pragma unroll
    for (int c = 0; c < 3; ++c) { const float d = v[c] - mean; var += d * d; }
    #pragma unroll
    for (int o = 32; o; o >>= 1) var += __shfl_xor(var, o);
    __syncthreads();
    if ((tid & 63) == 0) red[4 + (tid >> 6)] = var;
    __syncthreads();
    const float vt = (red[4] + red[5] + red[6] + red[7]) * (1.f / 768.f);
    const float rs = rsqrtf(vt + 1e-5f);
    unsigned short* dst = Fusedb + (size_t)row * 1536 + (job ? 768 : 0);
    #pragma unroll
    for (int c = 0; c < 3; ++c) {
        const int col = tid + 256 * c;
        dst[col] = f2b((v[c] - mean) * rs * g[col] + bb[col]);
    }
}

// ---------------------------------------------------------------------------
// final LN: out = LN(Fusedb(bf16, stride 1536) + H2(f32))
// ---------------------------------------------------------------------------
__global__ __launch_bounds__(256)
void ln2_kernel(const unsigned short* __restrict__ x1b,
                const float* __restrict__ x2,
                const float* __restrict__ g, const float* __restrict__ bb,
                float* __restrict__ dst)
{
    __shared__ float red[8];
    const int row = blockIdx.x, tid = threadIdx.x;
    float v[3]; float s = 0.f;
    #pragma unroll
    for (int c = 0; c < 3; ++c) {
        const int col = tid + 256 * c;
        v[c] = b2f(x1b[(size_t)row * 1536 + col]) + x2[(size_t)row * 768 + col];
        s += v[c];
    }
    #pragma unroll
    for (int o = 32; o; o >>= 1) s += __shfl_xor(s, o);
    if ((tid & 63) == 0) red[tid >> 6] = s;
    __syncthreads();
    const float mean = (red[0] + red[1] + red[2] + red[3]) * (1.f / 768.f);
    float var = 0.f;
    #pragma unroll
    for (int c = 0; c < 3; ++c) { const float d = v[c] - mean; var += d * d; }
    #pragma unroll
    for (int o = 32; o; o >>= 1) var += __shfl_xor(var, o);
    __syncthreads();
    if ((tid & 63) == 0) red[4 + (tid >> 6)] = var;
    __syncthreads();
    const float vt = (red[4] + red[5] + red[6] + red[7]) * (1.f / 768.f);
    const float rs = rsqrtf(vt + 1e-5f);
    #pragma unroll
    for (int c = 0; c < 3; ++c) {
        const int col = tid + 256 * c;
        dst[(size_t)row * 768 + col] = (v[c] - mean) * rs * g[col] + bb[col];
    }
}

// ---------------------------------------------------------------------------
extern "C" void kernel_launch(void* const* d_in, const int* in_sizes, int n_in,
                              void* d_out, int out_size, void* d_ws, size_t ws_size,
                              hipStream_t stream)
{
    (void)in_sizes; (void)n_in; (void)out_size; (void)ws_size;
    const float* lang  = (const float*)d_in[0];
    const float* obj   = (const float*)d_in[1];
    const int* co_mask = (const int*)d_in[4];
    const float* e_wq = (const float*)d_in[5];
    const float* e_bq = (const float*)d_in[6];
    const float* e_wk = (const float*)d_in[7];
    const float* e_bk = (const float*)d_in[8];
    const float* e_wv = (const float*)d_in[9];
    const float* e_bv = (const float*)d_in[10];
    const float* e_wo = (const float*)d_in[11];
    const float* e_bo = (const float*)d_in[12];
    const float* n_wq = (const float*)d_in[13];
    const float* n_bq = (const float*)d_in[14];
    const float* n_wk = (const float*)d_in[15];
    const float* n_bk = (const float*)d_in[16];
    const float* n_wv = (const float*)d_in[17];
    const float* n_bv = (const float*)d_in[18];
    const float* n_wo = (const float*)d_in[19];
    const float* n_bo = (const float*)d_in[20];
    const float* ffn_w1 = (const float*)d_in[21];
    const float* ffn_b1 = (const float*)d_in[22];
    const float* ffn_w2 = (const float*)d_in[23];
    const float* ffn_b2 = (const float*)d_in[24];
    const float* ln_e_g = (const float*)d_in[25];
    const float* ln_e_b = (const float*)d_in[26];
    const float* ln_q_g = (const float*)d_in[27];
    const float* ln_q_b = (const float*)d_in[28];
    const float* ln2_g = (const float*)d_in[29];
    const float* ln2_b = (const float*)d_in[30];
    float* out = (float*)d_out;

    // ---- workspace layout (flat, no aliasing; ~78 MB of ~256 MB) ----
    char* wsb = (char*)d_ws;
    unsigned short* Wqt   = (unsigned short*)(wsb + 0);          // [1536][768]
    unsigned short* Wlt   = (unsigned short*)(wsb + 2359296);    // [3072][768]
    unsigned short* Wet   = (unsigned short*)(wsb + 7077888);    // [768][768]
    unsigned short* Wot   = (unsigned short*)(wsb + 8257536);    // [768][768]
    unsigned short* W1t   = (unsigned short*)(wsb + 9437184);    // [2048][1536]
    unsigned short* W2t   = (unsigned short*)(wsb + 15728640);   // [768][2048]
    unsigned short* objb  = (unsigned short*)(wsb + 18874368);   // [832][768]
    unsigned short* langb = (unsigned short*)(wsb + 20152320);   // [384][768]
    float*          bqc   = (float*)(wsb + 20742144);            // [1536]
    float*          blc   = (float*)(wsb + 20748288);            // [3072]
    unsigned short* QCb   = (unsigned short*)(wsb + 20760576);   // [832][1536]
    unsigned short* LCb   = (unsigned short*)(wsb + 23316480);   // [384][3072]
    float*          S2e   = (float*)(wsb + 25675776);            // [16*12*52*24]
    float*          Tb    = (float*)(wsb + 26634240);            // [16*12*24]
    float*          S2n   = (float*)(wsb + 26652672);            // [16*12*52*24]
    unsigned short* VWe   = (unsigned short*)(wsb + 27611136);   // 16*221184
    unsigned short* VWn   = (unsigned short*)(wsb + 34689024);   // 16*221184
    unsigned short* Pe    = (unsigned short*)(wsb + 41766912);   // 832*14976
    unsigned short* Pn    = (unsigned short*)(wsb + 66686976);   // 16*14976 (+pad)
    unsigned short* NodePb= (unsigned short*)(wsb + 67198976);   // [832][768]
    unsigned short* EdgeBb= (unsigned short*)(wsb + 68476928);   // [832][768]
    unsigned short* Fusedb= (unsigned short*)(wsb + 69754880);   // [832][1536]
    unsigned short* H1b   = (unsigned short*)(wsb + 72310784);   // [832][2048]
    float*          H2    = (float*)(wsb + 75718656);            // [832][768]

    dim3 blk(256);
    // L1: pack all weights (transposed bf16) + activations + fused biases
    pack_all_kernel<<<3221, blk, 0, stream>>>(
        e_wq, n_wq, e_wk, e_wv, n_wk, n_wv, n_wo, e_wo, ffn_w1, ffn_w2,
        Wqt, Wqt + 589824, Wlt, Wlt + 589824, Wlt + 2 * 589824, Wlt + 3 * 589824,
        Wot, Wet, W1t, W2t,
        obj, lang, n_bq, e_bk, e_bv, n_bk, n_bv, objb, langb, bqc, blc);
    // L2: both input projections
    {
        GemmJob p0 = {objb, Wqt, bqc, nullptr, QCb, 768, 1536, 768, 12, 156, 0, 0};
        GemmJob p1 = {langb, Wlt, blc, nullptr, LCb, 768, 3072, 768, 24, 144, 0, 0};
        gemm_tn<<<300, blk, 0, stream>>>(p0, p1);
    }
    // L3: VWe + VWn (MFMA) + S2e/T + S2n
    mid3_kernel<<<816, blk, 0, stream>>>(QCb, LCb, Wet, Wot, e_bq,
                                         VWe, VWn, S2e, Tb, S2n);
    // L4: all softmax (edge 832 + node 16)
    sm_kernel<<<848, blk, 0, stream>>>(S2e, Tb, S2n, co_mask, Pe, Pn);
    // L5: A@VW (edge 1664 + node 64)
    av_kernel<<<1728, blk, 0, stream>>>(Pe, Pn, VWe, VWn, e_bo, n_bo, EdgeBb, NodePb);
    // L6: both fuse layernorms
    ln_dual_kernel<<<1664, blk, 0, stream>>>(obj, NodePb, EdgeBb, ln_q_g, ln_q_b,
                                             ln_e_g, ln_e_b, Fusedb);
    // L7-L8: FFN
    {
        GemmJob p0 = {Fusedb, W1t, ffn_b1, nullptr, H1b, 1536, 2048, 1536, 16, 208, 1, 1};
        gemm_tn<<<208, blk, 0, stream>>>(p0, p0);
    }
    {
        GemmJob p0 = {H1b, W2t, ffn_b2, H2, nullptr, 2048, 768, 2048, 6, 78, 0, 0};
        gemm_tn<<<78, blk, 0, stream>>>(p0, p0);
    }
    // L9: final LN
    ln2_kernel<<<832, blk, 0, stream>>>(Fusedb, H2, ln2_g, ln2_b, out);
}

// Round 7
// 125.179 us; speedup vs baseline: 4.1747x; 1.1003x over previous
//
#include <hip/hip_runtime.h>
#include <math.h>

#define NOBJ 52
#define LL 24
#define NHEAD 12

typedef __attribute__((ext_vector_type(8))) short bf16x8;
typedef __attribute__((ext_vector_type(4))) float f32x4;
typedef __attribute__((ext_vector_type(4))) unsigned int u32x4;
typedef __attribute__((ext_vector_type(2))) unsigned int u32x2;

__device__ __forceinline__ unsigned short f2b(float x) {
    union { float f; unsigned int u; } v; v.f = x;
    unsigned int r = v.u + 0x7fffu + ((v.u >> 16) & 1u);
    return (unsigned short)(r >> 16);
}
__device__ __forceinline__ float b2f(unsigned short u) {
    union { unsigned int u; float f; } v; v.u = ((unsigned int)u) << 16;
    return v.f;
}
__device__ __forceinline__ unsigned int pack2(float a, float b) {
    return (unsigned int)f2b(a) | ((unsigned int)f2b(b) << 16);
}
__device__ __forceinline__ f32x4 mfma16(bf16x8 a, bf16x8 b, f32x4 c) {
    return __builtin_amdgcn_mfma_f32_16x16x32_bf16(a, b, c, 0, 0, 0);
}
__device__ __forceinline__ void gl_lds16(const void* g, void* lds) {
    __builtin_amdgcn_global_load_lds(
        (const __attribute__((address_space(1))) unsigned int*)g,
        (__attribute__((address_space(3))) unsigned int*)lds, 16, 0, 0);
}

// ---------------------------------------------------------------------------
// 64x64 transpose tile: f32 [K][N] -> bf16 [N][K]
// ---------------------------------------------------------------------------
__device__ __forceinline__ void transpose_tile(const float* __restrict__ src,
    unsigned short* __restrict__ dst, int K, int N, int t, char* smem)
{
    float (*ts)[65] = (float(*)[65])smem;
    const int tid = threadIdx.x;
    const int ntk = K >> 6;
    const int k0 = (t % ntk) << 6, n0 = (t / ntk) << 6;
    const int tx = tid & 63, ty = tid >> 6;
    #pragma unroll
    for (int i2 = 0; i2 < 16; ++i2) {
        const int row = i2 * 4 + ty;
        ts[row][tx] = src[(size_t)(k0 + row) * N + n0 + tx];
    }
    __syncthreads();
    #pragma unroll
    for (int i2 = 0; i2 < 16; ++i2) {
        const int row = i2 * 4 + ty;
        dst[(size_t)(n0 + row) * K + k0 + tx] = f2b(ts[tx][row]);
    }
}

// ---------------------------------------------------------------------------
// pack1: 8 square weight transposes [0,1152) + activation/bias pack [1152,...)
// ---------------------------------------------------------------------------
__global__ __launch_bounds__(256)
void pack1_kernel(const float* s0, const float* s1, const float* s2,
                  const float* s3, const float* s4, const float* s5,
                  const float* s6, const float* s7,
                  unsigned short* d0, unsigned short* d1, unsigned short* d2,
                  unsigned short* d3, unsigned short* d4, unsigned short* d5,
                  unsigned short* d6, unsigned short* d7,
                  const float* obj, const float* lang, const float* n_bq,
                  const float* e_bk, const float* e_bv,
                  const float* n_bk, const float* n_bv,
                  unsigned short* objb, unsigned short* langb,
                  float* bqc, float* blc)
{
    __shared__ __align__(16) char smem[16640];
    const int bid = blockIdx.x;
    const int tid = threadIdx.x;
    if (bid < 1152) {
        const int job = bid / 144, t = bid % 144;
        const float* src; unsigned short* dst;
        switch (job) {
            case 0: src = s0; dst = d0; break;
            case 1: src = s1; dst = d1; break;
            case 2: src = s2; dst = d2; break;
            case 3: src = s3; dst = d3; break;
            case 4: src = s4; dst = d4; break;
            case 5: src = s5; dst = d5; break;
            case 6: src = s6; dst = d6; break;
            default: src = s7; dst = d7; break;
        }
        transpose_tile(src, dst, 768, 768, t, smem);
    } else {
        const int base = ((bid - 1152) * 256 + tid) * 4;
        const int T0 = 638976, T1 = 933888, T2 = 935424, T3 = 938496;
        if (base >= T3) return;
        if (base < T0) {
            f32x4 v = *(const f32x4*)(obj + base);
            *(u32x2*)(objb + base) = (u32x2){pack2(v[0], v[1]), pack2(v[2], v[3])};
        } else if (base < T1) {
            const int j = base - T0;
            f32x4 v = *(const f32x4*)(lang + j);
            *(u32x2*)(langb + j) = (u32x2){pack2(v[0], v[1]), pack2(v[2], v[3])};
        } else if (base < T2) {
            const int j = base - T1;
            if (j < 768) { *(f32x4*)(bqc + j) = (f32x4){0.f, 0.f, 0.f, 0.f}; }
            else         { *(f32x4*)(bqc + j) = *(const f32x4*)(n_bq + j - 768); }
        } else {
            const int j = base - T2;
            const int s = j / 768, c = j % 768;
            const float* p = (s == 0) ? e_bk : (s == 1) ? e_bv : (s == 2) ? n_bk : n_bv;
            *(f32x4*)(blc + j) = *(const f32x4*)(p + c);
        }
    }
}

// ---------------------------------------------------------------------------
// Generic GEMM: C[M,N] = A[M,K](bf16) @ Bt[N,K-slice]^T + bias (+relu).
// 64x128 tile, BK=64, dbuf global_load_lds, chunk-XOR swizzle. 256 thr.
// ldb = B row stride (for K-split partial jobs). swz requires nb%8==0.
// ---------------------------------------------------------------------------
struct GemmJob {
    const unsigned short* A; const unsigned short* Bt; const float* bias;
    float* C; unsigned short* Cb;
    int lda, ldb, ldc, K, nbx, nb, relu, swz;
};

__device__ __forceinline__ void gemm_body(const GemmJob J, int bid, char* smem)
{
    unsigned short* As = (unsigned short*)smem;             // 2 x 4096
    unsigned short* Bs = (unsigned short*)(smem + 16384);   // 2 x 8192
    int bx, by;
    if (J.swz) {
        const int cpx = J.nb >> 3;
        const int gid = (bid & 7) * cpx + (bid >> 3);
        const int nbm = J.nb / J.nbx;
        bx = gid / nbm; by = gid % nbm;
    } else { bx = bid % J.nbx; by = bid / J.nbx; }
    const int n0 = bx * 128, m0 = by * 64;
    const int tid = threadIdx.x;
    const int lane = tid & 63;
    const int w = tid >> 6, wr = w >> 1, wc = w & 1;
    const int lr = lane & 15, lk = lane >> 4;
    const int lda = J.lda, ldb = J.ldb, K = J.K;
    const unsigned short* Ab = J.A + (size_t)m0 * lda;
    const unsigned short* Bb = J.Bt + (size_t)n0 * ldb;

    f32x4 acc[2][4] = {};
    const int NT = K >> 6;

    #pragma unroll
    for (int q = 0; q < 2; ++q) {
        const int c = q * 256 + tid, row = c >> 3, p = (c & 7) ^ (row & 7);
        gl_lds16(Ab + (size_t)row * lda + p * 8, As + c * 8);
    }
    #pragma unroll
    for (int q = 0; q < 4; ++q) {
        const int c = q * 256 + tid, row = c >> 3, p = (c & 7) ^ (row & 7);
        gl_lds16(Bb + (size_t)row * ldb + p * 8, Bs + c * 8);
    }
    __syncthreads();

    for (int t = 0; t < NT; ++t) {
        const int cur = t & 1;
        if (t + 1 < NT) {
            const int k0 = (t + 1) << 6;
            #pragma unroll
            for (int q = 0; q < 2; ++q) {
                const int c = q * 256 + tid, row = c >> 3, p = (c & 7) ^ (row & 7);
                gl_lds16(Ab + (size_t)row * lda + k0 + p * 8, As + (cur ^ 1) * 4096 + c * 8);
            }
            #pragma unroll
            for (int q = 0; q < 4; ++q) {
                const int c = q * 256 + tid, row = c >> 3, p = (c & 7) ^ (row & 7);
                gl_lds16(Bb + (size_t)row * ldb + k0 + p * 8, Bs + (cur ^ 1) * 8192 + c * 8);
            }
        }
        #pragma unroll
        for (int kk = 0; kk < 2; ++kk) {
            bf16x8 af[2], bv[4];
            #pragma unroll
            for (int mt = 0; mt < 2; ++mt) {
                const int row = wr * 32 + mt * 16 + lr;
                const int pc = (kk * 4 + lk) ^ (row & 7);
                af[mt] = *(const bf16x8*)(As + cur * 4096 + row * 64 + pc * 8);
            }
            #pragma unroll
            for (int nt = 0; nt < 4; ++nt) {
                const int col = wc * 64 + nt * 16 + lr;
                const int pc = (kk * 4 + lk) ^ (col & 7);
                bv[nt] = *(const bf16x8*)(Bs + cur * 8192 + col * 64 + pc * 8);
            }
            #pragma unroll
            for (int mt = 0; mt < 2; ++mt)
                #pragma unroll
                for (int nt = 0; nt < 4; ++nt)
                    acc[mt][nt] = mfma16(af[mt], bv[nt], acc[mt][nt]);
        }
        __syncthreads();
    }

    #pragma unroll
    for (int mt = 0; mt < 2; ++mt) {
        #pragma unroll
        for (int nt = 0; nt < 4; ++nt) {
            const int col = n0 + wc * 64 + nt * 16 + lr;
            const float bvv = J.bias ? J.bias[col] : 0.f;
            #pragma unroll
            for (int r = 0; r < 4; ++r) {
                const int row = m0 + wr * 32 + mt * 16 + lk * 4 + r;
                float v = acc[mt][nt][r] + bvv;
                if (J.relu) v = fmaxf(v, 0.f);
                if (J.C)  J.C[(size_t)row * J.ldc + col] = v;
                if (J.Cb) J.Cb[(size_t)row * J.ldc + col] = f2b(v);
            }
        }
    }
}

__global__ __launch_bounds__(256)
void gemm_tn4(GemmJob j0, GemmJob j1, GemmJob j2, GemmJob j3)
{
    __shared__ __align__(16) char smem[49152];
    int bid = blockIdx.x;
    if (bid < j0.nb) { gemm_body(j0, bid, smem); return; }
    bid -= j0.nb;
    if (bid < j1.nb) { gemm_body(j1, bid, smem); return; }
    bid -= j1.nb;
    if (bid < j2.nb) { gemm_body(j2, bid, smem); return; }
    bid -= j2.nb;
    gemm_body(j3, bid, smem);
}

// ---------------------------------------------------------------------------
// proj_pack: [0,nb0+nb1) projection GEMMs; then ffn weight transposes
// ---------------------------------------------------------------------------
__global__ __launch_bounds__(256)
void proj_pack_kernel(GemmJob j0, GemmJob j1,
                      const float* w1, const float* w2,
                      unsigned short* W1t, unsigned short* W2t)
{
    __shared__ __align__(16) char smem[49152];
    int bid = blockIdx.x;
    if (bid < j0.nb) { gemm_body(j0, bid, smem); return; }
    bid -= j0.nb;
    if (bid < j1.nb) { gemm_body(j1, bid, smem); return; }
    const int t = bid - j1.nb;
    if (t < 768) transpose_tile(w1, W1t, 1536, 2048, t, smem);
    else transpose_tile(w2, W2t, 2048, 768, t - 768, smem);
}

// ---------------------------------------------------------------------------
// mid3: [0,216) VWe GEMM; [216,432) VWn GEMM; [432,624) S2e+T; [624,816) S2n
// ---------------------------------------------------------------------------
__global__ __launch_bounds__(256)
void mid3_kernel(const unsigned short* __restrict__ QCb,
                 const unsigned short* __restrict__ LCb,
                 const unsigned short* __restrict__ Wet,
                 const unsigned short* __restrict__ Wot,
                 const float* __restrict__ e_bq,
                 unsigned short* __restrict__ VWe,
                 unsigned short* __restrict__ VWn,
                 float* __restrict__ S2e, float* __restrict__ Tb,
                 float* __restrict__ S2n)
{
    __shared__ __align__(16) union USm {
        struct { unsigned short As[8192], Bs[8192]; } g;
        unsigned short Ct[128 * 136];
        struct { float sA[52][68], sB[24][68]; } s;
    } U;
    const int bid = blockIdx.x;
    const int tid = threadIdx.x;

    if (bid < 432) {
        const int sub = bid >= 216;
        const int b = sub ? bid - 216 : bid;
        const int aoff = sub ? 2304 : 768;
        const unsigned short* Bt = sub ? Wot : Wet;
        unsigned short* Vout = sub ? VWn : VWe;

        const int h = b / 18, rm = b % 18, mt = rm / 6, ntile = rm % 6;
        const int m0 = mt * 128, n0 = ntile * 128;
        const int lane = tid & 63, w = tid >> 6, wr = w >> 1, wc = w & 1;
        const int lr = lane & 15, lk = lane >> 4;
        #pragma unroll
        for (int q = 0; q < 4; ++q) {
            const int c = q * 256 + tid, row = c >> 3, p = (c & 7) ^ (row & 7);
            gl_lds16(LCb + (size_t)(m0 + row) * 3072 + aoff + h * 64 + p * 8, &U.g.As[c * 8]);
            gl_lds16(Bt + (size_t)(n0 + row) * 768 + h * 64 + p * 8, &U.g.Bs[c * 8]);
        }
        __syncthreads();
        f32x4 acc[4][4] = {};
        #pragma unroll
        for (int kk = 0; kk < 2; ++kk) {
            bf16x8 af[4], bv[4];
            #pragma unroll
            for (int m2 = 0; m2 < 4; ++m2) {
                const int row = wr * 64 + m2 * 16 + lr;
                const int pc = (kk * 4 + lk) ^ (row & 7);
                af[m2] = *(const bf16x8*)&U.g.As[row * 64 + pc * 8];
            }
            #pragma unroll
            for (int n2 = 0; n2 < 4; ++n2) {
                const int col = wc * 64 + n2 * 16 + lr;
                const int pc = (kk * 4 + lk) ^ (col & 7);
                bv[n2] = *(const bf16x8*)&U.g.Bs[col * 64 + pc * 8];
            }
            #pragma unroll
            for (int m2 = 0; m2 < 4; ++m2)
                #pragma unroll
                for (int n2 = 0; n2 < 4; ++n2)
                    acc[m2][n2] = mfma16(af[m2], bv[n2], acc[m2][n2]);
        }
        __syncthreads();
        #pragma unroll
        for (int m2 = 0; m2 < 4; ++m2)
            #pragma unroll
            for (int n2 = 0; n2 < 4; ++n2) {
                const int col = wc * 64 + n2 * 16 + lr;
                #pragma unroll
                for (int r = 0; r < 4; ++r) {
                    const int row = wr * 64 + m2 * 16 + lk * 4 + r;
                    U.Ct[row * 136 + col] = f2b(acc[m2][n2][r]);
                }
            }
        __syncthreads();
        #pragma unroll
        for (int q = 0; q < 8; ++q) {
            const int item = q * 256 + tid;
            const int dl = item & 127, kg = item >> 7;
            const int m = m0 + kg * 8;
            const int nn = m / 24, l0 = m % 24;
            const int kc = (h * 24 + l0) >> 3;
            const int ks = kc >> 2;
            const int dg = n0 + dl;
            const int kpos = (kc & 3) ^ ((dg >> 1) & 3);
            u32x4 uu;
            #pragma unroll
            for (int e = 0; e < 4; ++e)
                uu[e] = (unsigned int)U.Ct[(kg * 8 + 2 * e) * 136 + dl]
                      | ((unsigned int)U.Ct[(kg * 8 + 2 * e + 1) * 136 + dl] << 16);
            *(u32x4*)(Vout + (size_t)nn * 221184 + ks * 24576 + dg * 32 + kpos * 8) = uu;
        }
    } else {
        const int sub = bid >= 624;               // 0: S2e(+T), 1: S2n
        const int b = bid - (sub ? 624 : 432);
        const int n = b / NHEAD, h = b % NHEAD;
        const int qoff = sub ? 768 : 0, koff = sub ? 1536 : 0;
        float* Sout = sub ? S2n : S2e;
        for (int p = tid; p < 52 * 64; p += 256) {
            const int q = p >> 6, d = p & 63;
            U.s.sA[q][d] = b2f(QCb[(size_t)(n * 52 + q) * 1536 + qoff + h * 64 + d]);
        }
        for (int p = tid; p < 24 * 64; p += 256) {
            const int l = p >> 6, d = p & 63;
            U.s.sB[l][d] = b2f(LCb[(size_t)(n * 24 + l) * 3072 + koff + h * 64 + d]);
        }
        __syncthreads();
        for (int p = tid; p < 52 * 24; p += 256) {
            const int q = p / 24, l = p % 24;
            float s = 0.f;
            #pragma unroll
            for (int d = 0; d < 64; ++d) s += U.s.sA[q][d] * U.s.sB[l][d];
            Sout[((size_t)(n * NHEAD + h) * 52 + q) * 24 + l] = s;
        }
        if (!sub && tid < 24) {
            float s = 0.f;
            #pragma unroll
            for (int d = 0; d < 64; ++d) s += e_bq[h * 64 + d] * U.s.sB[tid][d];
            Tb[((size_t)n * NHEAD + h) * 24 + tid] = s;
        }
    }
}

// ---------------------------------------------------------------------------
// sm_kernel: [0,832) edge softmax per (n,i) -> Pe; [832,848) node softmax -> Pn
// ---------------------------------------------------------------------------
__global__ __launch_bounds__(256)
void sm_kernel(const float* __restrict__ S2e, const float* __restrict__ Tb,
               const float* __restrict__ S2n, const int* __restrict__ co_mask,
               unsigned short* __restrict__ Pe, unsigned short* __restrict__ Pn)
{
    __shared__ __align__(16) unsigned short Ps[52 * 288];
    __shared__ float SiT[288];
    __shared__ unsigned char cmb[1248];
    const int bid = blockIdx.x;
    const int tid = threadIdx.x;

    if (bid < 832) {
        const int n = bid / 52, i = bid % 52;
        const float* S2x = S2e + (size_t)n * NHEAD * 52 * 24;
        for (int p = tid; p < 288; p += 256) {
            const int h = p / 24, l = p % 24;
            SiT[p] = S2x[((size_t)h * 52 + i) * 24 + l] + Tb[((size_t)n * NHEAD + h) * 24 + l];
        }
        for (int p = tid; p < 1248; p += 256)
            cmb[p] = (unsigned char)(co_mask[(size_t)n * 1248 + p] > 0);
        __syncthreads();
        for (int p = tid; p < 624; p += 256) {
            const int h = p / 52, j = p % 52;
            const float* Sj = S2x + ((size_t)h * 52 + j) * 24;
            const float* st = SiT + h * 24;
            float x[24]; float mx = -1e30f;
            #pragma unroll
            for (int l = 0; l < 24; ++l) {
                float v = (st[l] - Sj[l]) * 0.125f;
                v = cmb[l * 52 + j] ? v : -1e9f;
                x[l] = v; mx = fmaxf(mx, v);
            }
            float sum = 0.f;
            #pragma unroll
            for (int l = 0; l < 24; ++l) { const float e = __expf(x[l] - mx); x[l] = e; sum += e; }
            const float inv = 1.f / sum;
            u32x4* dst = (u32x4*)(Ps + j * 288 + h * 24);
            u32x4 u0, u1, u2;
            #pragma unroll
            for (int c = 0; c < 4; ++c) {
                u0[c] = pack2(x[2 * c] * inv, x[2 * c + 1] * inv);
                u1[c] = pack2(x[8 + 2 * c] * inv, x[9 + 2 * c] * inv);
                u2[c] = pack2(x[16 + 2 * c] * inv, x[17 + 2 * c] * inv);
            }
            dst[0] = u0; dst[1] = u1; dst[2] = u2;
        }
        __syncthreads();
        unsigned short* dstG = Pe + (size_t)bid * 14976;
        for (int p = tid; p < 1872; p += 256)
            *(u32x4*)(dstG + p * 8) = *(const u32x4*)(Ps + p * 8);
    } else {
        const int n = bid - 832;
        const float* S2x = S2n + (size_t)n * NHEAD * 52 * 24;
        for (int p = tid; p < 1248; p += 256)
            cmb[p] = (unsigned char)(co_mask[(size_t)n * 1248 + p] > 0);
        __syncthreads();
        for (int p = tid; p < 624; p += 256) {
            const int h = p / 52, q = p % 52;
            const float* Sq = S2x + ((size_t)h * 52 + q) * 24;
            float x[24]; float mx = -1e30f;
            #pragma unroll
            for (int l = 0; l < 24; ++l) {
                float v = Sq[l] * 0.125f;
                v = cmb[l * 52 + q] ? v : -1e9f;
                x[l] = v; mx = fmaxf(mx, v);
            }
            float sum = 0.f;
            #pragma unroll
            for (int l = 0; l < 24; ++l) { const float e = __expf(x[l] - mx); x[l] = e; sum += e; }
            const float inv = 1.f / sum;
            u32x4* dst = (u32x4*)(Ps + q * 288 + h * 24);
            u32x4 u0, u1, u2;
            #pragma unroll
            for (int c = 0; c < 4; ++c) {
                u0[c] = pack2(x[2 * c] * inv, x[2 * c + 1] * inv);
                u1[c] = pack2(x[8 + 2 * c] * inv, x[9 + 2 * c] * inv);
                u2[c] = pack2(x[16 + 2 * c] * inv, x[17 + 2 * c] * inv);
            }
            dst[0] = u0; dst[1] = u1; dst[2] = u2;
        }
        __syncthreads();
        unsigned short* dstG = Pn + (size_t)n * 14976;
        for (int p = tid; p < 1872; p += 256)
            *(u32x4*)(dstG + p * 8) = *(const u32x4*)(Ps + p * 8);
    }
}

// ---------------------------------------------------------------------------
// av_kernel: [0,1664) edge A@VWe (n, i-pair, d-quarter) + fused max-over-j;
// [1664,1728) node A@VWn (n, d-quarter). dbuf gl_lds, ((x>>1)&3) keys.
// ---------------------------------------------------------------------------
__global__ __launch_bounds__(256)
void av_kernel(const unsigned short* __restrict__ Pe,
               const unsigned short* __restrict__ Pn,
               const unsigned short* __restrict__ VWe,
               const unsigned short* __restrict__ VWn,
               const float* __restrict__ ebo, const float* __restrict__ nbo,
               unsigned short* __restrict__ EdgeBb,
               unsigned short* __restrict__ NodePb)
{
    __shared__ __align__(16) char smem[40960];
    unsigned short* As = (unsigned short*)smem;             // 2 x 4096
    unsigned short* Bs = (unsigned short*)(smem + 16384);   // 2 x 6144
    const int bid = blockIdx.x;
    const int tid = threadIdx.x;
    const int lane = tid & 63, w = tid >> 6;
    const int lr = lane & 15, lk = lane >> 4;

    if (bid < 1664) {
        const int sw = (bid & 7) * 208 + (bid >> 3);        // XCD-contiguous
        const int n = sw / 104;
        const int r104 = sw % 104;
        const int ip = r104 >> 2, dq = r104 & 3;
        const int i0 = ip * 2;
        const unsigned short* Pa = Pe + (size_t)(n * 52 + i0) * 14976;
        const unsigned short* Bsrc = VWe + (size_t)n * 221184 + dq * 6144;

        const int ca0 = tid, ca1 = 256 + tid;
        const int ro0 = (ca0 >> 2) & 63, kp0 = ca0 & 3;
        const int ro1 = (ca1 >> 2) & 63, kp1 = ca1 & 3;
        const int sa0 = (ca0 >> 8) * 14976 + ro0 * 288 + ((kp0 ^ ((ro0 >> 1) & 3)) << 3);
        const int sa1 = (ca1 >> 8) * 14976 + ro1 * 288 + ((kp1 ^ ((ro1 >> 1) & 3)) << 3);

        gl_lds16(Pa + sa0, As + ca0 * 8);
        gl_lds16(Pa + sa1, As + ca1 * 8);
        #pragma unroll
        for (int q = 0; q < 3; ++q) {
            const int c = q * 256 + tid;
            gl_lds16(Bsrc + c * 8, Bs + c * 8);
        }
        __syncthreads();

        const int iw = w >> 1, cg = (w & 1) * 96;
        f32x4 acc[4][6] = {};
        for (int ks = 0; ks < 9; ++ks) {
            const int cur = ks & 1;
            if (ks < 8) {
                const int nb = cur ^ 1;
                gl_lds16(Pa + sa0 + (ks + 1) * 32, As + nb * 4096 + ca0 * 8);
                gl_lds16(Pa + sa1 + (ks + 1) * 32, As + nb * 4096 + ca1 * 8);
                #pragma unroll
                for (int q = 0; q < 3; ++q) {
                    const int c = q * 256 + tid;
                    gl_lds16(Bsrc + (size_t)(ks + 1) * 24576 + c * 8, Bs + nb * 6144 + c * 8);
                }
            }
            bf16x8 af[4];
            #pragma unroll
            for (int mt = 0; mt < 4; ++mt) {
                const int row = mt * 16 + lr;
                af[mt] = *(const bf16x8*)(As + cur * 4096 + iw * 2048 + row * 32
                                          + ((lk ^ ((row >> 1) & 3)) << 3));
            }
            #pragma unroll
            for (int nt = 0; nt < 6; ++nt) {
                const int cl = cg + nt * 16 + lr;
                bf16x8 bv = *(const bf16x8*)(Bs + cur * 6144 + cl * 32
                                             + ((lk ^ ((cl >> 1) & 3)) << 3));
                #pragma unroll
                for (int mt = 0; mt < 4; ++mt)
                    acc[mt][nt] = mfma16(af[mt], bv, acc[mt][nt]);
            }
            __syncthreads();
        }

        #pragma unroll
        for (int nt = 0; nt < 6; ++nt) {
            float m = -1e30f;
            #pragma unroll
            for (int mt = 0; mt < 4; ++mt)
                #pragma unroll
                for (int r = 0; r < 4; ++r) {
                    const int row = mt * 16 + lk * 4 + r;
                    if (row < NOBJ) m = fmaxf(m, acc[mt][nt][r]);
                }
            m = fmaxf(m, __shfl_xor(m, 16));
            m = fmaxf(m, __shfl_xor(m, 32));
            if (lk == 0) {
                const int col = dq * 192 + cg + nt * 16 + lr;
                EdgeBb[(size_t)(n * 52 + i0 + iw) * 768 + col] = f2b(m + ebo[col]);
            }
        }
    } else {
        const int t = bid - 1664;
        const int n = t >> 2, dq = t & 3;
        const unsigned short* Pa = Pn + (size_t)n * 14976;
        const unsigned short* Bsrc = VWn + (size_t)n * 221184 + dq * 6144;

        const int ro = (tid >> 2) & 63, kp = tid & 3;
        const int sa = ro * 288 + ((kp ^ ((ro >> 1) & 3)) << 3);

        gl_lds16(Pa + sa, As + tid * 8);
        #pragma unroll
        for (int q = 0; q < 3; ++q) {
            const int c = q * 256 + tid;
            gl_lds16(Bsrc + c * 8, Bs + c * 8);
        }
        __syncthreads();

        const int cg = w * 48;
        f32x4 acc[4][3] = {};
        for (int ks = 0; ks < 9; ++ks) {
            const int cur = ks & 1;
            if (ks < 8) {
                const int nb = cur ^ 1;
                gl_lds16(Pa + sa + (ks + 1) * 32, As + nb * 4096 + tid * 8);
                #pragma unroll
                for (int q = 0; q < 3; ++q) {
                    const int c = q * 256 + tid;
                    gl_lds16(Bsrc + (size_t)(ks + 1) * 24576 + c * 8, Bs + nb * 6144 + c * 8);
                }
            }
            bf16x8 af[4];
            #pragma unroll
            for (int mt = 0; mt < 4; ++mt) {
                const int row = mt * 16 + lr;
                af[mt] = *(const bf16x8*)(As + cur * 4096 + row * 32
                                          + ((lk ^ ((row >> 1) & 3)) << 3));
            }
            #pragma unroll
            for (int nt = 0; nt < 3; ++nt) {
                const int cl = cg + nt * 16 + lr;
                bf16x8 bv = *(const bf16x8*)(Bs + cur * 6144 + cl * 32
                                             + ((lk ^ ((cl >> 1) & 3)) << 3));
                #pragma unroll
                for (int mt = 0; mt < 4; ++mt)
                    acc[mt][nt] = mfma16(af[mt], bv, acc[mt][nt]);
            }
            __syncthreads();
        }

        #pragma unroll
        for (int nt = 0; nt < 3; ++nt) {
            const int col = dq * 192 + cg + nt * 16 + lr;
            const float bv = nbo[col];
            #pragma unroll
            for (int mt = 0; mt < 4; ++mt)
                #pragma unroll
                for (int r = 0; r < 4; ++r) {
                    const int row = mt * 16 + lk * 4 + r;
                    if (row < NOBJ)
                        NodePb[(size_t)(n * 52 + row) * 768 + col] = f2b(acc[mt][nt][r] + bv);
                }
        }
    }
}

// ---------------------------------------------------------------------------
// ln_dual: rows 0..831 -> LN(obj+NodePb); rows 832..1663 -> LN(obj+EdgeBb)
// ---------------------------------------------------------------------------
__global__ __launch_bounds__(256)
void ln_dual_kernel(const float* __restrict__ obj,
                    const unsigned short* __restrict__ NodePb,
                    const unsigned short* __restrict__ EdgeBb,
                    const float* __restrict__ gq, const float* __restrict__ bq,
                    const float* __restrict__ ge, const float* __restrict__ be,
                    unsigned short* __restrict__ Fusedb)
{
    __shared__ float red[8];
    const int job = blockIdx.x >= 832;
    const int row = blockIdx.x - (job ? 832 : 0);
    const int tid = threadIdx.x;
    const unsigned short* x2 = (job ? EdgeBb : NodePb) + (size_t)row * 768;
    const float* x1 = obj + (size_t)row * 768;
    const float* g = job ? ge : gq;
    const float* bb = job ? be : bq;
    float v[3]; float s = 0.f;
    #pragma unroll
    for (int c = 0; c < 3; ++c) {
        const int col = tid + 256 * c;
        v[c] = x1[col] + b2f(x2[col]); s += v[c];
    }
    #pragma unroll
    for (int o = 32; o; o >>= 1) s += __shfl_xor(s, o);
    if ((tid & 63) == 0) red[tid >> 6] = s;
    __syncthreads();
    const float mean = (red[0] + red[1] + red[2] + red[3]) * (1.f / 768.f);
    float var = 0.f;
    #pragma unroll
    for (int c = 0; c < 3; ++c) { const float d = v[c] - mean; var += d * d; }
    #pragma unroll
    for (int o = 32; o; o >>= 1) var += __shfl_xor(var, o);
    __syncthreads();
    if ((tid & 63) == 0) red[4 + (tid >> 6)] = var;
    __syncthreads();
    const float vt = (red[4] + red[5] + red[6] + red[7]) * (1.f / 768.f);
    const float rs = rsqrtf(vt + 1e-5f);
    unsigned short* dst = Fusedb + (size_t)row * 1536 + (job ? 768 : 0);
    #pragma unroll
    for (int c = 0; c < 3; ++c) {
        const int col = tid + 256 * c;
        dst[col] = f2b((v[c] - mean) * rs * g[col] + bb[col]);
    }
}

// ---------------------------------------------------------------------------
// final LN: out = LN(Fusedb + sum of 4 ffn2 K-partials + ffn_b2)
// ---------------------------------------------------------------------------
__global__ __launch_bounds__(256)
void ln2_kernel(const unsigned short* __restrict__ x1b,
                const float* __restrict__ Hp, const float* __restrict__ b2,
                const float* __restrict__ g, const float* __restrict__ bb,
                float* __restrict__ dst)
{
    __shared__ float red[8];
    const int row = blockIdx.x, tid = threadIdx.x;
    float v[3]; float s = 0.f;
    #pragma unroll
    for (int c = 0; c < 3; ++c) {
        const int col = tid + 256 * c;
        const size_t o = (size_t)row * 768 + col;
        float h = Hp[o] + Hp[638976 + o] + Hp[2 * 638976 + o] + Hp[3 * 638976 + o];
        v[c] = b2f(x1b[(size_t)row * 1536 + col]) + h + b2[col];
        s += v[c];
    }
    #pragma unroll
    for (int o = 32; o; o >>= 1) s += __shfl_xor(s, o);
    if ((tid & 63) == 0) red[tid >> 6] = s;
    __syncthreads();
    const float mean = (red[0] + red[1] + red[2] + red[3]) * (1.f / 768.f);
    float var = 0.f;
    #pragma unroll
    for (int c = 0; c < 3; ++c) { const float d = v[c] - mean; var += d * d; }
    #pragma unroll
    for (int o = 32; o; o >>= 1) var += __shfl_xor(var, o);
    __syncthreads();
    if ((tid & 63) == 0) red[4 + (tid >> 6)] = var;
    __syncthreads();
    const float vt = (red[4] + red[5] + red[6] + red[7]) * (1.f / 768.f);
    const float rs = rsqrtf(vt + 1e-5f);
    #pragma unroll
    for (int c = 0; c < 3; ++c) {
        const int col = tid + 256 * c;
        dst[(size_t)row * 768 + col] = (v[c] - mean) * rs * g[col] + bb[col];
    }
}

// ---------------------------------------------------------------------------
extern "C" void kernel_launch(void* const* d_in, const int* in_sizes, int n_in,
                              void* d_out, int out_size, void* d_ws, size_t ws_size,
                              hipStream_t stream)
{
    (void)in_sizes; (void)n_in; (void)out_size; (void)ws_size;
    const float* lang  = (const float*)d_in[0];
    const float* obj   = (const float*)d_in[1];
    const int* co_mask = (const int*)d_in[4];
    const float* e_wq = (const float*)d_in[5];
    const float* e_bq = (const float*)d_in[6];
    const float* e_wk = (const float*)d_in[7];
    const float* e_bk = (const float*)d_in[8];
    const float* e_wv = (const float*)d_in[9];
    const float* e_bv = (const float*)d_in[10];
    const float* e_wo = (const float*)d_in[11];
    const float* e_bo = (const float*)d_in[12];
    const float* n_wq = (const float*)d_in[13];
    const float* n_bq = (const float*)d_in[14];
    const float* n_wk = (const float*)d_in[15];
    const float* n_bk = (const float*)d_in[16];
    const float* n_wv = (const float*)d_in[17];
    const float* n_bv = (const float*)d_in[18];
    const float* n_wo = (const float*)d_in[19];
    const float* n_bo = (const float*)d_in[20];
    const float* ffn_w1 = (const float*)d_in[21];
    const float* ffn_b1 = (const float*)d_in[22];
    const float* ffn_w2 = (const float*)d_in[23];
    const float* ffn_b2 = (const float*)d_in[24];
    const float* ln_e_g = (const float*)d_in[25];
    const float* ln_e_b = (const float*)d_in[26];
    const float* ln_q_g = (const float*)d_in[27];
    const float* ln_q_b = (const float*)d_in[28];
    const float* ln2_g = (const float*)d_in[29];
    const float* ln2_b = (const float*)d_in[30];
    float* out = (float*)d_out;

    // ---- workspace layout (flat, ~86 MB of ~256 MB) ----
    char* wsb = (char*)d_ws;
    unsigned short* Wqt   = (unsigned short*)(wsb + 0);          // [1536][768]
    unsigned short* Wlt   = (unsigned short*)(wsb + 2359296);    // [3072][768]
    unsigned short* Wet   = (unsigned short*)(wsb + 7077888);    // [768][768]
    unsigned short* Wot   = (unsigned short*)(wsb + 8257536);    // [768][768]
    unsigned short* W1t   = (unsigned short*)(wsb + 9437184);    // [2048][1536]
    unsigned short* W2t   = (unsigned short*)(wsb + 15728640);   // [768][2048]
    unsigned short* objb  = (unsigned short*)(wsb + 18874368);   // [832][768]
    unsigned short* langb = (unsigned short*)(wsb + 20152320);   // [384][768]
    float*          bqc   = (float*)(wsb + 20742144);            // [1536]
    float*          blc   = (float*)(wsb + 20748288);            // [3072]
    unsigned short* QCb   = (unsigned short*)(wsb + 20760576);   // [832][1536]
    unsigned short* LCb   = (unsigned short*)(wsb + 23316480);   // [384][3072]
    float*          S2e   = (float*)(wsb + 25675776);
    float*          Tb    = (float*)(wsb + 26634240);
    float*          S2n   = (float*)(wsb + 26652672);
    unsigned short* VWe   = (unsigned short*)(wsb + 27611136);   // 16*221184
    unsigned short* VWn   = (unsigned short*)(wsb + 34689024);   // 16*221184
    unsigned short* Pe    = (unsigned short*)(wsb + 41766912);   // 832*14976
    unsigned short* Pn    = (unsigned short*)(wsb + 66686976);   // 16*14976
    unsigned short* NodePb= (unsigned short*)(wsb + 67198976);   // [832][768]
    unsigned short* EdgeBb= (unsigned short*)(wsb + 68476928);   // [832][768]
    unsigned short* Fusedb= (unsigned short*)(wsb + 69754880);   // [832][1536]
    unsigned short* H1b   = (unsigned short*)(wsb + 72310784);   // [832][2048]
    float*          Hp    = (float*)(wsb + 75718656);            // 4x[832][768] f32

    dim3 blk(256);
    // L1: pack square weights + activations + fused biases
    pack1_kernel<<<2069, blk, 0, stream>>>(
        e_wq, n_wq, e_wk, e_wv, n_wk, n_wv, n_wo, e_wo,
        Wqt, Wqt + 589824, Wlt, Wlt + 589824, Wlt + 2 * 589824, Wlt + 3 * 589824,
        Wot, Wet,
        obj, lang, n_bq, e_bk, e_bv, n_bk, n_bv, objb, langb, bqc, blc);
    // L2: both input projections + FFN weight transposes (independent filler)
    {
        GemmJob p0 = {objb, Wqt, bqc, nullptr, QCb, 768, 768, 1536, 768, 12, 156, 0, 0};
        GemmJob p1 = {langb, Wlt, blc, nullptr, LCb, 768, 768, 3072, 768, 24, 144, 0, 0};
        proj_pack_kernel<<<1452, blk, 0, stream>>>(p0, p1, ffn_w1, ffn_w2, W1t, W2t);
    }
    // L3: VWe + VWn (MFMA) + S2e/T + S2n
    mid3_kernel<<<816, blk, 0, stream>>>(QCb, LCb, Wet, Wot, e_bq,
                                         VWe, VWn, S2e, Tb, S2n);
    // L4: all softmax (edge 832 + node 16)
    sm_kernel<<<848, blk, 0, stream>>>(S2e, Tb, S2n, co_mask, Pe, Pn);
    // L5: A@VW (edge 1664 + node 64)
    av_kernel<<<1728, blk, 0, stream>>>(Pe, Pn, VWe, VWn, e_bo, n_bo, EdgeBb, NodePb);
    // L6: both fuse layernorms
    ln_dual_kernel<<<1664, blk, 0, stream>>>(obj, NodePb, EdgeBb, ln_q_g, ln_q_b,
                                             ln_e_g, ln_e_b, Fusedb);
    // L7: FFN1
    {
        GemmJob p0 = {Fusedb, W1t, ffn_b1, nullptr, H1b, 1536, 1536, 2048, 1536, 16, 208, 1, 1};
        gemm_tn4<<<208, blk, 0, stream>>>(p0, p0, p0, p0);
    }
    // L8: FFN2 K-split x4 -> f32 partials
    {
        GemmJob q0 = {H1b,        W2t,        nullptr, Hp,               nullptr, 2048, 2048, 768, 512, 6, 78, 0, 0};
        GemmJob q1 = {H1b + 512,  W2t + 512,  nullptr, Hp + 638976,      nullptr, 2048, 2048, 768, 512, 6, 78, 0, 0};
        GemmJob q2 = {H1b + 1024, W2t + 1024, nullptr, Hp + 2 * 638976,  nullptr, 2048, 2048, 768, 512, 6, 78, 0, 0};
        GemmJob q3 = {H1b + 1536, W2t + 1536, nullptr, Hp + 3 * 638976,  nullptr, 2048, 2048, 768, 512, 6, 78, 0, 0};
        gemm_tn4<<<312, blk, 0, stream>>>(q0, q1, q2, q3);
    }
    // L9: final LN (sums partials + bias)
    ln2_kernel<<<832, blk, 0, stream>>>(Fusedb, Hp, ffn_b2, ln2_g, ln2_b, out);
}